// Round 18
// baseline (231.884 us; speedup 1.0000x reference)
//
#include <hip/hip_runtime.h>
#include <hip/hip_bf16.h>

typedef __attribute__((ext_vector_type(4))) float f32x4;
typedef __attribute__((ext_vector_type(8))) short bf16x8;

#define B_ROWS 16384
#define IN_DIM 768
#define H1 512
#define H2 256
#define NC 50
#define NE 8
#define RH1 256
#define RH2 128
#define CHK 128
#define CHKX 64

static __device__ __forceinline__ f32x4 mfma16(bf16x8 a, bf16x8 b, f32x4 c) {
    return __builtin_amdgcn_mfma_f32_16x16x32_bf16(a, b, c, 0, 0, 0);
}

typedef __attribute__((address_space(1))) const unsigned int gas_u32;
typedef __attribute__((address_space(3))) unsigned int las_u32;
static __device__ __forceinline__ void gl16(const void* g, void* l) {
    __builtin_amdgcn_global_load_lds((gas_u32*)g, (las_u32*)l, 16, 0, 0);
}

// expand 8 ternary byte-codes (bf16 high byte: 0x3F/0xBF/0x00) to exact bf16x8
static __device__ __forceinline__ bf16x8 expand_frag(uint2 pw) {
    unsigned q0 = (pw.x & 0x01010101u) << 7;
    unsigned q1 = (pw.y & 0x01010101u) << 7;
    union { unsigned u[4]; bf16x8 v; } r;
    r.u[0] = __builtin_amdgcn_perm(pw.x, q0, 0x05010400u);
    r.u[1] = __builtin_amdgcn_perm(pw.x, q0, 0x07030602u);
    r.u[2] = __builtin_amdgcn_perm(pw.y, q1, 0x05010400u);
    r.u[3] = __builtin_amdgcn_perm(pw.y, q1, 0x07030602u);
    return r.v;
}

// ---------------- merged ternarize+pack+abs-sum: grid (96, 24), 512 thr.
// W1/W2: PAIR layout — frags (2p,2p+1) adjacent 16B per lane. W3: flat layout.
__global__ __launch_bounds__(512) void pack_absum_kernel(
    const float* __restrict__ eW1, const float* __restrict__ eW2, const float* __restrict__ eW3,
    unsigned char* __restrict__ W1p8, unsigned char* __restrict__ W2p8,
    unsigned char* __restrict__ W3p8,
    float* __restrict__ p1, float* __restrict__ p2, float* __restrict__ p3)
{
    const int mat = blockIdx.y >> 3, e = blockIdx.y & 7;
    const int u = blockIdx.x * 512 + threadIdx.x;
    const float* src; unsigned char* dst; int valid = 1; float* P; int np;
    if (mat == 0) {
        int lane = u & 63, nblk = (u >> 6) & 31, ks = u >> 11;
        int n = nblk * 16 + (lane & 15), k = ks * 32 + (lane >> 4) * 8;
        src = eW1 + ((size_t)e * H1 + n) * IN_DIM + k;
        dst = W1p8 + (size_t)e * 393216
            + (size_t)ks * 16384 + (nblk >> 1) * 1024 + lane * 16 + (nblk & 1) * 8;
        P = p1; np = 96;
    } else if (mat == 1) {
        if (u >= 16384) return;
        int lane = u & 63, nblk = (u >> 6) & 15, ks = u >> 10;
        int n = nblk * 16 + (lane & 15), k = ks * 32 + (lane >> 4) * 8;
        src = eW2 + ((size_t)e * H2 + n) * H1 + k;
        dst = W2p8 + (size_t)e * 131072
            + (size_t)ks * 8192 + (nblk >> 1) * 1024 + lane * 16 + (nblk & 1) * 8;
        P = p2; np = 32;
    } else {
        if (u >= 2048) return;
        int lane = u & 63, nblk = (u >> 6) & 3, ks = u >> 8;
        int n = nblk * 16 + (lane & 15), k = ks * 32 + (lane >> 4) * 8;
        valid = (n < NC);
        src = eW3 + ((size_t)e * NC + (valid ? n : 0)) * H2 + k;
        dst = W3p8 + ((size_t)e * 2048 + u) * 8;
        P = p3; np = 4;
    }
    unsigned lo = 0, hi = 0;
    float s = 0.f;
    #pragma unroll
    for (int j = 0; j < 4; ++j) {
        float w = valid ? src[j] : 0.f;
        s += fabsf(w);
        unsigned c = (fabsf(w) > 0.05f) ? (w > 0.f ? 0x3Fu : 0xBFu) : 0u;
        lo |= c << (8 * j);
    }
    #pragma unroll
    for (int j = 0; j < 4; ++j) {
        float w = valid ? src[4 + j] : 0.f;
        s += fabsf(w);
        unsigned c = (fabsf(w) > 0.05f) ? (w > 0.f ? 0x3Fu : 0xBFu) : 0u;
        hi |= c << (8 * j);
    }
    *(uint2*)dst = make_uint2(lo, hi);
    const int lane = threadIdx.x & 63, wave = threadIdx.x >> 6;
    #pragma unroll
    for (int o = 32; o; o >>= 1) s += __shfl_down(s, o);
    __shared__ float red[8];
    if (lane == 0) red[wave] = s;
    __syncthreads();
    if (threadIdx.x == 0) {
        float t = 0.f;
        #pragma unroll
        for (int i = 0; i < 8; ++i) t += red[i];
        P[e * np + blockIdx.x] = t;
    }
}

// ---------------- finalize scales + zero dispatch counts
__global__ __launch_bounds__(64) void finalize_scales_kernel(
    const float* __restrict__ p1, const float* __restrict__ p2, const float* __restrict__ p3,
    float* __restrict__ s1, float* __restrict__ s2, float* __restrict__ s3,
    int* __restrict__ counts)
{
    int t = threadIdx.x;
    if (t < 8) {
        float a = 0.f;
        for (int i = 0; i < 96; ++i) a += p1[t * 96 + i];
        s1[t] = a / (float)(H1 * IN_DIM);
    } else if (t < 16) {
        int e = t - 8; float a = 0.f;
        for (int i = 0; i < 32; ++i) a += p2[e * 32 + i];
        s2[e] = a / (float)(H2 * H1);
    } else if (t < 24) {
        int e = t - 16; float a = 0.f;
        for (int i = 0; i < 4; ++i) a += p3[e * 4 + i];
        s3[e] = a / (float)(NC * H2);
    } else if (t < 32) {
        counts[t - 24] = 0;
    }
}

// ---------------- pack router weights into fragment-order hi/lo images
__global__ __launch_bounds__(512) void pack_router_kernel(
    const float* __restrict__ rW1, ushort* __restrict__ rw1hp, ushort* __restrict__ rw1lp,
    const float* __restrict__ rW2, ushort* __restrict__ rw2hp, ushort* __restrict__ rw2lp)
{
    int u = blockIdx.x * 512 + threadIdx.x;
    const float* src; ushort* dh; ushort* dl;
    if (u < 24576) {
        int lane = u & 63, nblk = (u >> 6) & 15, ks = u >> 10;
        int n = nblk * 16 + (lane & 15), k = ks * 32 + (lane >> 4) * 8;
        src = rW1 + (size_t)n * IN_DIM + k;
        dh = rw1hp + (size_t)u * 8; dl = rw1lp + (size_t)u * 8;
    } else {
        int v = u - 24576;
        if (v >= 4096) return;
        int lane = v & 63, nblk = (v >> 6) & 7, ks = v >> 9;
        int n = nblk * 16 + (lane & 15), k = ks * 32 + (lane >> 4) * 8;
        src = rW2 + (size_t)n * RH1 + k;
        dh = rw2hp + (size_t)v * 8; dl = rw2lp + (size_t)v * 8;
    }
    ushort oh[8], ol[8];
    #pragma unroll
    for (int j = 0; j < 8; ++j) {
        float w = src[j];
        __hip_bfloat16 h = __float2bfloat16(w);
        float hf = __bfloat162float(h);
        __hip_bfloat16 l = __float2bfloat16(w - hf);
        oh[j] = *(ushort*)&h; ol[j] = *(ushort*)&l;
    }
    ((ushort4*)dh)[0] = make_ushort4(oh[0], oh[1], oh[2], oh[3]);
    ((ushort4*)dh)[1] = make_ushort4(oh[4], oh[5], oh[6], oh[7]);
    ((ushort4*)dl)[0] = make_ushort4(ol[0], ol[1], ol[2], ol[3]);
    ((ushort4*)dl)[1] = make_ushort4(ol[4], ol[5], ol[6], ol[7]);
}

// ---------------- x hi/lo decomposition (3072 blocks)
__global__ __launch_bounds__(256) void decomp_x_kernel(
    const float* __restrict__ x, ushort* __restrict__ xh, ushort* __restrict__ xl)
{
    const float4* in = (const float4*)x;
    ushort4* hi = (ushort4*)xh;
    ushort4* lo = (ushort4*)xl;
    const int base = blockIdx.x * 1024;
    #pragma unroll
    for (int j = 0; j < 4; ++j) {
        int i = base + j * 256 + threadIdx.x;
        float4 v = in[i];
        float vv[4] = {v.x, v.y, v.z, v.w};
        ushort ho[4], lo4[4];
        #pragma unroll
        for (int q = 0; q < 4; ++q) {
            __hip_bfloat16 h = __float2bfloat16(vv[q]);
            float hf = __bfloat162float(h);
            __hip_bfloat16 l = __float2bfloat16(vv[q] - hf);
            ho[q] = *(ushort*)&h; lo4[q] = *(ushort*)&l;
        }
        hi[i] = make_ushort4(ho[0], ho[1], ho[2], ho[3]);
        lo[i] = make_ushort4(lo4[0], lo4[1], lo4[2], lo4[3]);
    }
}

// ---------------- fused router, 1024 threads (unchanged from R16/R17)
__global__ __launch_bounds__(1024) void router_fused_kernel(
    const ushort* __restrict__ xh, const ushort* __restrict__ xl,
    const ushort* __restrict__ rw1hp, const ushort* __restrict__ rw1lp, const float* __restrict__ rb1,
    const ushort* __restrict__ rw2hp, const ushort* __restrict__ rw2lp, const float* __restrict__ rb2,
    const float* __restrict__ rW3, const float* __restrict__ rb3,
    float* __restrict__ router_p, float* __restrict__ gate,
    float* __restrict__ lb_out, int* __restrict__ t2)
{
    __shared__ __align__(16) unsigned char smem[134144];
    unsigned char* Wst = smem;
    ushort (*Xdh)[32][136] = (ushort(*)[32][136])(smem + 65536);
    ushort (*Xdl)[32][136] = (ushort(*)[32][136])(smem + 65536 + 17408);
    float (*h2s)[132]      = (float(*)[132])(smem + 65536);
    ushort (*h1hs)[264]    = (ushort(*)[264])(smem + 100352);
    ushort (*h1ls)[264]    = (ushort(*)[264])(smem + 117248);

    const int tid = threadIdx.x, wave = tid >> 6, lane = tid & 63;
    const int lm = lane & 15, lk = lane >> 4;
    const int r0 = blockIdx.x * 32;

    const int half = tid >> 9;
    const int st   = tid & 511;
    const int srow = st >> 4;
    const int sc8  = (st & 15) * 8;
    const ushort* sg = (half ? xl : xh) + (size_t)(r0 + srow) * IN_DIM + sc8;

    bf16x8 sv = *(const bf16x8*)sg;
    gl16(rw1hp + tid * 8, Wst + tid * 16);
    gl16(rw1lp + tid * 8, Wst + 16384 + tid * 16);
    if (half) *(bf16x8*)&Xdl[0][srow][sc8] = sv;
    else      *(bf16x8*)&Xdh[0][srow][sc8] = sv;
    __syncthreads();

    // ---- layer 1
    {
        f32x4 acc[2] = {};
        for (int s = 0; s < 24; ++s) {
            const int c = s >> 2;
            const unsigned char* curh = Wst + (s & 1) * 32768;
            const unsigned char* curl = curh + 16384;
            if (s + 1 < 24) {
                unsigned char* dst = Wst + ((s + 1) & 1) * 32768;
                gl16(rw1hp + (size_t)(s + 1) * 8192 + tid * 8, dst + tid * 16);
                gl16(rw1lp + (size_t)(s + 1) * 8192 + tid * 8, dst + 16384 + tid * 16);
            } else {
                if (tid < 512) gl16(rw2hp + tid * 8, Wst + tid * 16);
                else           gl16(rw2lp + st * 8, Wst + 16384 + st * 16);
            }
            if ((s & 3) == 0 && c < 5)
                sv = *(const bf16x8*)(sg + (c + 1) * CHK);
            const ushort (*Xch)[136] = Xdh[c & 1];
            const ushort (*Xcl)[136] = Xdl[c & 1];
            const int ko = (s & 3) * 32 + lk * 8;
            bf16x8 ah0 = *(const bf16x8*)&Xch[lm][ko];
            bf16x8 al0 = *(const bf16x8*)&Xcl[lm][ko];
            bf16x8 ah1 = *(const bf16x8*)&Xch[16 + lm][ko];
            bf16x8 al1 = *(const bf16x8*)&Xcl[16 + lm][ko];
            bf16x8 bh = *(const bf16x8*)(curh + (wave * 64 + lane) * 16);
            bf16x8 bl = *(const bf16x8*)(curl + (wave * 64 + lane) * 16);
            acc[0] = mfma16(ah0, bh, acc[0]);
            acc[0] = mfma16(ah0, bl, acc[0]);
            acc[0] = mfma16(al0, bh, acc[0]);
            acc[1] = mfma16(ah1, bh, acc[1]);
            acc[1] = mfma16(ah1, bl, acc[1]);
            acc[1] = mfma16(al1, bh, acc[1]);
            if ((s & 3) == 2 && c < 5) {
                if (half) *(bf16x8*)&Xdl[(c + 1) & 1][srow][sc8] = sv;
                else      *(bf16x8*)&Xdh[(c + 1) & 1][srow][sc8] = sv;
            }
            __syncthreads();
        }
        int col = wave * 16 + lm;
        float bv = rb1[col];
        #pragma unroll
        for (int m = 0; m < 2; ++m)
            #pragma unroll
            for (int r = 0; r < 4; ++r) {
                float v = acc[m][r] + bv;
                v = v > 0.f ? v : 0.f;
                __hip_bfloat16 h = __float2bfloat16(v);
                float hf = __bfloat162float(h);
                __hip_bfloat16 l = __float2bfloat16(v - hf);
                int row = m * 16 + lk * 4 + r;
                h1hs[row][col] = *(ushort*)&h;
                h1ls[row][col] = *(ushort*)&l;
            }
    }
    __syncthreads();

    // ---- layer 2
    {
        const int mt = wave >> 3, nb = wave & 7;
        f32x4 acc2 = {};
        for (int s = 0; s < 8; ++s) {
            const unsigned char* curh = Wst + (s & 1) * 32768;
            const unsigned char* curl = curh + 16384;
            if (s + 1 < 8) {
                unsigned char* dst = Wst + ((s + 1) & 1) * 32768;
                if (tid < 512) gl16(rw2hp + (size_t)(s + 1) * 4096 + tid * 8, dst + tid * 16);
                else           gl16(rw2lp + (size_t)(s + 1) * 4096 + st * 8, dst + 16384 + st * 16);
            }
            const int ko = s * 32 + lk * 8;
            bf16x8 ah = *(const bf16x8*)&h1hs[mt * 16 + lm][ko];
            bf16x8 al = *(const bf16x8*)&h1ls[mt * 16 + lm][ko];
            bf16x8 bh = *(const bf16x8*)(curh + (nb * 64 + lane) * 16);
            bf16x8 bl = *(const bf16x8*)(curl + (nb * 64 + lane) * 16);
            acc2 = mfma16(ah, bh, acc2);
            acc2 = mfma16(ah, bl, acc2);
            acc2 = mfma16(al, bh, acc2);
            __syncthreads();
        }
        int col2 = nb * 16 + lm;
        float bv = rb2[col2];
        #pragma unroll
        for (int r = 0; r < 4; ++r) {
            float v = acc2[r] + bv;
            h2s[mt * 16 + lk * 4 + r][col2] = v > 0.f ? v : 0.f;
        }
    }
    __syncthreads();

    // ---- head
    const int o = lane >> 3, kq = lane & 7;
    #pragma unroll
    for (int i = 0; i < 2; ++i) {
        int rloc = wave * 2 + i;
        int b = r0 + rloc;
        float s = 0.f;
        #pragma unroll
        for (int q = 0; q < 4; ++q) {
            float4 hv = *(const float4*)&h2s[rloc][kq * 16 + q * 4];
            float4 wv = *(const float4*)&rW3[o * RH2 + kq * 16 + q * 4];
            s += hv.x * wv.x + hv.y * wv.y + hv.z * wv.z + hv.w * wv.w;
        }
        s += __shfl_xor(s, 1);
        s += __shfl_xor(s, 2);
        s += __shfl_xor(s, 4);
        float logit = s + rb3[o];
        float l[8];
        #pragma unroll
        for (int j = 0; j < 8; ++j) l[j] = __shfl(logit, j * 8);
        float m = l[0];
        #pragma unroll
        for (int j = 1; j < 8; ++j) m = fmaxf(m, l[j]);
        float p[8]; float sum = 0.f;
        #pragma unroll
        for (int j = 0; j < 8; ++j) { p[j] = expf(l[j] - m); sum += p[j]; }
        float inv = 1.f / sum;
        #pragma unroll
        for (int j = 0; j < 8; ++j) p[j] *= inv;
        int i1 = 0; float v1 = p[0];
        #pragma unroll
        for (int j = 1; j < 8; ++j) if (p[j] > v1) { v1 = p[j]; i1 = j; }
        int i2 = -1; float v2 = -1.f;
        #pragma unroll
        for (int j = 0; j < 8; ++j) if (j != i1 && p[j] > v2) { v2 = p[j]; i2 = j; }
        if (lane < 8) {
            router_p[(size_t)b * 8 + lane] = p[lane];
            float gv = (lane == i1) ? v1 * 0.5f : ((lane == i2) ? v2 * 0.5f : 0.f);
            gate[(size_t)b * 8 + lane] = gv;
        }
        if (lane == 0) t2[b] = i1 | (i2 << 8);
    }
    if (blockIdx.x == 0 && tid == 0) lb_out[0] = 0.f;
}

// ---------------- build dispatch lists
__global__ __launch_bounds__(256) void build_lists_kernel(
    const int* __restrict__ t2, int* __restrict__ counts, int* __restrict__ ent)
{
    __shared__ int hist[8], base[8];
    const int r = blockIdx.x * 256 + threadIdx.x;
    if (threadIdx.x < 8) hist[threadIdx.x] = 0;
    __syncthreads();
    const int v = t2[r];
    const int i1 = v & 255, i2 = v >> 8;
    const int rk1 = atomicAdd(&hist[i1], 1);
    const int rk2 = atomicAdd(&hist[i2], 1);
    __syncthreads();
    if (threadIdx.x < 8) base[threadIdx.x] = atomicAdd(&counts[threadIdx.x], hist[threadIdx.x]);
    __syncthreads();
    ent[i1 * B_ROWS + base[i1] + rk1] = (r << 1);
    ent[i2 * B_ROWS + base[i2] + rk2] = (r << 1) | 1;
}

// ---------------- sparse fused expert kernel: BM=32, 512 thr, 66.5KB LDS -> 2 blocks/CU.
// LDS: [0,32K) Wst (L1 dbuf 2x16K; L2 dbuf 2x8K in [0,16K); W3 final [0,16K))
//      A1s[32][516] at 16384 (aliases Wst buf1; written only after L1's last read)
//      A2s[32][260] at 49408 (Xd[2][32][68] aliased inside; Xd dead after L1).
__global__ __launch_bounds__(512) void expert_fused_kernel(
    const ushort* __restrict__ xh,
    const unsigned char* __restrict__ W1p8, const unsigned char* __restrict__ W2p8,
    const unsigned char* __restrict__ W3p8,
    const float* __restrict__ s1, const float* __restrict__ s2, const float* __restrict__ s3,
    const float* __restrict__ eb1, const float* __restrict__ eb2, const float* __restrict__ eb3,
    const float* __restrict__ gate,
    const int* __restrict__ counts, const int* __restrict__ ent,
    float* __restrict__ S0, float* __restrict__ S1)
{
    // balanced-affinity tile scheduler (BM=32)
    int pfx[9]; pfx[0] = 0;
    #pragma unroll
    for (int i = 0; i < 8; ++i) pfx[i + 1] = pfx[i] + ((counts[i] + 31) >> 5);
    const int T = pfx[8];
    const int R = (T + 7) >> 3;
    const int xcd = blockIdx.x & 7, j = blockIdx.x >> 3;
    if (j >= R) return;
    const int g = xcd * R + j;
    if (g >= T) return;
    int e = 0;
    #pragma unroll
    for (int i = 0; i < 7; ++i) if (g >= pfx[i + 1]) e = i + 1;
    const int t = g - pfx[e];
    const int cnt = counts[e];

    __shared__ __align__(16) unsigned char smem[66048];
    unsigned char* Wst = smem;
    __hip_bfloat16 (*A1s)[516] = (__hip_bfloat16(*)[516])(smem + 16384);
    __hip_bfloat16 (*A2s)[260] = (__hip_bfloat16(*)[260])(smem + 49408);
    ushort (*Xd)[32][68]       = (ushort(*)[32][68])(smem + 49408);
    __shared__ int rowL[32];
    __shared__ int slotL[32];
    __shared__ float gL[32];

    const int tid = threadIdx.x;
    const int wave = tid >> 6;
    const int lane = tid & 63;
    const int lm = lane & 15;
    const int lk = lane >> 4;

    if (tid < 32) {
        int idx = t * 32 + tid;
        if (idx < cnt) {
            int entv = ent[e * B_ROWS + idx];
            int r = entv >> 1;
            rowL[tid] = r;
            slotL[tid] = entv & 1;
            gL[tid] = gate[(size_t)r * NE + e];
        } else {
            rowL[tid] = -1; slotL[tid] = 0; gL[tid] = 0.f;
        }
    }
    __syncthreads();

    // X staging: 512 thr x 8B = one 32x64 chunk (CHKX=64); 12 chunks
    const int srow = tid >> 4;
    const int sc4  = (tid & 15) * 4;
    int SR = rowL[srow]; if (SR < 0) SR = 0;
    const ushort* sg = xh + (size_t)SR * IN_DIM + sc4;
    const unsigned char* Wsrc1 = W1p8 + (size_t)e * 393216;
    const unsigned char* Wsrc2 = W2p8 + (size_t)e * 131072;
    const unsigned char* Wsrc3 = W3p8 + (size_t)e * 16384;

    // prologue: X chunk 0; stage W1 step 0 (16KB = 2 gl16/thread)
    ushort4 sv = *(const ushort4*)sg;
    gl16(Wsrc1 + tid * 16, Wst + tid * 16);
    gl16(Wsrc1 + 8192 + tid * 16, Wst + 8192 + tid * 16);
    *(ushort4*)&Xd[0][srow][sc4] = sv;
    __syncthreads();

    // ---- layer 1: 24 K-steps, 16KB pair-packed image per step, dbuf
    {
        f32x4 acc[2][4] = {};
        for (int s = 0; s < 24; ++s) {
            const int c = s >> 1;
            const unsigned char* cur = Wst + (s & 1) * 16384;
            if (s + 1 < 24) {
                unsigned char* dst = Wst + ((s + 1) & 1) * 16384;
                gl16(Wsrc1 + (size_t)(s + 1) * 16384 + tid * 16, dst + tid * 16);
                gl16(Wsrc1 + (size_t)(s + 1) * 16384 + 8192 + tid * 16, dst + 8192 + tid * 16);
            } else {
                gl16(Wsrc2 + tid * 16, Wst + tid * 16);   // W2 step0 (8K) -> [0,8K)
            }
            if ((s & 1) == 0 && c < 11)
                sv = *(const ushort4*)(sg + (c + 1) * CHKX);
            const ushort (*Xc)[68] = Xd[c & 1];
            const int ko = (s & 1) * 32 + lk * 8;
            bf16x8 a0 = *(const bf16x8*)&Xc[     lm][ko];
            bf16x8 a1 = *(const bf16x8*)&Xc[16 + lm][ko];
            #pragma unroll
            for (int p = 0; p < 2; ++p) {
                uint4 pw4 = *(const uint4*)(cur + (wave * 2 + p) * 1024 + lane * 16);
                bf16x8 b0 = expand_frag(make_uint2(pw4.x, pw4.y));
                bf16x8 b1 = expand_frag(make_uint2(pw4.z, pw4.w));
                acc[0][p * 2 + 0] = mfma16(a0, b0, acc[0][p * 2 + 0]);
                acc[1][p * 2 + 0] = mfma16(a1, b0, acc[1][p * 2 + 0]);
                acc[0][p * 2 + 1] = mfma16(a0, b1, acc[0][p * 2 + 1]);
                acc[1][p * 2 + 1] = mfma16(a1, b1, acc[1][p * 2 + 1]);
            }
            if ((s & 1) == 1 && c < 11)
                *(ushort4*)&Xd[(c + 1) & 1][srow][sc4] = sv;
            __syncthreads();
        }
        const float* bias = eb1 + e * H1;
        const float sc = s1[e];
        #pragma unroll
        for (int n = 0; n < 4; ++n) {
            int ncol = (wave * 4 + n) * 16 + lm;
            float bv = bias[ncol];
            #pragma unroll
            for (int m = 0; m < 2; ++m)
                #pragma unroll
                for (int r = 0; r < 4; ++r) {
                    float v = fmaf(acc[m][n][r], sc, bv);
                    v = v > 0.f ? v : 0.f;
                    A1s[m * 16 + lk * 4 + r][ncol] = __float2bfloat16(v);
                }
        }
    }
    __syncthreads();

    // ---- layer 2: 16 K-steps, 8KB pair-packed images in [0,16K) dbuf
    {
        f32x4 acc[2][2] = {};
        for (int s = 0; s < 16; ++s) {
            const unsigned char* cur = Wst + (s & 1) * 8192;
            if (s + 1 < 16) {
                gl16(Wsrc2 + (size_t)(s + 1) * 8192 + tid * 16,
                     Wst + ((s + 1) & 1) * 8192 + tid * 16);
            } else {
                gl16(Wsrc3 + tid * 16, Wst + tid * 16);   // W3 half0 -> [0,8K)
            }
            const int ko = s * 32 + lk * 8;
            bf16x8 a0 = *(const bf16x8*)&A1s[     lm][ko];
            bf16x8 a1 = *(const bf16x8*)&A1s[16 + lm][ko];
            uint4 pw4 = *(const uint4*)(cur + wave * 1024 + lane * 16);
            bf16x8 b0 = expand_frag(make_uint2(pw4.x, pw4.y));
            bf16x8 b1 = expand_frag(make_uint2(pw4.z, pw4.w));
            acc[0][0] = mfma16(a0, b0, acc[0][0]);
            acc[1][0] = mfma16(a1, b0, acc[1][0]);
            acc[0][1] = mfma16(a0, b1, acc[0][1]);
            acc[1][1] = mfma16(a1, b1, acc[1][1]);
            __syncthreads();
        }
        // stage W3 half1 -> [8K,16K) (last read at s=15, complete after barrier)
        gl16(Wsrc3 + 8192 + tid * 16, Wst + 8192 + tid * 16);
        const float* bias = eb2 + e * H2;
        const float sc = s2[e];
        #pragma unroll
        for (int n = 0; n < 2; ++n) {
            int ncol = (wave * 2 + n) * 16 + lm;
            float bv = bias[ncol];
            #pragma unroll
            for (int m = 0; m < 2; ++m)
                #pragma unroll
                for (int r = 0; r < 4; ++r) {
                    float v = fmaf(acc[m][n][r], sc, bv);
                    v = v > 0.f ? v : 0.f;
                    A2s[m * 16 + lk * 4 + r][ncol] = __float2bfloat16(v);
                }
        }
    }
    __syncthreads();   // drains W3 half1 DMA + A2s visible

    // ---- layer 3: W3 flat panel resident at [0,16K)
    {
        const int mt = wave & 1, nt = wave >> 1;   // nt 0..3
        f32x4 acc = {};
        #pragma unroll
        for (int s = 0; s < 8; ++s) {
            bf16x8 a = *(const bf16x8*)&A2s[mt * 16 + lm][s * 32 + lk * 8];
            uint2 pw = *(const uint2*)(Wst + ((s * 4 + nt) * 64 + lane) * 8);
            bf16x8 b = expand_frag(pw);
            acc = mfma16(a, b, acc);
        }
        int col = nt * 16 + lm;
        if (col < NC) {
            const float bv = eb3[e * NC + col];
            const float sc = s3[e];
            #pragma unroll
            for (int r = 0; r < 4; ++r) {
                int row = mt * 16 + lk * 4 + r;
                int R2 = rowL[row];
                if (R2 >= 0) {
                    float v = gL[row] * fmaf(acc[r], sc, bv);
                    float* Sb = slotL[row] ? S1 : S0;
                    Sb[(size_t)R2 * 64 + col] = v;
                }
            }
        }
    }
}

// ---------------- combine
__global__ __launch_bounds__(256) void combine_kernel(
    const float* __restrict__ S0, const float* __restrict__ S1, float* __restrict__ out)
{
    int i = blockIdx.x * 256 + threadIdx.x;
    if (i < B_ROWS * NC) {
        int row = i / NC, col = i % NC;
        out[i] = S0[(size_t)row * 64 + col] + S1[(size_t)row * 64 + col];
    }
}

extern "C" void kernel_launch(void* const* d_in, const int* in_sizes, int n_in,
                              void* d_out, int out_size, void* d_ws, size_t ws_size,
                              hipStream_t stream) {
    const float* x   = (const float*)d_in[0];
    const float* rW1 = (const float*)d_in[1];
    const float* rb1 = (const float*)d_in[2];
    const float* rW2 = (const float*)d_in[3];
    const float* rb2 = (const float*)d_in[4];
    const float* rW3 = (const float*)d_in[5];
    const float* rb3 = (const float*)d_in[6];
    const float* eW1 = (const float*)d_in[7];
    const float* eb1 = (const float*)d_in[8];
    const float* eW2 = (const float*)d_in[9];
    const float* eb2 = (const float*)d_in[10];
    const float* eW3 = (const float*)d_in[11];
    const float* eb3 = (const float*)d_in[12];

    float* out_main = (float*)d_out;
    float* router_p = out_main + (size_t)B_ROWS * NC;
    float* lb_out   = router_p + (size_t)B_ROWS * NE;

    char* ws = (char*)d_ws;
    size_t off = 0;
    unsigned char* W1p8 = (unsigned char*)(ws + off); off += (size_t)NE * 49152 * 8;
    unsigned char* W2p8 = (unsigned char*)(ws + off); off += (size_t)NE * 16384 * 8;
    unsigned char* W3p8 = (unsigned char*)(ws + off); off += (size_t)NE * 2048 * 8;
    ushort* xh  = (ushort*)(ws + off); off += (size_t)B_ROWS * IN_DIM * 2;
    ushort* xl  = (ushort*)(ws + off); off += (size_t)B_ROWS * IN_DIM * 2;
    float* S0   = (float*)(ws + off);  off += (size_t)B_ROWS * 64 * 4;
    float* S1   = (float*)(ws + off);  off += (size_t)B_ROWS * 64 * 4;
    ushort* rw1hp = (ushort*)(ws + off); off += (size_t)24576 * 8 * 2;
    ushort* rw1lp = (ushort*)(ws + off); off += (size_t)24576 * 8 * 2;
    ushort* rw2hp = (ushort*)(ws + off); off += (size_t)4096 * 8 * 2;
    ushort* rw2lp = (ushort*)(ws + off); off += (size_t)4096 * 8 * 2;
    float* gate = (float*)(ws + off);  off += (size_t)B_ROWS * NE * 4;
    int*   ent  = (int*)(ws + off);    off += (size_t)NE * B_ROWS * 4;
    int*   t2   = (int*)(ws + off);    off += (size_t)B_ROWS * 4;
    int* counts = (int*)(ws + off);    off += 256;
    float* s1   = (float*)(ws + off);  off += 256;
    float* s2   = (float*)(ws + off);  off += 256;
    float* s3   = (float*)(ws + off);  off += 256;
    float* p1   = (float*)(ws + off);  off += NE * 96 * 4;
    float* p2   = (float*)(ws + off);  off += NE * 32 * 4;
    float* p3   = (float*)(ws + off);  off += NE * 4 * 4;

    // 1) prep
    pack_absum_kernel<<<dim3(96, 24), 512, 0, stream>>>(
        eW1, eW2, eW3, W1p8, W2p8, W3p8, p1, p2, p3);
    pack_router_kernel<<<56, 512, 0, stream>>>(rW1, rw1hp, rw1lp, rW2, rw2hp, rw2lp);
    decomp_x_kernel<<<3072, 256, 0, stream>>>(x, xh, xl);
    finalize_scales_kernel<<<1, 64, 0, stream>>>(p1, p2, p3, s1, s2, s3, counts);

    // 2) fused router
    router_fused_kernel<<<B_ROWS / 32, 1024, 0, stream>>>(
        xh, xl, rw1hp, rw1lp, rb1, rw2hp, rw2lp, rb2, rW3, rb3, router_p, gate, lb_out, t2);
    build_lists_kernel<<<B_ROWS / 256, 256, 0, stream>>>(t2, counts, ent);

    // 3) sparse fused experts (BM=32, 2 blocks/CU) + combine
    expert_fused_kernel<<<2048, 512, 0, stream>>>(
        xh, W1p8, W2p8, W3p8, s1, s2, s3, eb1, eb2, eb3, gate, counts, ent, S0, S1);
    combine_kernel<<<(B_ROWS * NC + 255) / 256, 256, 0, stream>>>(S0, S1, out_main);
}

// Round 19
// 169.857 us; speedup vs baseline: 1.3652x; 1.3652x over previous
//
#include <hip/hip_runtime.h>
#include <hip/hip_bf16.h>

typedef __attribute__((ext_vector_type(4))) float f32x4;
typedef __attribute__((ext_vector_type(8))) short bf16x8;

#define B_ROWS 16384
#define IN_DIM 768
#define H1 512
#define H2 256
#define NC 50
#define NE 8
#define RH1 256
#define RH2 128
#define W1_STEPS 24
#define W2_STEPS 16
#define CHK 128
#define CHKX 64

static __device__ __forceinline__ f32x4 mfma16(bf16x8 a, bf16x8 b, f32x4 c) {
    return __builtin_amdgcn_mfma_f32_16x16x32_bf16(a, b, c, 0, 0, 0);
}

typedef __attribute__((address_space(1))) const unsigned int gas_u32;
typedef __attribute__((address_space(3))) unsigned int las_u32;
static __device__ __forceinline__ void gl16(const void* g, void* l) {
    __builtin_amdgcn_global_load_lds((gas_u32*)g, (las_u32*)l, 16, 0, 0);
}

// expand 8 ternary byte-codes (bf16 high byte: 0x3F/0xBF/0x00) to exact bf16x8
static __device__ __forceinline__ bf16x8 expand_frag(uint2 pw) {
    unsigned q0 = (pw.x & 0x01010101u) << 7;
    unsigned q1 = (pw.y & 0x01010101u) << 7;
    union { unsigned u[4]; bf16x8 v; } r;
    r.u[0] = __builtin_amdgcn_perm(pw.x, q0, 0x05010400u);
    r.u[1] = __builtin_amdgcn_perm(pw.x, q0, 0x07030602u);
    r.u[2] = __builtin_amdgcn_perm(pw.y, q1, 0x05010400u);
    r.u[3] = __builtin_amdgcn_perm(pw.y, q1, 0x07030602u);
    return r.v;
}

// ---------------- merged ternarize+pack+abs-sum: grid (96, 24), 512 thr.
// W1/W2: PAIR layout — frags (2p,2p+1) adjacent 16B per lane. W3: flat layout.
__global__ __launch_bounds__(512) void pack_absum_kernel(
    const float* __restrict__ eW1, const float* __restrict__ eW2, const float* __restrict__ eW3,
    unsigned char* __restrict__ W1p8, unsigned char* __restrict__ W2p8,
    unsigned char* __restrict__ W3p8,
    float* __restrict__ p1, float* __restrict__ p2, float* __restrict__ p3)
{
    const int mat = blockIdx.y >> 3, e = blockIdx.y & 7;
    const int u = blockIdx.x * 512 + threadIdx.x;
    const float* src; unsigned char* dst; int valid = 1; float* P; int np;
    if (mat == 0) {
        int lane = u & 63, nblk = (u >> 6) & 31, ks = u >> 11;
        int n = nblk * 16 + (lane & 15), k = ks * 32 + (lane >> 4) * 8;
        src = eW1 + ((size_t)e * H1 + n) * IN_DIM + k;
        dst = W1p8 + (size_t)e * 393216
            + (size_t)ks * 16384 + (nblk >> 1) * 1024 + lane * 16 + (nblk & 1) * 8;
        P = p1; np = 96;
    } else if (mat == 1) {
        if (u >= 16384) return;
        int lane = u & 63, nblk = (u >> 6) & 15, ks = u >> 10;
        int n = nblk * 16 + (lane & 15), k = ks * 32 + (lane >> 4) * 8;
        src = eW2 + ((size_t)e * H2 + n) * H1 + k;
        dst = W2p8 + (size_t)e * 131072
            + (size_t)ks * 8192 + (nblk >> 1) * 1024 + lane * 16 + (nblk & 1) * 8;
        P = p2; np = 32;
    } else {
        if (u >= 2048) return;
        int lane = u & 63, nblk = (u >> 6) & 3, ks = u >> 8;
        int n = nblk * 16 + (lane & 15), k = ks * 32 + (lane >> 4) * 8;
        valid = (n < NC);
        src = eW3 + ((size_t)e * NC + (valid ? n : 0)) * H2 + k;
        dst = W3p8 + ((size_t)e * 2048 + u) * 8;
        P = p3; np = 4;
    }
    unsigned lo = 0, hi = 0;
    float s = 0.f;
    #pragma unroll
    for (int j = 0; j < 4; ++j) {
        float w = valid ? src[j] : 0.f;
        s += fabsf(w);
        unsigned c = (fabsf(w) > 0.05f) ? (w > 0.f ? 0x3Fu : 0xBFu) : 0u;
        lo |= c << (8 * j);
    }
    #pragma unroll
    for (int j = 0; j < 4; ++j) {
        float w = valid ? src[4 + j] : 0.f;
        s += fabsf(w);
        unsigned c = (fabsf(w) > 0.05f) ? (w > 0.f ? 0x3Fu : 0xBFu) : 0u;
        hi |= c << (8 * j);
    }
    *(uint2*)dst = make_uint2(lo, hi);
    const int lane = threadIdx.x & 63, wave = threadIdx.x >> 6;
    #pragma unroll
    for (int o = 32; o; o >>= 1) s += __shfl_down(s, o);
    __shared__ float red[8];
    if (lane == 0) red[wave] = s;
    __syncthreads();
    if (threadIdx.x == 0) {
        float t = 0.f;
        #pragma unroll
        for (int i = 0; i < 8; ++i) t += red[i];
        P[e * np + blockIdx.x] = t;
    }
}

// ---------------- finalize scales + zero dispatch counts
__global__ __launch_bounds__(64) void finalize_scales_kernel(
    const float* __restrict__ p1, const float* __restrict__ p2, const float* __restrict__ p3,
    float* __restrict__ s1, float* __restrict__ s2, float* __restrict__ s3,
    int* __restrict__ counts)
{
    int t = threadIdx.x;
    if (t < 8) {
        float a = 0.f;
        for (int i = 0; i < 96; ++i) a += p1[t * 96 + i];
        s1[t] = a / (float)(H1 * IN_DIM);
    } else if (t < 16) {
        int e = t - 8; float a = 0.f;
        for (int i = 0; i < 32; ++i) a += p2[e * 32 + i];
        s2[e] = a / (float)(H2 * H1);
    } else if (t < 24) {
        int e = t - 16; float a = 0.f;
        for (int i = 0; i < 4; ++i) a += p3[e * 4 + i];
        s3[e] = a / (float)(NC * H2);
    } else if (t < 32) {
        counts[t - 24] = 0;
    }
}

// ---------------- pack router weights into fragment-order hi/lo images
__global__ __launch_bounds__(512) void pack_router_kernel(
    const float* __restrict__ rW1, ushort* __restrict__ rw1hp, ushort* __restrict__ rw1lp,
    const float* __restrict__ rW2, ushort* __restrict__ rw2hp, ushort* __restrict__ rw2lp)
{
    int u = blockIdx.x * 512 + threadIdx.x;
    const float* src; ushort* dh; ushort* dl;
    if (u < 24576) {
        int lane = u & 63, nblk = (u >> 6) & 15, ks = u >> 10;
        int n = nblk * 16 + (lane & 15), k = ks * 32 + (lane >> 4) * 8;
        src = rW1 + (size_t)n * IN_DIM + k;
        dh = rw1hp + (size_t)u * 8; dl = rw1lp + (size_t)u * 8;
    } else {
        int v = u - 24576;
        if (v >= 4096) return;
        int lane = v & 63, nblk = (v >> 6) & 7, ks = v >> 9;
        int n = nblk * 16 + (lane & 15), k = ks * 32 + (lane >> 4) * 8;
        src = rW2 + (size_t)n * RH1 + k;
        dh = rw2hp + (size_t)v * 8; dl = rw2lp + (size_t)v * 8;
    }
    ushort oh[8], ol[8];
    #pragma unroll
    for (int j = 0; j < 8; ++j) {
        float w = src[j];
        __hip_bfloat16 h = __float2bfloat16(w);
        float hf = __bfloat162float(h);
        __hip_bfloat16 l = __float2bfloat16(w - hf);
        oh[j] = *(ushort*)&h; ol[j] = *(ushort*)&l;
    }
    ((ushort4*)dh)[0] = make_ushort4(oh[0], oh[1], oh[2], oh[3]);
    ((ushort4*)dh)[1] = make_ushort4(oh[4], oh[5], oh[6], oh[7]);
    ((ushort4*)dl)[0] = make_ushort4(ol[0], ol[1], ol[2], ol[3]);
    ((ushort4*)dl)[1] = make_ushort4(ol[4], ol[5], ol[6], ol[7]);
}

// ---------------- x hi/lo decomposition (3072 blocks)
__global__ __launch_bounds__(256) void decomp_x_kernel(
    const float* __restrict__ x, ushort* __restrict__ xh, ushort* __restrict__ xl)
{
    const float4* in = (const float4*)x;
    ushort4* hi = (ushort4*)xh;
    ushort4* lo = (ushort4*)xl;
    const int base = blockIdx.x * 1024;
    #pragma unroll
    for (int j = 0; j < 4; ++j) {
        int i = base + j * 256 + threadIdx.x;
        float4 v = in[i];
        float vv[4] = {v.x, v.y, v.z, v.w};
        ushort ho[4], lo4[4];
        #pragma unroll
        for (int q = 0; q < 4; ++q) {
            __hip_bfloat16 h = __float2bfloat16(vv[q]);
            float hf = __bfloat162float(h);
            __hip_bfloat16 l = __float2bfloat16(vv[q] - hf);
            ho[q] = *(ushort*)&h; lo4[q] = *(ushort*)&l;
        }
        hi[i] = make_ushort4(ho[0], ho[1], ho[2], ho[3]);
        lo[i] = make_ushort4(lo4[0], lo4[1], lo4[2], lo4[3]);
    }
}

// ---------------- fused router, 1024 threads
__global__ __launch_bounds__(1024) void router_fused_kernel(
    const ushort* __restrict__ xh, const ushort* __restrict__ xl,
    const ushort* __restrict__ rw1hp, const ushort* __restrict__ rw1lp, const float* __restrict__ rb1,
    const ushort* __restrict__ rw2hp, const ushort* __restrict__ rw2lp, const float* __restrict__ rb2,
    const float* __restrict__ rW3, const float* __restrict__ rb3,
    float* __restrict__ router_p, float* __restrict__ gate,
    float* __restrict__ lb_out, int* __restrict__ t2)
{
    __shared__ __align__(16) unsigned char smem[134144];
    unsigned char* Wst = smem;
    ushort (*Xdh)[32][136] = (ushort(*)[32][136])(smem + 65536);
    ushort (*Xdl)[32][136] = (ushort(*)[32][136])(smem + 65536 + 17408);
    float (*h2s)[132]      = (float(*)[132])(smem + 65536);
    ushort (*h1hs)[264]    = (ushort(*)[264])(smem + 100352);
    ushort (*h1ls)[264]    = (ushort(*)[264])(smem + 117248);

    const int tid = threadIdx.x, wave = tid >> 6, lane = tid & 63;
    const int lm = lane & 15, lk = lane >> 4;
    const int r0 = blockIdx.x * 32;

    const int half = tid >> 9;
    const int st   = tid & 511;
    const int srow = st >> 4;
    const int sc8  = (st & 15) * 8;
    const ushort* sg = (half ? xl : xh) + (size_t)(r0 + srow) * IN_DIM + sc8;

    bf16x8 sv = *(const bf16x8*)sg;
    gl16(rw1hp + tid * 8, Wst + tid * 16);
    gl16(rw1lp + tid * 8, Wst + 16384 + tid * 16);
    if (half) *(bf16x8*)&Xdl[0][srow][sc8] = sv;
    else      *(bf16x8*)&Xdh[0][srow][sc8] = sv;
    __syncthreads();

    // ---- layer 1
    {
        f32x4 acc[2] = {};
        for (int s = 0; s < 24; ++s) {
            const int c = s >> 2;
            const unsigned char* curh = Wst + (s & 1) * 32768;
            const unsigned char* curl = curh + 16384;
            if (s + 1 < 24) {
                unsigned char* dst = Wst + ((s + 1) & 1) * 32768;
                gl16(rw1hp + (size_t)(s + 1) * 8192 + tid * 8, dst + tid * 16);
                gl16(rw1lp + (size_t)(s + 1) * 8192 + tid * 8, dst + 16384 + tid * 16);
            } else {
                if (tid < 512) gl16(rw2hp + tid * 8, Wst + tid * 16);
                else           gl16(rw2lp + st * 8, Wst + 16384 + st * 16);
            }
            if ((s & 3) == 0 && c < 5)
                sv = *(const bf16x8*)(sg + (c + 1) * CHK);
            const ushort (*Xch)[136] = Xdh[c & 1];
            const ushort (*Xcl)[136] = Xdl[c & 1];
            const int ko = (s & 3) * 32 + lk * 8;
            bf16x8 ah0 = *(const bf16x8*)&Xch[lm][ko];
            bf16x8 al0 = *(const bf16x8*)&Xcl[lm][ko];
            bf16x8 ah1 = *(const bf16x8*)&Xch[16 + lm][ko];
            bf16x8 al1 = *(const bf16x8*)&Xcl[16 + lm][ko];
            bf16x8 bh = *(const bf16x8*)(curh + (wave * 64 + lane) * 16);
            bf16x8 bl = *(const bf16x8*)(curl + (wave * 64 + lane) * 16);
            acc[0] = mfma16(ah0, bh, acc[0]);
            acc[0] = mfma16(ah0, bl, acc[0]);
            acc[0] = mfma16(al0, bh, acc[0]);
            acc[1] = mfma16(ah1, bh, acc[1]);
            acc[1] = mfma16(ah1, bl, acc[1]);
            acc[1] = mfma16(al1, bh, acc[1]);
            if ((s & 3) == 2 && c < 5) {
                if (half) *(bf16x8*)&Xdl[(c + 1) & 1][srow][sc8] = sv;
                else      *(bf16x8*)&Xdh[(c + 1) & 1][srow][sc8] = sv;
            }
            __syncthreads();
        }
        int col = wave * 16 + lm;
        float bv = rb1[col];
        #pragma unroll
        for (int m = 0; m < 2; ++m)
            #pragma unroll
            for (int r = 0; r < 4; ++r) {
                float v = acc[m][r] + bv;
                v = v > 0.f ? v : 0.f;
                __hip_bfloat16 h = __float2bfloat16(v);
                float hf = __bfloat162float(h);
                __hip_bfloat16 l = __float2bfloat16(v - hf);
                int row = m * 16 + lk * 4 + r;
                h1hs[row][col] = *(ushort*)&h;
                h1ls[row][col] = *(ushort*)&l;
            }
    }
    __syncthreads();

    // ---- layer 2
    {
        const int mt = wave >> 3, nb = wave & 7;
        f32x4 acc2 = {};
        for (int s = 0; s < 8; ++s) {
            const unsigned char* curh = Wst + (s & 1) * 32768;
            const unsigned char* curl = curh + 16384;
            if (s + 1 < 8) {
                unsigned char* dst = Wst + ((s + 1) & 1) * 32768;
                if (tid < 512) gl16(rw2hp + (size_t)(s + 1) * 4096 + tid * 8, dst + tid * 16);
                else           gl16(rw2lp + (size_t)(s + 1) * 4096 + st * 8, dst + 16384 + st * 16);
            }
            const int ko = s * 32 + lk * 8;
            bf16x8 ah = *(const bf16x8*)&h1hs[mt * 16 + lm][ko];
            bf16x8 al = *(const bf16x8*)&h1ls[mt * 16 + lm][ko];
            bf16x8 bh = *(const bf16x8*)(curh + (nb * 64 + lane) * 16);
            bf16x8 bl = *(const bf16x8*)(curl + (nb * 64 + lane) * 16);
            acc2 = mfma16(ah, bh, acc2);
            acc2 = mfma16(ah, bl, acc2);
            acc2 = mfma16(al, bh, acc2);
            __syncthreads();
        }
        int col2 = nb * 16 + lm;
        float bv = rb2[col2];
        #pragma unroll
        for (int r = 0; r < 4; ++r) {
            float v = acc2[r] + bv;
            h2s[mt * 16 + lk * 4 + r][col2] = v > 0.f ? v : 0.f;
        }
    }
    __syncthreads();

    // ---- head
    const int o = lane >> 3, kq = lane & 7;
    #pragma unroll
    for (int i = 0; i < 2; ++i) {
        int rloc = wave * 2 + i;
        int b = r0 + rloc;
        float s = 0.f;
        #pragma unroll
        for (int q = 0; q < 4; ++q) {
            float4 hv = *(const float4*)&h2s[rloc][kq * 16 + q * 4];
            float4 wv = *(const float4*)&rW3[o * RH2 + kq * 16 + q * 4];
            s += hv.x * wv.x + hv.y * wv.y + hv.z * wv.z + hv.w * wv.w;
        }
        s += __shfl_xor(s, 1);
        s += __shfl_xor(s, 2);
        s += __shfl_xor(s, 4);
        float logit = s + rb3[o];
        float l[8];
        #pragma unroll
        for (int j = 0; j < 8; ++j) l[j] = __shfl(logit, j * 8);
        float m = l[0];
        #pragma unroll
        for (int j = 1; j < 8; ++j) m = fmaxf(m, l[j]);
        float p[8]; float sum = 0.f;
        #pragma unroll
        for (int j = 0; j < 8; ++j) { p[j] = expf(l[j] - m); sum += p[j]; }
        float inv = 1.f / sum;
        #pragma unroll
        for (int j = 0; j < 8; ++j) p[j] *= inv;
        int i1 = 0; float v1 = p[0];
        #pragma unroll
        for (int j = 1; j < 8; ++j) if (p[j] > v1) { v1 = p[j]; i1 = j; }
        int i2 = -1; float v2 = -1.f;
        #pragma unroll
        for (int j = 0; j < 8; ++j) if (j != i1 && p[j] > v2) { v2 = p[j]; i2 = j; }
        if (lane < 8) {
            router_p[(size_t)b * 8 + lane] = p[lane];
            float gv = (lane == i1) ? v1 * 0.5f : ((lane == i2) ? v2 * 0.5f : 0.f);
            gate[(size_t)b * 8 + lane] = gv;
        }
        if (lane == 0) t2[b] = i1 | (i2 << 8);
    }
    if (blockIdx.x == 0 && tid == 0) lb_out[0] = 0.f;
}

// ---------------- build dispatch lists
__global__ __launch_bounds__(256) void build_lists_kernel(
    const int* __restrict__ t2, int* __restrict__ counts, int* __restrict__ ent)
{
    __shared__ int hist[8], base[8];
    const int r = blockIdx.x * 256 + threadIdx.x;
    if (threadIdx.x < 8) hist[threadIdx.x] = 0;
    __syncthreads();
    const int v = t2[r];
    const int i1 = v & 255, i2 = v >> 8;
    const int rk1 = atomicAdd(&hist[i1], 1);
    const int rk2 = atomicAdd(&hist[i2], 1);
    __syncthreads();
    if (threadIdx.x < 8) base[threadIdx.x] = atomicAdd(&counts[threadIdx.x], hist[threadIdx.x]);
    __syncthreads();
    ent[i1 * B_ROWS + base[i1] + rk1] = (r << 1);
    ent[i2 * B_ROWS + base[i2] + rk2] = (r << 1) | 1;
}

// ---------------- sparse fused expert kernel (R17 best): BM=64, 1024 thr, balanced
// affinity, 2 K-steps per barrier in L1 (12 intervals), pair-packed W b128 reads.
__global__ __launch_bounds__(1024) void expert_fused_kernel(
    const ushort* __restrict__ xh,
    const unsigned char* __restrict__ W1p8, const unsigned char* __restrict__ W2p8,
    const unsigned char* __restrict__ W3p8,
    const float* __restrict__ s1, const float* __restrict__ s2, const float* __restrict__ s3,
    const float* __restrict__ eb1, const float* __restrict__ eb2, const float* __restrict__ eb3,
    const float* __restrict__ gate,
    const int* __restrict__ counts, const int* __restrict__ ent,
    float* __restrict__ S0, float* __restrict__ S1)
{
    int pfx[9]; pfx[0] = 0;
    #pragma unroll
    for (int i = 0; i < 8; ++i) pfx[i + 1] = pfx[i] + ((counts[i] + 63) >> 6);
    const int T = pfx[8];
    const int R = (T + 7) >> 3;
    const int xcd = blockIdx.x & 7, j = blockIdx.x >> 3;
    if (j >= R) return;
    const int g = xcd * R + j;
    if (g >= T) return;
    int e = 0;
    #pragma unroll
    for (int i = 0; i < 7; ++i) if (g >= pfx[i + 1]) e = i + 1;
    const int t = g - pfx[e];
    const int cnt = counts[e];

    __shared__ __align__(16) unsigned char smem[151552];
    unsigned char* Wst = smem;
    __hip_bfloat16 (*A2s)[264] = (__hip_bfloat16(*)[264])(smem + 32768);
    __hip_bfloat16 (*A1s)[520] = (__hip_bfloat16(*)[520])(smem + 66560);
    ushort (*Xd)[64][72]       = (ushort(*)[64][72])(smem + 133120);
    __shared__ int rowL[64];
    __shared__ int slotL[64];
    __shared__ float gL[64];

    const int tid = threadIdx.x;
    const int wave = tid >> 6;
    const int lane = tid & 63;
    const int lm = lane & 15;
    const int lk = lane >> 4;

    if (tid < 64) {
        int idx = t * 64 + tid;
        if (idx < cnt) {
            int entv = ent[e * B_ROWS + idx];
            int r = entv >> 1;
            rowL[tid] = r;
            slotL[tid] = entv & 1;
            gL[tid] = gate[(size_t)r * NE + e];
        } else {
            rowL[tid] = -1; slotL[tid] = 0; gL[tid] = 0.f;
        }
    }
    __syncthreads();

    const int srow = tid >> 4;
    const int sc4  = (tid & 15) * 4;
    int SR = rowL[srow]; if (SR < 0) SR = 0;
    const ushort* sg = xh + (size_t)SR * IN_DIM + sc4;
    const unsigned char* Wsrc1 = W1p8 + (size_t)e * 393216;
    const unsigned char* Wsrc2 = W2p8 + (size_t)e * 131072;
    const unsigned char* Wsrc3 = W3p8 + (size_t)e * 16384;

    ushort4 sv = *(const ushort4*)sg;
    gl16(Wsrc1 + tid * 16, Wst + tid * 16);
    gl16(Wsrc1 + 16384 + tid * 16, Wst + 16384 + tid * 16);
    *(ushort4*)&Xd[0][srow][sc4] = sv;
    __syncthreads();

    // ---- layer 1: 12 intervals x 2 K-steps
    {
        f32x4 acc[4][2] = {};
        const int w2 = wave * 2;
        for (int i = 0; i < 12; ++i) {
            const unsigned char* buf = Wst + (i & 1) * 32768;
            if (i + 1 < 12) {
                unsigned char* dst = Wst + ((i + 1) & 1) * 32768;
                gl16(Wsrc1 + (size_t)(i + 1) * 32768 + tid * 16, dst + tid * 16);
                gl16(Wsrc1 + (size_t)(i + 1) * 32768 + 16384 + tid * 16, dst + 16384 + tid * 16);
            } else if (tid < 512) {
                gl16(Wsrc2 + tid * 16, Wst + tid * 16);
            }
            if (i + 1 < 12) sv = *(const ushort4*)(sg + (i + 1) * CHKX);
            const ushort (*Xc)[72] = Xd[i & 1];
            #pragma unroll
            for (int k2 = 0; k2 < 2; ++k2) {
                const unsigned char* cur = buf + k2 * 16384;
                const int ko = k2 * 32 + lk * 8;
                bf16x8 a0 = *(const bf16x8*)&Xc[     lm][ko];
                bf16x8 a1 = *(const bf16x8*)&Xc[16 + lm][ko];
                bf16x8 a2 = *(const bf16x8*)&Xc[32 + lm][ko];
                bf16x8 a3 = *(const bf16x8*)&Xc[48 + lm][ko];
                uint4 pw4 = *(const uint4*)(cur + wave * 1024 + lane * 16);
                bf16x8 b0 = expand_frag(make_uint2(pw4.x, pw4.y));
                bf16x8 b1 = expand_frag(make_uint2(pw4.z, pw4.w));
                acc[0][0] = mfma16(a0, b0, acc[0][0]);
                acc[1][0] = mfma16(a1, b0, acc[1][0]);
                acc[2][0] = mfma16(a2, b0, acc[2][0]);
                acc[3][0] = mfma16(a3, b0, acc[3][0]);
                acc[0][1] = mfma16(a0, b1, acc[0][1]);
                acc[1][1] = mfma16(a1, b1, acc[1][1]);
                acc[2][1] = mfma16(a2, b1, acc[2][1]);
                acc[3][1] = mfma16(a3, b1, acc[3][1]);
            }
            if (i + 1 < 12) *(ushort4*)&Xd[(i + 1) & 1][srow][sc4] = sv;
            __syncthreads();
        }
        const float* bias = eb1 + e * H1;
        const float sc = s1[e];
        #pragma unroll
        for (int n = 0; n < 2; ++n) {
            int ncol = (w2 + n) * 16 + lm;
            float bv = bias[ncol];
            #pragma unroll
            for (int m = 0; m < 4; ++m)
                #pragma unroll
                for (int r = 0; r < 4; ++r) {
                    float v = fmaf(acc[m][n][r], sc, bv);
                    v = v > 0.f ? v : 0.f;
                    A1s[m * 16 + lk * 4 + r][ncol] = __float2bfloat16(v);
                }
        }
    }
    __syncthreads();

    // ---- layer 2: 16 K-steps, 8KB pair-packed images at Wst + (s&1)*8192
    {
        const int mt = wave >> 3, ntw = wave & 7;
        f32x4 acc[2][2] = {};
        for (int s = 0; s < W2_STEPS; ++s) {
            const unsigned char* cur = Wst + (s & 1) * 8192;
            if (s + 1 < W2_STEPS) {
                if (tid < 512)
                    gl16(Wsrc2 + (size_t)(s + 1) * 8192 + tid * 16,
                         Wst + ((s + 1) & 1) * 8192 + tid * 16);
            } else {
                gl16(Wsrc3 + tid * 16, Wst + 16384 + tid * 16);
            }
            const int ko = s * 32 + lk * 8;
            bf16x8 a0 = *(const bf16x8*)&A1s[mt * 32 +      lm][ko];
            bf16x8 a1 = *(const bf16x8*)&A1s[mt * 32 + 16 + lm][ko];
            uint4 pw4 = *(const uint4*)(cur + ntw * 1024 + lane * 16);
            bf16x8 b0 = expand_frag(make_uint2(pw4.x, pw4.y));
            bf16x8 b1 = expand_frag(make_uint2(pw4.z, pw4.w));
            acc[0][0] = mfma16(a0, b0, acc[0][0]);
            acc[1][0] = mfma16(a1, b0, acc[1][0]);
            acc[0][1] = mfma16(a0, b1, acc[0][1]);
            acc[1][1] = mfma16(a1, b1, acc[1][1]);
            __syncthreads();
        }
        const float* bias = eb2 + e * H2;
        const float sc = s2[e];
        #pragma unroll
        for (int n = 0; n < 2; ++n) {
            int ncol = (ntw * 2 + n) * 16 + lm;
            float bv = bias[ncol];
            #pragma unroll
            for (int m = 0; m < 2; ++m)
                #pragma unroll
                for (int r = 0; r < 4; ++r) {
                    float v = fmaf(acc[m][n][r], sc, bv);
                    v = v > 0.f ? v : 0.f;
                    A2s[mt * 32 + m * 16 + lk * 4 + r][ncol] = __float2bfloat16(v);
                }
        }
    }
    __syncthreads();

    // ---- layer 3: W3 flat panel resident at Wst+16384
    {
        const int mt = wave & 3, nt = wave >> 2;
        f32x4 acc = {};
        #pragma unroll
        for (int s = 0; s < 8; ++s) {
            bf16x8 a = *(const bf16x8*)&A2s[mt * 16 + lm][s * 32 + lk * 8];
            uint2 pw = *(const uint2*)(Wst + 16384 + ((s * 4 + nt) * 64 + lane) * 8);
            bf16x8 b = expand_frag(pw);
            acc = mfma16(a, b, acc);
        }
        int col = nt * 16 + lm;
        if (col < NC) {
            const float bv = eb3[e * NC + col];
            const float sc = s3[e];
            #pragma unroll
            for (int r = 0; r < 4; ++r) {
                int row = mt * 16 + lk * 4 + r;
                int R2 = rowL[row];
                if (R2 >= 0) {
                    float v = gL[row] * fmaf(acc[r], sc, bv);
                    float* Sb = slotL[row] ? S1 : S0;
                    Sb[(size_t)R2 * 64 + col] = v;
                }
            }
        }
    }
}

// ---------------- combine
__global__ __launch_bounds__(256) void combine_kernel(
    const float* __restrict__ S0, const float* __restrict__ S1, float* __restrict__ out)
{
    int i = blockIdx.x * 256 + threadIdx.x;
    if (i < B_ROWS * NC) {
        int row = i / NC, col = i % NC;
        out[i] = S0[(size_t)row * 64 + col] + S1[(size_t)row * 64 + col];
    }
}

extern "C" void kernel_launch(void* const* d_in, const int* in_sizes, int n_in,
                              void* d_out, int out_size, void* d_ws, size_t ws_size,
                              hipStream_t stream) {
    const float* x   = (const float*)d_in[0];
    const float* rW1 = (const float*)d_in[1];
    const float* rb1 = (const float*)d_in[2];
    const float* rW2 = (const float*)d_in[3];
    const float* rb2 = (const float*)d_in[4];
    const float* rW3 = (const float*)d_in[5];
    const float* rb3 = (const float*)d_in[6];
    const float* eW1 = (const float*)d_in[7];
    const float* eb1 = (const float*)d_in[8];
    const float* eW2 = (const float*)d_in[9];
    const float* eb2 = (const float*)d_in[10];
    const float* eW3 = (const float*)d_in[11];
    const float* eb3 = (const float*)d_in[12];

    float* out_main = (float*)d_out;
    float* router_p = out_main + (size_t)B_ROWS * NC;
    float* lb_out   = router_p + (size_t)B_ROWS * NE;

    char* ws = (char*)d_ws;
    size_t off = 0;
    unsigned char* W1p8 = (unsigned char*)(ws + off); off += (size_t)NE * 49152 * 8;
    unsigned char* W2p8 = (unsigned char*)(ws + off); off += (size_t)NE * 16384 * 8;
    unsigned char* W3p8 = (unsigned char*)(ws + off); off += (size_t)NE * 2048 * 8;
    ushort* xh  = (ushort*)(ws + off); off += (size_t)B_ROWS * IN_DIM * 2;
    ushort* xl  = (ushort*)(ws + off); off += (size_t)B_ROWS * IN_DIM * 2;
    float* S0   = (float*)(ws + off);  off += (size_t)B_ROWS * 64 * 4;
    float* S1   = (float*)(ws + off);  off += (size_t)B_ROWS * 64 * 4;
    ushort* rw1hp = (ushort*)(ws + off); off += (size_t)24576 * 8 * 2;
    ushort* rw1lp = (ushort*)(ws + off); off += (size_t)24576 * 8 * 2;
    ushort* rw2hp = (ushort*)(ws + off); off += (size_t)4096 * 8 * 2;
    ushort* rw2lp = (ushort*)(ws + off); off += (size_t)4096 * 8 * 2;
    float* gate = (float*)(ws + off);  off += (size_t)B_ROWS * NE * 4;
    int*   ent  = (int*)(ws + off);    off += (size_t)NE * B_ROWS * 4;
    int*   t2   = (int*)(ws + off);    off += (size_t)B_ROWS * 4;
    int* counts = (int*)(ws + off);    off += 256;
    float* s1   = (float*)(ws + off);  off += 256;
    float* s2   = (float*)(ws + off);  off += 256;
    float* s3   = (float*)(ws + off);  off += 256;
    float* p1   = (float*)(ws + off);  off += NE * 96 * 4;
    float* p2   = (float*)(ws + off);  off += NE * 32 * 4;
    float* p3   = (float*)(ws + off);  off += NE * 4 * 4;

    // 1) prep
    pack_absum_kernel<<<dim3(96, 24), 512, 0, stream>>>(
        eW1, eW2, eW3, W1p8, W2p8, W3p8, p1, p2, p3);
    pack_router_kernel<<<56, 512, 0, stream>>>(rW1, rw1hp, rw1lp, rW2, rw2hp, rw2lp);
    decomp_x_kernel<<<3072, 256, 0, stream>>>(x, xh, xl);
    finalize_scales_kernel<<<1, 64, 0, stream>>>(p1, p2, p3, s1, s2, s3, counts);

    // 2) fused router
    router_fused_kernel<<<B_ROWS / 32, 1024, 0, stream>>>(
        xh, xl, rw1hp, rw1lp, rb1, rw2hp, rw2lp, rb2, rW3, rb3, router_p, gate, lb_out, t2);
    build_lists_kernel<<<B_ROWS / 256, 256, 0, stream>>>(t2, counts, ent);

    // 3) sparse fused experts (R17 best: 2-step intervals, pair-packed W) + combine
    expert_fused_kernel<<<1024, 1024, 0, stream>>>(
        xh, W1p8, W2p8, W3p8, s1, s2, s3, eb1, eb2, eb3, gate, counts, ent, S0, S1);
    combine_kernel<<<(B_ROWS * NC + 255) / 256, 256, 0, stream>>>(S0, S1, out_main);
}

// Round 20
// 164.567 us; speedup vs baseline: 1.4091x; 1.0321x over previous
//
#include <hip/hip_runtime.h>
#include <hip/hip_bf16.h>

typedef __attribute__((ext_vector_type(4))) float f32x4;
typedef __attribute__((ext_vector_type(8))) short bf16x8;

#define B_ROWS 16384
#define IN_DIM 768
#define H1 512
#define H2 256
#define NC 50
#define NE 8
#define RH1 256
#define RH2 128
#define W1_STEPS 24
#define W2_STEPS 16
#define CHK 128
#define CHKX 64

static __device__ __forceinline__ f32x4 mfma16(bf16x8 a, bf16x8 b, f32x4 c) {
    return __builtin_amdgcn_mfma_f32_16x16x32_bf16(a, b, c, 0, 0, 0);
}

typedef __attribute__((address_space(1))) const unsigned int gas_u32;
typedef __attribute__((address_space(3))) unsigned int las_u32;
static __device__ __forceinline__ void gl16(const void* g, void* l) {
    __builtin_amdgcn_global_load_lds((gas_u32*)g, (las_u32*)l, 16, 0, 0);
}

// expand 8 ternary byte-codes (bf16 high byte: 0x3F/0xBF/0x00) to exact bf16x8
static __device__ __forceinline__ bf16x8 expand_frag(uint2 pw) {
    unsigned q0 = (pw.x & 0x01010101u) << 7;
    unsigned q1 = (pw.y & 0x01010101u) << 7;
    union { unsigned u[4]; bf16x8 v; } r;
    r.u[0] = __builtin_amdgcn_perm(pw.x, q0, 0x05010400u);
    r.u[1] = __builtin_amdgcn_perm(pw.x, q0, 0x07030602u);
    r.u[2] = __builtin_amdgcn_perm(pw.y, q1, 0x05010400u);
    r.u[3] = __builtin_amdgcn_perm(pw.y, q1, 0x07030602u);
    return r.v;
}

// ---------------- merged ternarize+pack+abs-sum: grid (96, 24), 512 thr.
// W1/W2: PAIR layout — frags (2p,2p+1) adjacent 16B per lane. W3: flat layout.
__global__ __launch_bounds__(512) void pack_absum_kernel(
    const float* __restrict__ eW1, const float* __restrict__ eW2, const float* __restrict__ eW3,
    unsigned char* __restrict__ W1p8, unsigned char* __restrict__ W2p8,
    unsigned char* __restrict__ W3p8,
    float* __restrict__ p1, float* __restrict__ p2, float* __restrict__ p3)
{
    const int mat = blockIdx.y >> 3, e = blockIdx.y & 7;
    const int u = blockIdx.x * 512 + threadIdx.x;
    const float* src; unsigned char* dst; int valid = 1; float* P; int np;
    if (mat == 0) {
        int lane = u & 63, nblk = (u >> 6) & 31, ks = u >> 11;
        int n = nblk * 16 + (lane & 15), k = ks * 32 + (lane >> 4) * 8;
        src = eW1 + ((size_t)e * H1 + n) * IN_DIM + k;
        dst = W1p8 + (size_t)e * 393216
            + (size_t)ks * 16384 + (nblk >> 1) * 1024 + lane * 16 + (nblk & 1) * 8;
        P = p1; np = 96;
    } else if (mat == 1) {
        if (u >= 16384) return;
        int lane = u & 63, nblk = (u >> 6) & 15, ks = u >> 10;
        int n = nblk * 16 + (lane & 15), k = ks * 32 + (lane >> 4) * 8;
        src = eW2 + ((size_t)e * H2 + n) * H1 + k;
        dst = W2p8 + (size_t)e * 131072
            + (size_t)ks * 8192 + (nblk >> 1) * 1024 + lane * 16 + (nblk & 1) * 8;
        P = p2; np = 32;
    } else {
        if (u >= 2048) return;
        int lane = u & 63, nblk = (u >> 6) & 3, ks = u >> 8;
        int n = nblk * 16 + (lane & 15), k = ks * 32 + (lane >> 4) * 8;
        valid = (n < NC);
        src = eW3 + ((size_t)e * NC + (valid ? n : 0)) * H2 + k;
        dst = W3p8 + ((size_t)e * 2048 + u) * 8;
        P = p3; np = 4;
    }
    unsigned lo = 0, hi = 0;
    float s = 0.f;
    #pragma unroll
    for (int j = 0; j < 4; ++j) {
        float w = valid ? src[j] : 0.f;
        s += fabsf(w);
        unsigned c = (fabsf(w) > 0.05f) ? (w > 0.f ? 0x3Fu : 0xBFu) : 0u;
        lo |= c << (8 * j);
    }
    #pragma unroll
    for (int j = 0; j < 4; ++j) {
        float w = valid ? src[4 + j] : 0.f;
        s += fabsf(w);
        unsigned c = (fabsf(w) > 0.05f) ? (w > 0.f ? 0x3Fu : 0xBFu) : 0u;
        hi |= c << (8 * j);
    }
    *(uint2*)dst = make_uint2(lo, hi);
    const int lane = threadIdx.x & 63, wave = threadIdx.x >> 6;
    #pragma unroll
    for (int o = 32; o; o >>= 1) s += __shfl_down(s, o);
    __shared__ float red[8];
    if (lane == 0) red[wave] = s;
    __syncthreads();
    if (threadIdx.x == 0) {
        float t = 0.f;
        #pragma unroll
        for (int i = 0; i < 8; ++i) t += red[i];
        P[e * np + blockIdx.x] = t;
    }
}

// ---------------- finalize scales + zero dispatch counts
__global__ __launch_bounds__(64) void finalize_scales_kernel(
    const float* __restrict__ p1, const float* __restrict__ p2, const float* __restrict__ p3,
    float* __restrict__ s1, float* __restrict__ s2, float* __restrict__ s3,
    int* __restrict__ counts)
{
    int t = threadIdx.x;
    if (t < 8) {
        float a = 0.f;
        for (int i = 0; i < 96; ++i) a += p1[t * 96 + i];
        s1[t] = a / (float)(H1 * IN_DIM);
    } else if (t < 16) {
        int e = t - 8; float a = 0.f;
        for (int i = 0; i < 32; ++i) a += p2[e * 32 + i];
        s2[e] = a / (float)(H2 * H1);
    } else if (t < 24) {
        int e = t - 16; float a = 0.f;
        for (int i = 0; i < 4; ++i) a += p3[e * 4 + i];
        s3[e] = a / (float)(NC * H2);
    } else if (t < 32) {
        counts[t - 24] = 0;
    }
}

// ---------------- pack router weights into fragment-order hi/lo images
__global__ __launch_bounds__(512) void pack_router_kernel(
    const float* __restrict__ rW1, ushort* __restrict__ rw1hp, ushort* __restrict__ rw1lp,
    const float* __restrict__ rW2, ushort* __restrict__ rw2hp, ushort* __restrict__ rw2lp)
{
    int u = blockIdx.x * 512 + threadIdx.x;
    const float* src; ushort* dh; ushort* dl;
    if (u < 24576) {
        int lane = u & 63, nblk = (u >> 6) & 15, ks = u >> 10;
        int n = nblk * 16 + (lane & 15), k = ks * 32 + (lane >> 4) * 8;
        src = rW1 + (size_t)n * IN_DIM + k;
        dh = rw1hp + (size_t)u * 8; dl = rw1lp + (size_t)u * 8;
    } else {
        int v = u - 24576;
        if (v >= 4096) return;
        int lane = v & 63, nblk = (v >> 6) & 7, ks = v >> 9;
        int n = nblk * 16 + (lane & 15), k = ks * 32 + (lane >> 4) * 8;
        src = rW2 + (size_t)n * RH1 + k;
        dh = rw2hp + (size_t)v * 8; dl = rw2lp + (size_t)v * 8;
    }
    ushort oh[8], ol[8];
    #pragma unroll
    for (int j = 0; j < 8; ++j) {
        float w = src[j];
        __hip_bfloat16 h = __float2bfloat16(w);
        float hf = __bfloat162float(h);
        __hip_bfloat16 l = __float2bfloat16(w - hf);
        oh[j] = *(ushort*)&h; ol[j] = *(ushort*)&l;
    }
    ((ushort4*)dh)[0] = make_ushort4(oh[0], oh[1], oh[2], oh[3]);
    ((ushort4*)dh)[1] = make_ushort4(oh[4], oh[5], oh[6], oh[7]);
    ((ushort4*)dl)[0] = make_ushort4(ol[0], ol[1], ol[2], ol[3]);
    ((ushort4*)dl)[1] = make_ushort4(ol[4], ol[5], ol[6], ol[7]);
}

// ---------------- x hi/lo decomposition (3072 blocks)
__global__ __launch_bounds__(256) void decomp_x_kernel(
    const float* __restrict__ x, ushort* __restrict__ xh, ushort* __restrict__ xl)
{
    const float4* in = (const float4*)x;
    ushort4* hi = (ushort4*)xh;
    ushort4* lo = (ushort4*)xl;
    const int base = blockIdx.x * 1024;
    #pragma unroll
    for (int j = 0; j < 4; ++j) {
        int i = base + j * 256 + threadIdx.x;
        float4 v = in[i];
        float vv[4] = {v.x, v.y, v.z, v.w};
        ushort ho[4], lo4[4];
        #pragma unroll
        for (int q = 0; q < 4; ++q) {
            __hip_bfloat16 h = __float2bfloat16(vv[q]);
            float hf = __bfloat162float(h);
            __hip_bfloat16 l = __float2bfloat16(vv[q] - hf);
            ho[q] = *(ushort*)&h; lo4[q] = *(ushort*)&l;
        }
        hi[i] = make_ushort4(ho[0], ho[1], ho[2], ho[3]);
        lo[i] = make_ushort4(lo4[0], lo4[1], lo4[2], lo4[3]);
    }
}

// ---------------- fused router, 1024 threads (unchanged)
__global__ __launch_bounds__(1024) void router_fused_kernel(
    const ushort* __restrict__ xh, const ushort* __restrict__ xl,
    const ushort* __restrict__ rw1hp, const ushort* __restrict__ rw1lp, const float* __restrict__ rb1,
    const ushort* __restrict__ rw2hp, const ushort* __restrict__ rw2lp, const float* __restrict__ rb2,
    const float* __restrict__ rW3, const float* __restrict__ rb3,
    float* __restrict__ router_p, float* __restrict__ gate,
    float* __restrict__ lb_out, int* __restrict__ t2)
{
    __shared__ __align__(16) unsigned char smem[134144];
    unsigned char* Wst = smem;
    ushort (*Xdh)[32][136] = (ushort(*)[32][136])(smem + 65536);
    ushort (*Xdl)[32][136] = (ushort(*)[32][136])(smem + 65536 + 17408);
    float (*h2s)[132]      = (float(*)[132])(smem + 65536);
    ushort (*h1hs)[264]    = (ushort(*)[264])(smem + 100352);
    ushort (*h1ls)[264]    = (ushort(*)[264])(smem + 117248);

    const int tid = threadIdx.x, wave = tid >> 6, lane = tid & 63;
    const int lm = lane & 15, lk = lane >> 4;
    const int r0 = blockIdx.x * 32;

    const int half = tid >> 9;
    const int st   = tid & 511;
    const int srow = st >> 4;
    const int sc8  = (st & 15) * 8;
    const ushort* sg = (half ? xl : xh) + (size_t)(r0 + srow) * IN_DIM + sc8;

    bf16x8 sv = *(const bf16x8*)sg;
    gl16(rw1hp + tid * 8, Wst + tid * 16);
    gl16(rw1lp + tid * 8, Wst + 16384 + tid * 16);
    if (half) *(bf16x8*)&Xdl[0][srow][sc8] = sv;
    else      *(bf16x8*)&Xdh[0][srow][sc8] = sv;
    __syncthreads();

    // ---- layer 1
    {
        f32x4 acc[2] = {};
        for (int s = 0; s < 24; ++s) {
            const int c = s >> 2;
            const unsigned char* curh = Wst + (s & 1) * 32768;
            const unsigned char* curl = curh + 16384;
            if (s + 1 < 24) {
                unsigned char* dst = Wst + ((s + 1) & 1) * 32768;
                gl16(rw1hp + (size_t)(s + 1) * 8192 + tid * 8, dst + tid * 16);
                gl16(rw1lp + (size_t)(s + 1) * 8192 + tid * 8, dst + 16384 + tid * 16);
            } else {
                if (tid < 512) gl16(rw2hp + tid * 8, Wst + tid * 16);
                else           gl16(rw2lp + st * 8, Wst + 16384 + st * 16);
            }
            if ((s & 3) == 0 && c < 5)
                sv = *(const bf16x8*)(sg + (c + 1) * CHK);
            const ushort (*Xch)[136] = Xdh[c & 1];
            const ushort (*Xcl)[136] = Xdl[c & 1];
            const int ko = (s & 3) * 32 + lk * 8;
            bf16x8 ah0 = *(const bf16x8*)&Xch[lm][ko];
            bf16x8 al0 = *(const bf16x8*)&Xcl[lm][ko];
            bf16x8 ah1 = *(const bf16x8*)&Xch[16 + lm][ko];
            bf16x8 al1 = *(const bf16x8*)&Xcl[16 + lm][ko];
            bf16x8 bh = *(const bf16x8*)(curh + (wave * 64 + lane) * 16);
            bf16x8 bl = *(const bf16x8*)(curl + (wave * 64 + lane) * 16);
            acc[0] = mfma16(ah0, bh, acc[0]);
            acc[0] = mfma16(ah0, bl, acc[0]);
            acc[0] = mfma16(al0, bh, acc[0]);
            acc[1] = mfma16(ah1, bh, acc[1]);
            acc[1] = mfma16(ah1, bl, acc[1]);
            acc[1] = mfma16(al1, bh, acc[1]);
            if ((s & 3) == 2 && c < 5) {
                if (half) *(bf16x8*)&Xdl[(c + 1) & 1][srow][sc8] = sv;
                else      *(bf16x8*)&Xdh[(c + 1) & 1][srow][sc8] = sv;
            }
            __syncthreads();
        }
        int col = wave * 16 + lm;
        float bv = rb1[col];
        #pragma unroll
        for (int m = 0; m < 2; ++m)
            #pragma unroll
            for (int r = 0; r < 4; ++r) {
                float v = acc[m][r] + bv;
                v = v > 0.f ? v : 0.f;
                __hip_bfloat16 h = __float2bfloat16(v);
                float hf = __bfloat162float(h);
                __hip_bfloat16 l = __float2bfloat16(v - hf);
                int row = m * 16 + lk * 4 + r;
                h1hs[row][col] = *(ushort*)&h;
                h1ls[row][col] = *(ushort*)&l;
            }
    }
    __syncthreads();

    // ---- layer 2
    {
        const int mt = wave >> 3, nb = wave & 7;
        f32x4 acc2 = {};
        for (int s = 0; s < 8; ++s) {
            const unsigned char* curh = Wst + (s & 1) * 32768;
            const unsigned char* curl = curh + 16384;
            if (s + 1 < 8) {
                unsigned char* dst = Wst + ((s + 1) & 1) * 32768;
                if (tid < 512) gl16(rw2hp + (size_t)(s + 1) * 4096 + tid * 8, dst + tid * 16);
                else           gl16(rw2lp + (size_t)(s + 1) * 4096 + st * 8, dst + 16384 + st * 16);
            }
            const int ko = s * 32 + lk * 8;
            bf16x8 ah = *(const bf16x8*)&h1hs[mt * 16 + lm][ko];
            bf16x8 al = *(const bf16x8*)&h1ls[mt * 16 + lm][ko];
            bf16x8 bh = *(const bf16x8*)(curh + (nb * 64 + lane) * 16);
            bf16x8 bl = *(const bf16x8*)(curl + (nb * 64 + lane) * 16);
            acc2 = mfma16(ah, bh, acc2);
            acc2 = mfma16(ah, bl, acc2);
            acc2 = mfma16(al, bh, acc2);
            __syncthreads();
        }
        int col2 = nb * 16 + lm;
        float bv = rb2[col2];
        #pragma unroll
        for (int r = 0; r < 4; ++r) {
            float v = acc2[r] + bv;
            h2s[mt * 16 + lk * 4 + r][col2] = v > 0.f ? v : 0.f;
        }
    }
    __syncthreads();

    // ---- head
    const int o = lane >> 3, kq = lane & 7;
    #pragma unroll
    for (int i = 0; i < 2; ++i) {
        int rloc = wave * 2 + i;
        int b = r0 + rloc;
        float s = 0.f;
        #pragma unroll
        for (int q = 0; q < 4; ++q) {
            float4 hv = *(const float4*)&h2s[rloc][kq * 16 + q * 4];
            float4 wv = *(const float4*)&rW3[o * RH2 + kq * 16 + q * 4];
            s += hv.x * wv.x + hv.y * wv.y + hv.z * wv.z + hv.w * wv.w;
        }
        s += __shfl_xor(s, 1);
        s += __shfl_xor(s, 2);
        s += __shfl_xor(s, 4);
        float logit = s + rb3[o];
        float l[8];
        #pragma unroll
        for (int j = 0; j < 8; ++j) l[j] = __shfl(logit, j * 8);
        float m = l[0];
        #pragma unroll
        for (int j = 1; j < 8; ++j) m = fmaxf(m, l[j]);
        float p[8]; float sum = 0.f;
        #pragma unroll
        for (int j = 0; j < 8; ++j) { p[j] = expf(l[j] - m); sum += p[j]; }
        float inv = 1.f / sum;
        #pragma unroll
        for (int j = 0; j < 8; ++j) p[j] *= inv;
        int i1 = 0; float v1 = p[0];
        #pragma unroll
        for (int j = 1; j < 8; ++j) if (p[j] > v1) { v1 = p[j]; i1 = j; }
        int i2 = -1; float v2 = -1.f;
        #pragma unroll
        for (int j = 0; j < 8; ++j) if (j != i1 && p[j] > v2) { v2 = p[j]; i2 = j; }
        if (lane < 8) {
            router_p[(size_t)b * 8 + lane] = p[lane];
            float gv = (lane == i1) ? v1 * 0.5f : ((lane == i2) ? v2 * 0.5f : 0.f);
            gate[(size_t)b * 8 + lane] = gv;
        }
        if (lane == 0) t2[b] = i1 | (i2 << 8);
    }
    if (blockIdx.x == 0 && tid == 0) lb_out[0] = 0.f;
}

// ---------------- build dispatch lists
__global__ __launch_bounds__(256) void build_lists_kernel(
    const int* __restrict__ t2, int* __restrict__ counts, int* __restrict__ ent)
{
    __shared__ int hist[8], base[8];
    const int r = blockIdx.x * 256 + threadIdx.x;
    if (threadIdx.x < 8) hist[threadIdx.x] = 0;
    __syncthreads();
    const int v = t2[r];
    const int i1 = v & 255, i2 = v >> 8;
    const int rk1 = atomicAdd(&hist[i1], 1);
    const int rk2 = atomicAdd(&hist[i2], 1);
    __syncthreads();
    if (threadIdx.x < 8) base[threadIdx.x] = atomicAdd(&counts[threadIdx.x], hist[threadIdx.x]);
    __syncthreads();
    ent[i1 * B_ROWS + base[i1] + rk1] = (r << 1);
    ent[i2 * B_ROWS + base[i2] + rk2] = (r << 1) | 1;
}

// ---------------- sparse fused expert kernel: BM=64, 1024 thr, balanced affinity,
// 2 K-steps per barrier in BOTH L1 (12 intervals) and L2 (8 intervals), pair-packed W.
__global__ __launch_bounds__(1024) void expert_fused_kernel(
    const ushort* __restrict__ xh,
    const unsigned char* __restrict__ W1p8, const unsigned char* __restrict__ W2p8,
    const unsigned char* __restrict__ W3p8,
    const float* __restrict__ s1, const float* __restrict__ s2, const float* __restrict__ s3,
    const float* __restrict__ eb1, const float* __restrict__ eb2, const float* __restrict__ eb3,
    const float* __restrict__ gate,
    const int* __restrict__ counts, const int* __restrict__ ent,
    float* __restrict__ S0, float* __restrict__ S1)
{
    int pfx[9]; pfx[0] = 0;
    #pragma unroll
    for (int i = 0; i < 8; ++i) pfx[i + 1] = pfx[i] + ((counts[i] + 63) >> 6);
    const int T = pfx[8];
    const int R = (T + 7) >> 3;
    const int xcd = blockIdx.x & 7, j = blockIdx.x >> 3;
    if (j >= R) return;
    const int g = xcd * R + j;
    if (g >= T) return;
    int e = 0;
    #pragma unroll
    for (int i = 0; i < 7; ++i) if (g >= pfx[i + 1]) e = i + 1;
    const int t = g - pfx[e];
    const int cnt = counts[e];

    __shared__ __align__(16) unsigned char smem[151552];
    unsigned char* Wst = smem;
    __hip_bfloat16 (*A2s)[264] = (__hip_bfloat16(*)[264])(smem + 32768);
    __hip_bfloat16 (*A1s)[520] = (__hip_bfloat16(*)[520])(smem + 66560);
    ushort (*Xd)[64][72]       = (ushort(*)[64][72])(smem + 133120);
    __shared__ int rowL[64];
    __shared__ int slotL[64];
    __shared__ float gL[64];

    const int tid = threadIdx.x;
    const int wave = tid >> 6;
    const int lane = tid & 63;
    const int lm = lane & 15;
    const int lk = lane >> 4;

    if (tid < 64) {
        int idx = t * 64 + tid;
        if (idx < cnt) {
            int entv = ent[e * B_ROWS + idx];
            int r = entv >> 1;
            rowL[tid] = r;
            slotL[tid] = entv & 1;
            gL[tid] = gate[(size_t)r * NE + e];
        } else {
            rowL[tid] = -1; slotL[tid] = 0; gL[tid] = 0.f;
        }
    }
    __syncthreads();

    const int srow = tid >> 4;
    const int sc4  = (tid & 15) * 4;
    int SR = rowL[srow]; if (SR < 0) SR = 0;
    const ushort* sg = xh + (size_t)SR * IN_DIM + sc4;
    const unsigned char* Wsrc1 = W1p8 + (size_t)e * 393216;
    const unsigned char* Wsrc2 = W2p8 + (size_t)e * 131072;
    const unsigned char* Wsrc3 = W3p8 + (size_t)e * 16384;

    ushort4 sv = *(const ushort4*)sg;
    gl16(Wsrc1 + tid * 16, Wst + tid * 16);
    gl16(Wsrc1 + 16384 + tid * 16, Wst + 16384 + tid * 16);
    *(ushort4*)&Xd[0][srow][sc4] = sv;
    __syncthreads();

    // ---- layer 1: 12 intervals x 2 K-steps
    {
        f32x4 acc[4][2] = {};
        const int w2 = wave * 2;
        for (int i = 0; i < 12; ++i) {
            const unsigned char* buf = Wst + (i & 1) * 32768;
            if (i + 1 < 12) {
                unsigned char* dst = Wst + ((i + 1) & 1) * 32768;
                gl16(Wsrc1 + (size_t)(i + 1) * 32768 + tid * 16, dst + tid * 16);
                gl16(Wsrc1 + (size_t)(i + 1) * 32768 + 16384 + tid * 16, dst + 16384 + tid * 16);
            } else {
                // W2 interval 0 (16KB = steps 0,1) -> [0,16K) (buf0, last read at i=10)
                gl16(Wsrc2 + tid * 16, Wst + tid * 16);
            }
            if (i + 1 < 12) sv = *(const ushort4*)(sg + (i + 1) * CHKX);
            const ushort (*Xc)[72] = Xd[i & 1];
            #pragma unroll
            for (int k2 = 0; k2 < 2; ++k2) {
                const unsigned char* cur = buf + k2 * 16384;
                const int ko = k2 * 32 + lk * 8;
                bf16x8 a0 = *(const bf16x8*)&Xc[     lm][ko];
                bf16x8 a1 = *(const bf16x8*)&Xc[16 + lm][ko];
                bf16x8 a2 = *(const bf16x8*)&Xc[32 + lm][ko];
                bf16x8 a3 = *(const bf16x8*)&Xc[48 + lm][ko];
                uint4 pw4 = *(const uint4*)(cur + wave * 1024 + lane * 16);
                bf16x8 b0 = expand_frag(make_uint2(pw4.x, pw4.y));
                bf16x8 b1 = expand_frag(make_uint2(pw4.z, pw4.w));
                acc[0][0] = mfma16(a0, b0, acc[0][0]);
                acc[1][0] = mfma16(a1, b0, acc[1][0]);
                acc[2][0] = mfma16(a2, b0, acc[2][0]);
                acc[3][0] = mfma16(a3, b0, acc[3][0]);
                acc[0][1] = mfma16(a0, b1, acc[0][1]);
                acc[1][1] = mfma16(a1, b1, acc[1][1]);
                acc[2][1] = mfma16(a2, b1, acc[2][1]);
                acc[3][1] = mfma16(a3, b1, acc[3][1]);
            }
            if (i + 1 < 12) *(ushort4*)&Xd[(i + 1) & 1][srow][sc4] = sv;
            __syncthreads();
        }
        const float* bias = eb1 + e * H1;
        const float sc = s1[e];
        #pragma unroll
        for (int n = 0; n < 2; ++n) {
            int ncol = (w2 + n) * 16 + lm;
            float bv = bias[ncol];
            #pragma unroll
            for (int m = 0; m < 4; ++m)
                #pragma unroll
                for (int r = 0; r < 4; ++r) {
                    float v = fmaf(acc[m][n][r], sc, bv);
                    v = v > 0.f ? v : 0.f;
                    A1s[m * 16 + lk * 4 + r][ncol] = __float2bfloat16(v);
                }
        }
    }
    __syncthreads();

    // ---- layer 2: 8 intervals x 2 K-steps, 16KB images at (i&1)*16384
    {
        const int mt = wave >> 3, ntw = wave & 7;
        f32x4 acc[2][2] = {};
        for (int i = 0; i < 8; ++i) {
            const unsigned char* buf = Wst + (i & 1) * 16384;
            if (i + 1 < 8) {
                gl16(Wsrc2 + (size_t)(i + 1) * 16384 + tid * 16,
                     Wst + ((i + 1) & 1) * 16384 + tid * 16);
            } else {
                // W3 panel (16KB) -> [0,16K) (buf0, last read at i=6)
                gl16(Wsrc3 + tid * 16, Wst + tid * 16);
            }
            #pragma unroll
            for (int k2 = 0; k2 < 2; ++k2) {
                const unsigned char* cur = buf + k2 * 8192;
                const int s = i * 2 + k2;
                const int ko = s * 32 + lk * 8;
                bf16x8 a0 = *(const bf16x8*)&A1s[mt * 32 +      lm][ko];
                bf16x8 a1 = *(const bf16x8*)&A1s[mt * 32 + 16 + lm][ko];
                uint4 pw4 = *(const uint4*)(cur + ntw * 1024 + lane * 16);
                bf16x8 b0 = expand_frag(make_uint2(pw4.x, pw4.y));
                bf16x8 b1 = expand_frag(make_uint2(pw4.z, pw4.w));
                acc[0][0] = mfma16(a0, b0, acc[0][0]);
                acc[1][0] = mfma16(a1, b0, acc[1][0]);
                acc[0][1] = mfma16(a0, b1, acc[0][1]);
                acc[1][1] = mfma16(a1, b1, acc[1][1]);
            }
            __syncthreads();
        }
        const float* bias = eb2 + e * H2;
        const float sc = s2[e];
        #pragma unroll
        for (int n = 0; n < 2; ++n) {
            int ncol = (ntw * 2 + n) * 16 + lm;
            float bv = bias[ncol];
            #pragma unroll
            for (int m = 0; m < 2; ++m)
                #pragma unroll
                for (int r = 0; r < 4; ++r) {
                    float v = fmaf(acc[m][n][r], sc, bv);
                    v = v > 0.f ? v : 0.f;
                    A2s[mt * 32 + m * 16 + lk * 4 + r][ncol] = __float2bfloat16(v);
                }
        }
    }
    __syncthreads();   // drains W3 DMA + A2s visible

    // ---- layer 3: W3 flat panel resident at Wst+0
    {
        const int mt = wave & 3, nt = wave >> 2;
        f32x4 acc = {};
        #pragma unroll
        for (int s = 0; s < 8; ++s) {
            bf16x8 a = *(const bf16x8*)&A2s[mt * 16 + lm][s * 32 + lk * 8];
            uint2 pw = *(const uint2*)(Wst + ((s * 4 + nt) * 64 + lane) * 8);
            bf16x8 b = expand_frag(pw);
            acc = mfma16(a, b, acc);
        }
        int col = nt * 16 + lm;
        if (col < NC) {
            const float bv = eb3[e * NC + col];
            const float sc = s3[e];
            #pragma unroll
            for (int r = 0; r < 4; ++r) {
                int row = mt * 16 + lk * 4 + r;
                int R2 = rowL[row];
                if (R2 >= 0) {
                    float v = gL[row] * fmaf(acc[r], sc, bv);
                    float* Sb = slotL[row] ? S1 : S0;
                    Sb[(size_t)R2 * 64 + col] = v;
                }
            }
        }
    }
}

// ---------------- combine
__global__ __launch_bounds__(256) void combine_kernel(
    const float* __restrict__ S0, const float* __restrict__ S1, float* __restrict__ out)
{
    int i = blockIdx.x * 256 + threadIdx.x;
    if (i < B_ROWS * NC) {
        int row = i / NC, col = i % NC;
        out[i] = S0[(size_t)row * 64 + col] + S1[(size_t)row * 64 + col];
    }
}

extern "C" void kernel_launch(void* const* d_in, const int* in_sizes, int n_in,
                              void* d_out, int out_size, void* d_ws, size_t ws_size,
                              hipStream_t stream) {
    const float* x   = (const float*)d_in[0];
    const float* rW1 = (const float*)d_in[1];
    const float* rb1 = (const float*)d_in[2];
    const float* rW2 = (const float*)d_in[3];
    const float* rb2 = (const float*)d_in[4];
    const float* rW3 = (const float*)d_in[5];
    const float* rb3 = (const float*)d_in[6];
    const float* eW1 = (const float*)d_in[7];
    const float* eb1 = (const float*)d_in[8];
    const float* eW2 = (const float*)d_in[9];
    const float* eb2 = (const float*)d_in[10];
    const float* eW3 = (const float*)d_in[11];
    const float* eb3 = (const float*)d_in[12];

    float* out_main = (float*)d_out;
    float* router_p = out_main + (size_t)B_ROWS * NC;
    float* lb_out   = router_p + (size_t)B_ROWS * NE;

    char* ws = (char*)d_ws;
    size_t off = 0;
    unsigned char* W1p8 = (unsigned char*)(ws + off); off += (size_t)NE * 49152 * 8;
    unsigned char* W2p8 = (unsigned char*)(ws + off); off += (size_t)NE * 16384 * 8;
    unsigned char* W3p8 = (unsigned char*)(ws + off); off += (size_t)NE * 2048 * 8;
    ushort* xh  = (ushort*)(ws + off); off += (size_t)B_ROWS * IN_DIM * 2;
    ushort* xl  = (ushort*)(ws + off); off += (size_t)B_ROWS * IN_DIM * 2;
    float* S0   = (float*)(ws + off);  off += (size_t)B_ROWS * 64 * 4;
    float* S1   = (float*)(ws + off);  off += (size_t)B_ROWS * 64 * 4;
    ushort* rw1hp = (ushort*)(ws + off); off += (size_t)24576 * 8 * 2;
    ushort* rw1lp = (ushort*)(ws + off); off += (size_t)24576 * 8 * 2;
    ushort* rw2hp = (ushort*)(ws + off); off += (size_t)4096 * 8 * 2;
    ushort* rw2lp = (ushort*)(ws + off); off += (size_t)4096 * 8 * 2;
    float* gate = (float*)(ws + off);  off += (size_t)B_ROWS * NE * 4;
    int*   ent  = (int*)(ws + off);    off += (size_t)NE * B_ROWS * 4;
    int*   t2   = (int*)(ws + off);    off += (size_t)B_ROWS * 4;
    int* counts = (int*)(ws + off);    off += 256;
    float* s1   = (float*)(ws + off);  off += 256;
    float* s2   = (float*)(ws + off);  off += 256;
    float* s3   = (float*)(ws + off);  off += 256;
    float* p1   = (float*)(ws + off);  off += NE * 96 * 4;
    float* p2   = (float*)(ws + off);  off += NE * 32 * 4;
    float* p3   = (float*)(ws + off);  off += NE * 4 * 4;

    // 1) prep
    pack_absum_kernel<<<dim3(96, 24), 512, 0, stream>>>(
        eW1, eW2, eW3, W1p8, W2p8, W3p8, p1, p2, p3);
    pack_router_kernel<<<56, 512, 0, stream>>>(rW1, rw1hp, rw1lp, rW2, rw2hp, rw2lp);
    decomp_x_kernel<<<3072, 256, 0, stream>>>(x, xh, xl);
    finalize_scales_kernel<<<1, 64, 0, stream>>>(p1, p2, p3, s1, s2, s3, counts);

    // 2) fused router
    router_fused_kernel<<<B_ROWS / 32, 1024, 0, stream>>>(
        xh, xl, rw1hp, rw1lp, rb1, rw2hp, rw2lp, rb2, rW3, rb3, router_p, gate, lb_out, t2);
    build_lists_kernel<<<B_ROWS / 256, 256, 0, stream>>>(t2, counts, ent);

    // 3) sparse fused experts (2-step intervals in L1 AND L2) + combine
    expert_fused_kernel<<<1024, 1024, 0, stream>>>(
        xh, W1p8, W2p8, W3p8, s1, s2, s3, eb1, eb2, eb3, gate, counts, ent, S0, S1);
    combine_kernel<<<(B_ROWS * NC + 255) / 256, 256, 0, stream>>>(S0, S1, out_main);
}

// Round 21
// 162.786 us; speedup vs baseline: 1.4245x; 1.0109x over previous
//
#include <hip/hip_runtime.h>
#include <hip/hip_bf16.h>

typedef __attribute__((ext_vector_type(4))) float f32x4;
typedef __attribute__((ext_vector_type(8))) short bf16x8;

#define B_ROWS 16384
#define IN_DIM 768
#define H1 512
#define H2 256
#define NC 50
#define NE 8
#define RH1 256
#define RH2 128
#define CHK 128
#define CHKX 64

static __device__ __forceinline__ f32x4 mfma16(bf16x8 a, bf16x8 b, f32x4 c) {
    return __builtin_amdgcn_mfma_f32_16x16x32_bf16(a, b, c, 0, 0, 0);
}

typedef __attribute__((address_space(1))) const unsigned int gas_u32;
typedef __attribute__((address_space(3))) unsigned int las_u32;
static __device__ __forceinline__ void gl16(const void* g, void* l) {
    __builtin_amdgcn_global_load_lds((gas_u32*)g, (las_u32*)l, 16, 0, 0);
}

// expand 8 ternary byte-codes (bf16 high byte: 0x3F/0xBF/0x00) to exact bf16x8
static __device__ __forceinline__ bf16x8 expand_frag(uint2 pw) {
    unsigned q0 = (pw.x & 0x01010101u) << 7;
    unsigned q1 = (pw.y & 0x01010101u) << 7;
    union { unsigned u[4]; bf16x8 v; } r;
    r.u[0] = __builtin_amdgcn_perm(pw.x, q0, 0x05010400u);
    r.u[1] = __builtin_amdgcn_perm(pw.x, q0, 0x07030602u);
    r.u[2] = __builtin_amdgcn_perm(pw.y, q1, 0x05010400u);
    r.u[3] = __builtin_amdgcn_perm(pw.y, q1, 0x07030602u);
    return r.v;
}

// ---------------- merged ternarize+pack+abs-sum: grid (96, 24), 512 thr.
__global__ __launch_bounds__(512) void pack_absum_kernel(
    const float* __restrict__ eW1, const float* __restrict__ eW2, const float* __restrict__ eW3,
    unsigned char* __restrict__ W1p8, unsigned char* __restrict__ W2p8,
    unsigned char* __restrict__ W3p8,
    float* __restrict__ p1, float* __restrict__ p2, float* __restrict__ p3)
{
    const int mat = blockIdx.y >> 3, e = blockIdx.y & 7;
    const int u = blockIdx.x * 512 + threadIdx.x;
    const float* src; unsigned char* dst; int valid = 1; float* P; int np;
    if (mat == 0) {
        int lane = u & 63, nblk = (u >> 6) & 31, ks = u >> 11;
        int n = nblk * 16 + (lane & 15), k = ks * 32 + (lane >> 4) * 8;
        src = eW1 + ((size_t)e * H1 + n) * IN_DIM + k;
        dst = W1p8 + (size_t)e * 393216
            + (size_t)ks * 16384 + (nblk >> 1) * 1024 + lane * 16 + (nblk & 1) * 8;
        P = p1; np = 96;
    } else if (mat == 1) {
        if (u >= 16384) return;
        int lane = u & 63, nblk = (u >> 6) & 15, ks = u >> 10;
        int n = nblk * 16 + (lane & 15), k = ks * 32 + (lane >> 4) * 8;
        src = eW2 + ((size_t)e * H2 + n) * H1 + k;
        dst = W2p8 + (size_t)e * 131072
            + (size_t)ks * 8192 + (nblk >> 1) * 1024 + lane * 16 + (nblk & 1) * 8;
        P = p2; np = 32;
    } else {
        if (u >= 2048) return;
        int lane = u & 63, nblk = (u >> 6) & 3, ks = u >> 8;
        int n = nblk * 16 + (lane & 15), k = ks * 32 + (lane >> 4) * 8;
        valid = (n < NC);
        src = eW3 + ((size_t)e * NC + (valid ? n : 0)) * H2 + k;
        dst = W3p8 + ((size_t)e * 2048 + u) * 8;
        P = p3; np = 4;
    }
    unsigned lo = 0, hi = 0;
    float s = 0.f;
    #pragma unroll
    for (int j = 0; j < 4; ++j) {
        float w = valid ? src[j] : 0.f;
        s += fabsf(w);
        unsigned c = (fabsf(w) > 0.05f) ? (w > 0.f ? 0x3Fu : 0xBFu) : 0u;
        lo |= c << (8 * j);
    }
    #pragma unroll
    for (int j = 0; j < 4; ++j) {
        float w = valid ? src[4 + j] : 0.f;
        s += fabsf(w);
        unsigned c = (fabsf(w) > 0.05f) ? (w > 0.f ? 0x3Fu : 0xBFu) : 0u;
        hi |= c << (8 * j);
    }
    *(uint2*)dst = make_uint2(lo, hi);
    const int lane = threadIdx.x & 63, wave = threadIdx.x >> 6;
    #pragma unroll
    for (int o = 32; o; o >>= 1) s += __shfl_down(s, o);
    __shared__ float red[8];
    if (lane == 0) red[wave] = s;
    __syncthreads();
    if (threadIdx.x == 0) {
        float t = 0.f;
        #pragma unroll
        for (int i = 0; i < 8; ++i) t += red[i];
        P[e * np + blockIdx.x] = t;
    }
}

// ---------------- finalize scales + zero dispatch counts
__global__ __launch_bounds__(64) void finalize_scales_kernel(
    const float* __restrict__ p1, const float* __restrict__ p2, const float* __restrict__ p3,
    float* __restrict__ s1, float* __restrict__ s2, float* __restrict__ s3,
    int* __restrict__ counts)
{
    int t = threadIdx.x;
    if (t < 8) {
        float a = 0.f;
        for (int i = 0; i < 96; ++i) a += p1[t * 96 + i];
        s1[t] = a / (float)(H1 * IN_DIM);
    } else if (t < 16) {
        int e = t - 8; float a = 0.f;
        for (int i = 0; i < 32; ++i) a += p2[e * 32 + i];
        s2[e] = a / (float)(H2 * H1);
    } else if (t < 24) {
        int e = t - 16; float a = 0.f;
        for (int i = 0; i < 4; ++i) a += p3[e * 4 + i];
        s3[e] = a / (float)(NC * H2);
    } else if (t < 32) {
        counts[t - 24] = 0;
    }
}

// ---------------- pack router weights into fragment-order hi/lo images
__global__ __launch_bounds__(512) void pack_router_kernel(
    const float* __restrict__ rW1, ushort* __restrict__ rw1hp, ushort* __restrict__ rw1lp,
    const float* __restrict__ rW2, ushort* __restrict__ rw2hp, ushort* __restrict__ rw2lp)
{
    int u = blockIdx.x * 512 + threadIdx.x;
    const float* src; ushort* dh; ushort* dl;
    if (u < 24576) {
        int lane = u & 63, nblk = (u >> 6) & 15, ks = u >> 10;
        int n = nblk * 16 + (lane & 15), k = ks * 32 + (lane >> 4) * 8;
        src = rW1 + (size_t)n * IN_DIM + k;
        dh = rw1hp + (size_t)u * 8; dl = rw1lp + (size_t)u * 8;
    } else {
        int v = u - 24576;
        if (v >= 4096) return;
        int lane = v & 63, nblk = (v >> 6) & 7, ks = v >> 9;
        int n = nblk * 16 + (lane & 15), k = ks * 32 + (lane >> 4) * 8;
        src = rW2 + (size_t)n * RH1 + k;
        dh = rw2hp + (size_t)v * 8; dl = rw2lp + (size_t)v * 8;
    }
    ushort oh[8], ol[8];
    #pragma unroll
    for (int j = 0; j < 8; ++j) {
        float w = src[j];
        __hip_bfloat16 h = __float2bfloat16(w);
        float hf = __bfloat162float(h);
        __hip_bfloat16 l = __float2bfloat16(w - hf);
        oh[j] = *(ushort*)&h; ol[j] = *(ushort*)&l;
    }
    ((ushort4*)dh)[0] = make_ushort4(oh[0], oh[1], oh[2], oh[3]);
    ((ushort4*)dh)[1] = make_ushort4(oh[4], oh[5], oh[6], oh[7]);
    ((ushort4*)dl)[0] = make_ushort4(ol[0], ol[1], ol[2], ol[3]);
    ((ushort4*)dl)[1] = make_ushort4(ol[4], ol[5], ol[6], ol[7]);
}

// ---------------- x hi/lo decomposition (3072 blocks)
__global__ __launch_bounds__(256) void decomp_x_kernel(
    const float* __restrict__ x, ushort* __restrict__ xh, ushort* __restrict__ xl)
{
    const float4* in = (const float4*)x;
    ushort4* hi = (ushort4*)xh;
    ushort4* lo = (ushort4*)xl;
    const int base = blockIdx.x * 1024;
    #pragma unroll
    for (int j = 0; j < 4; ++j) {
        int i = base + j * 256 + threadIdx.x;
        float4 v = in[i];
        float vv[4] = {v.x, v.y, v.z, v.w};
        ushort ho[4], lo4[4];
        #pragma unroll
        for (int q = 0; q < 4; ++q) {
            __hip_bfloat16 h = __float2bfloat16(vv[q]);
            float hf = __bfloat162float(h);
            __hip_bfloat16 l = __float2bfloat16(vv[q] - hf);
            ho[q] = *(ushort*)&h; lo4[q] = *(ushort*)&l;
        }
        hi[i] = make_ushort4(ho[0], ho[1], ho[2], ho[3]);
        lo[i] = make_ushort4(lo4[0], lo4[1], lo4[2], lo4[3]);
    }
}

// ---------------- fused router, 1024 threads (unchanged)
__global__ __launch_bounds__(1024) void router_fused_kernel(
    const ushort* __restrict__ xh, const ushort* __restrict__ xl,
    const ushort* __restrict__ rw1hp, const ushort* __restrict__ rw1lp, const float* __restrict__ rb1,
    const ushort* __restrict__ rw2hp, const ushort* __restrict__ rw2lp, const float* __restrict__ rb2,
    const float* __restrict__ rW3, const float* __restrict__ rb3,
    float* __restrict__ router_p, float* __restrict__ gate,
    float* __restrict__ lb_out, int* __restrict__ t2)
{
    __shared__ __align__(16) unsigned char smem[134144];
    unsigned char* Wst = smem;
    ushort (*Xdh)[32][136] = (ushort(*)[32][136])(smem + 65536);
    ushort (*Xdl)[32][136] = (ushort(*)[32][136])(smem + 65536 + 17408);
    float (*h2s)[132]      = (float(*)[132])(smem + 65536);
    ushort (*h1hs)[264]    = (ushort(*)[264])(smem + 100352);
    ushort (*h1ls)[264]    = (ushort(*)[264])(smem + 117248);

    const int tid = threadIdx.x, wave = tid >> 6, lane = tid & 63;
    const int lm = lane & 15, lk = lane >> 4;
    const int r0 = blockIdx.x * 32;

    const int half = tid >> 9;
    const int st   = tid & 511;
    const int srow = st >> 4;
    const int sc8  = (st & 15) * 8;
    const ushort* sg = (half ? xl : xh) + (size_t)(r0 + srow) * IN_DIM + sc8;

    bf16x8 sv = *(const bf16x8*)sg;
    gl16(rw1hp + tid * 8, Wst + tid * 16);
    gl16(rw1lp + tid * 8, Wst + 16384 + tid * 16);
    if (half) *(bf16x8*)&Xdl[0][srow][sc8] = sv;
    else      *(bf16x8*)&Xdh[0][srow][sc8] = sv;
    __syncthreads();

    // ---- layer 1
    {
        f32x4 acc[2] = {};
        for (int s = 0; s < 24; ++s) {
            const int c = s >> 2;
            const unsigned char* curh = Wst + (s & 1) * 32768;
            const unsigned char* curl = curh + 16384;
            if (s + 1 < 24) {
                unsigned char* dst = Wst + ((s + 1) & 1) * 32768;
                gl16(rw1hp + (size_t)(s + 1) * 8192 + tid * 8, dst + tid * 16);
                gl16(rw1lp + (size_t)(s + 1) * 8192 + tid * 8, dst + 16384 + tid * 16);
            } else {
                if (tid < 512) gl16(rw2hp + tid * 8, Wst + tid * 16);
                else           gl16(rw2lp + st * 8, Wst + 16384 + st * 16);
            }
            if ((s & 3) == 0 && c < 5)
                sv = *(const bf16x8*)(sg + (c + 1) * CHK);
            const ushort (*Xch)[136] = Xdh[c & 1];
            const ushort (*Xcl)[136] = Xdl[c & 1];
            const int ko = (s & 3) * 32 + lk * 8;
            bf16x8 ah0 = *(const bf16x8*)&Xch[lm][ko];
            bf16x8 al0 = *(const bf16x8*)&Xcl[lm][ko];
            bf16x8 ah1 = *(const bf16x8*)&Xch[16 + lm][ko];
            bf16x8 al1 = *(const bf16x8*)&Xcl[16 + lm][ko];
            bf16x8 bh = *(const bf16x8*)(curh + (wave * 64 + lane) * 16);
            bf16x8 bl = *(const bf16x8*)(curl + (wave * 64 + lane) * 16);
            acc[0] = mfma16(ah0, bh, acc[0]);
            acc[0] = mfma16(ah0, bl, acc[0]);
            acc[0] = mfma16(al0, bh, acc[0]);
            acc[1] = mfma16(ah1, bh, acc[1]);
            acc[1] = mfma16(ah1, bl, acc[1]);
            acc[1] = mfma16(al1, bh, acc[1]);
            if ((s & 3) == 2 && c < 5) {
                if (half) *(bf16x8*)&Xdl[(c + 1) & 1][srow][sc8] = sv;
                else      *(bf16x8*)&Xdh[(c + 1) & 1][srow][sc8] = sv;
            }
            __syncthreads();
        }
        int col = wave * 16 + lm;
        float bv = rb1[col];
        #pragma unroll
        for (int m = 0; m < 2; ++m)
            #pragma unroll
            for (int r = 0; r < 4; ++r) {
                float v = acc[m][r] + bv;
                v = v > 0.f ? v : 0.f;
                __hip_bfloat16 h = __float2bfloat16(v);
                float hf = __bfloat162float(h);
                __hip_bfloat16 l = __float2bfloat16(v - hf);
                int row = m * 16 + lk * 4 + r;
                h1hs[row][col] = *(ushort*)&h;
                h1ls[row][col] = *(ushort*)&l;
            }
    }
    __syncthreads();

    // ---- layer 2
    {
        const int mt = wave >> 3, nb = wave & 7;
        f32x4 acc2 = {};
        for (int s = 0; s < 8; ++s) {
            const unsigned char* curh = Wst + (s & 1) * 32768;
            const unsigned char* curl = curh + 16384;
            if (s + 1 < 8) {
                unsigned char* dst = Wst + ((s + 1) & 1) * 32768;
                if (tid < 512) gl16(rw2hp + (size_t)(s + 1) * 4096 + tid * 8, dst + tid * 16);
                else           gl16(rw2lp + (size_t)(s + 1) * 4096 + st * 8, dst + 16384 + st * 16);
            }
            const int ko = s * 32 + lk * 8;
            bf16x8 ah = *(const bf16x8*)&h1hs[mt * 16 + lm][ko];
            bf16x8 al = *(const bf16x8*)&h1ls[mt * 16 + lm][ko];
            bf16x8 bh = *(const bf16x8*)(curh + (nb * 64 + lane) * 16);
            bf16x8 bl = *(const bf16x8*)(curl + (nb * 64 + lane) * 16);
            acc2 = mfma16(ah, bh, acc2);
            acc2 = mfma16(ah, bl, acc2);
            acc2 = mfma16(al, bh, acc2);
            __syncthreads();
        }
        int col2 = nb * 16 + lm;
        float bv = rb2[col2];
        #pragma unroll
        for (int r = 0; r < 4; ++r) {
            float v = acc2[r] + bv;
            h2s[mt * 16 + lk * 4 + r][col2] = v > 0.f ? v : 0.f;
        }
    }
    __syncthreads();

    // ---- head
    const int o = lane >> 3, kq = lane & 7;
    #pragma unroll
    for (int i = 0; i < 2; ++i) {
        int rloc = wave * 2 + i;
        int b = r0 + rloc;
        float s = 0.f;
        #pragma unroll
        for (int q = 0; q < 4; ++q) {
            float4 hv = *(const float4*)&h2s[rloc][kq * 16 + q * 4];
            float4 wv = *(const float4*)&rW3[o * RH2 + kq * 16 + q * 4];
            s += hv.x * wv.x + hv.y * wv.y + hv.z * wv.z + hv.w * wv.w;
        }
        s += __shfl_xor(s, 1);
        s += __shfl_xor(s, 2);
        s += __shfl_xor(s, 4);
        float logit = s + rb3[o];
        float l[8];
        #pragma unroll
        for (int j = 0; j < 8; ++j) l[j] = __shfl(logit, j * 8);
        float m = l[0];
        #pragma unroll
        for (int j = 1; j < 8; ++j) m = fmaxf(m, l[j]);
        float p[8]; float sum = 0.f;
        #pragma unroll
        for (int j = 0; j < 8; ++j) { p[j] = expf(l[j] - m); sum += p[j]; }
        float inv = 1.f / sum;
        #pragma unroll
        for (int j = 0; j < 8; ++j) p[j] *= inv;
        int i1 = 0; float v1 = p[0];
        #pragma unroll
        for (int j = 1; j < 8; ++j) if (p[j] > v1) { v1 = p[j]; i1 = j; }
        int i2 = -1; float v2 = -1.f;
        #pragma unroll
        for (int j = 0; j < 8; ++j) if (j != i1 && p[j] > v2) { v2 = p[j]; i2 = j; }
        if (lane < 8) {
            router_p[(size_t)b * 8 + lane] = p[lane];
            float gv = (lane == i1) ? v1 * 0.5f : ((lane == i2) ? v2 * 0.5f : 0.f);
            gate[(size_t)b * 8 + lane] = gv;
        }
        if (lane == 0) t2[b] = i1 | (i2 << 8);
    }
    if (blockIdx.x == 0 && tid == 0) lb_out[0] = 0.f;
}

// ---------------- build dispatch lists
__global__ __launch_bounds__(256) void build_lists_kernel(
    const int* __restrict__ t2, int* __restrict__ counts, int* __restrict__ ent)
{
    __shared__ int hist[8], base[8];
    const int r = blockIdx.x * 256 + threadIdx.x;
    if (threadIdx.x < 8) hist[threadIdx.x] = 0;
    __syncthreads();
    const int v = t2[r];
    const int i1 = v & 255, i2 = v >> 8;
    const int rk1 = atomicAdd(&hist[i1], 1);
    const int rk2 = atomicAdd(&hist[i2], 1);
    __syncthreads();
    if (threadIdx.x < 8) base[threadIdx.x] = atomicAdd(&counts[threadIdx.x], hist[threadIdx.x]);
    __syncthreads();
    ent[i1 * B_ROWS + base[i1] + rk1] = (r << 1);
    ent[i2 * B_ROWS + base[i2] + rk2] = (r << 1) | 1;
}

// ---------------- sparse fused expert kernel: BM=64, 1024 thr, balanced affinity,
// 2-step intervals in L1 (12 barriers), NEW 4-step intervals in L2 (4 barriers).
__global__ __launch_bounds__(1024) void expert_fused_kernel(
    const ushort* __restrict__ xh,
    const unsigned char* __restrict__ W1p8, const unsigned char* __restrict__ W2p8,
    const unsigned char* __restrict__ W3p8,
    const float* __restrict__ s1, const float* __restrict__ s2, const float* __restrict__ s3,
    const float* __restrict__ eb1, const float* __restrict__ eb2, const float* __restrict__ eb3,
    const float* __restrict__ gate,
    const int* __restrict__ counts, const int* __restrict__ ent,
    float* __restrict__ S0, float* __restrict__ S1)
{
    int pfx[9]; pfx[0] = 0;
    #pragma unroll
    for (int i = 0; i < 8; ++i) pfx[i + 1] = pfx[i] + ((counts[i] + 63) >> 6);
    const int T = pfx[8];
    const int R = (T + 7) >> 3;
    const int xcd = blockIdx.x & 7, j = blockIdx.x >> 3;
    if (j >= R) return;
    const int g = xcd * R + j;
    if (g >= T) return;
    int e = 0;
    #pragma unroll
    for (int i = 0; i < 7; ++i) if (g >= pfx[i + 1]) e = i + 1;
    const int t = g - pfx[e];
    const int cnt = counts[e];

    __shared__ __align__(16) unsigned char smem[151552];
    unsigned char* Wst = smem;
    __hip_bfloat16 (*A2s)[264] = (__hip_bfloat16(*)[264])(smem + 32768);
    __hip_bfloat16 (*A1s)[520] = (__hip_bfloat16(*)[520])(smem + 66560);
    ushort (*Xd)[64][72]       = (ushort(*)[64][72])(smem + 133120);
    __shared__ int rowL[64];
    __shared__ int slotL[64];
    __shared__ float gL[64];

    const int tid = threadIdx.x;
    const int wave = tid >> 6;
    const int lane = tid & 63;
    const int lm = lane & 15;
    const int lk = lane >> 4;

    if (tid < 64) {
        int idx = t * 64 + tid;
        if (idx < cnt) {
            int entv = ent[e * B_ROWS + idx];
            int r = entv >> 1;
            rowL[tid] = r;
            slotL[tid] = entv & 1;
            gL[tid] = gate[(size_t)r * NE + e];
        } else {
            rowL[tid] = -1; slotL[tid] = 0; gL[tid] = 0.f;
        }
    }
    __syncthreads();

    const int srow = tid >> 4;
    const int sc4  = (tid & 15) * 4;
    int SR = rowL[srow]; if (SR < 0) SR = 0;
    const ushort* sg = xh + (size_t)SR * IN_DIM + sc4;
    const unsigned char* Wsrc1 = W1p8 + (size_t)e * 393216;
    const unsigned char* Wsrc2 = W2p8 + (size_t)e * 131072;
    const unsigned char* Wsrc3 = W3p8 + (size_t)e * 16384;

    ushort4 sv = *(const ushort4*)sg;
    gl16(Wsrc1 + tid * 16, Wst + tid * 16);
    gl16(Wsrc1 + 16384 + tid * 16, Wst + 16384 + tid * 16);
    *(ushort4*)&Xd[0][srow][sc4] = sv;
    __syncthreads();

    // ---- layer 1: 12 intervals x 2 K-steps
    {
        f32x4 acc[4][2] = {};
        const int w2 = wave * 2;
        for (int i = 0; i < 12; ++i) {
            const unsigned char* buf = Wst + (i & 1) * 32768;
            if (i + 1 < 12) {
                unsigned char* dst = Wst + ((i + 1) & 1) * 32768;
                gl16(Wsrc1 + (size_t)(i + 1) * 32768 + tid * 16, dst + tid * 16);
                gl16(Wsrc1 + (size_t)(i + 1) * 32768 + 16384 + tid * 16, dst + 16384 + tid * 16);
            } else {
                // W2 interval 0 (32KB = steps 0..3) -> buf0 [0,32K) (free since i=10)
                gl16(Wsrc2 + tid * 16, Wst + tid * 16);
                gl16(Wsrc2 + 16384 + tid * 16, Wst + 16384 + tid * 16);
            }
            if (i + 1 < 12) sv = *(const ushort4*)(sg + (i + 1) * CHKX);
            const ushort (*Xc)[72] = Xd[i & 1];
            #pragma unroll
            for (int k2 = 0; k2 < 2; ++k2) {
                const unsigned char* cur = buf + k2 * 16384;
                const int ko = k2 * 32 + lk * 8;
                bf16x8 a0 = *(const bf16x8*)&Xc[     lm][ko];
                bf16x8 a1 = *(const bf16x8*)&Xc[16 + lm][ko];
                bf16x8 a2 = *(const bf16x8*)&Xc[32 + lm][ko];
                bf16x8 a3 = *(const bf16x8*)&Xc[48 + lm][ko];
                uint4 pw4 = *(const uint4*)(cur + wave * 1024 + lane * 16);
                bf16x8 b0 = expand_frag(make_uint2(pw4.x, pw4.y));
                bf16x8 b1 = expand_frag(make_uint2(pw4.z, pw4.w));
                acc[0][0] = mfma16(a0, b0, acc[0][0]);
                acc[1][0] = mfma16(a1, b0, acc[1][0]);
                acc[2][0] = mfma16(a2, b0, acc[2][0]);
                acc[3][0] = mfma16(a3, b0, acc[3][0]);
                acc[0][1] = mfma16(a0, b1, acc[0][1]);
                acc[1][1] = mfma16(a1, b1, acc[1][1]);
                acc[2][1] = mfma16(a2, b1, acc[2][1]);
                acc[3][1] = mfma16(a3, b1, acc[3][1]);
            }
            if (i + 1 < 12) *(ushort4*)&Xd[(i + 1) & 1][srow][sc4] = sv;
            __syncthreads();
        }
        const float* bias = eb1 + e * H1;
        const float sc = s1[e];
        #pragma unroll
        for (int n = 0; n < 2; ++n) {
            int ncol = (w2 + n) * 16 + lm;
            float bv = bias[ncol];
            #pragma unroll
            for (int m = 0; m < 4; ++m)
                #pragma unroll
                for (int r = 0; r < 4; ++r) {
                    float v = fmaf(acc[m][n][r], sc, bv);
                    v = v > 0.f ? v : 0.f;
                    A1s[m * 16 + lk * 4 + r][ncol] = __float2bfloat16(v);
                }
        }
    }
    __syncthreads();

    // ---- layer 2: 4 intervals x 4 K-steps, 32KB images at (i&1)*32768
    {
        const int mt = wave >> 3, ntw = wave & 7;
        f32x4 acc[2][2] = {};
        for (int i = 0; i < 4; ++i) {
            const unsigned char* buf = Wst + (i & 1) * 32768;
            if (i + 1 < 4) {
                unsigned char* dst = Wst + ((i + 1) & 1) * 32768;
                gl16(Wsrc2 + (size_t)(i + 1) * 32768 + tid * 16, dst + tid * 16);
                gl16(Wsrc2 + (size_t)(i + 1) * 32768 + 16384 + tid * 16, dst + 16384 + tid * 16);
            } else {
                // W3 panel (16KB) -> buf0 [0,16K) (free since i=2's barrier)
                gl16(Wsrc3 + tid * 16, Wst + tid * 16);
            }
            #pragma unroll
            for (int k4 = 0; k4 < 4; ++k4) {
                const unsigned char* cur = buf + k4 * 8192;
                const int s = i * 4 + k4;
                const int ko = s * 32 + lk * 8;
                bf16x8 a0 = *(const bf16x8*)&A1s[mt * 32 +      lm][ko];
                bf16x8 a1 = *(const bf16x8*)&A1s[mt * 32 + 16 + lm][ko];
                uint4 pw4 = *(const uint4*)(cur + ntw * 1024 + lane * 16);
                bf16x8 b0 = expand_frag(make_uint2(pw4.x, pw4.y));
                bf16x8 b1 = expand_frag(make_uint2(pw4.z, pw4.w));
                acc[0][0] = mfma16(a0, b0, acc[0][0]);
                acc[1][0] = mfma16(a1, b0, acc[1][0]);
                acc[0][1] = mfma16(a0, b1, acc[0][1]);
                acc[1][1] = mfma16(a1, b1, acc[1][1]);
            }
            __syncthreads();
        }
        const float* bias = eb2 + e * H2;
        const float sc = s2[e];
        #pragma unroll
        for (int n = 0; n < 2; ++n) {
            int ncol = (ntw * 2 + n) * 16 + lm;
            float bv = bias[ncol];
            #pragma unroll
            for (int m = 0; m < 2; ++m)
                #pragma unroll
                for (int r = 0; r < 4; ++r) {
                    float v = fmaf(acc[m][n][r], sc, bv);
                    v = v > 0.f ? v : 0.f;
                    A2s[mt * 32 + m * 16 + lk * 4 + r][ncol] = __float2bfloat16(v);
                }
        }
    }
    __syncthreads();   // drains W3 DMA + A2s visible

    // ---- layer 3: W3 flat panel resident at Wst+0
    {
        const int mt = wave & 3, nt = wave >> 2;
        f32x4 acc = {};
        #pragma unroll
        for (int s = 0; s < 8; ++s) {
            bf16x8 a = *(const bf16x8*)&A2s[mt * 16 + lm][s * 32 + lk * 8];
            uint2 pw = *(const uint2*)(Wst + ((s * 4 + nt) * 64 + lane) * 8);
            bf16x8 b = expand_frag(pw);
            acc = mfma16(a, b, acc);
        }
        int col = nt * 16 + lm;
        if (col < NC) {
            const float bv = eb3[e * NC + col];
            const float sc = s3[e];
            #pragma unroll
            for (int r = 0; r < 4; ++r) {
                int row = mt * 16 + lk * 4 + r;
                int R2 = rowL[row];
                if (R2 >= 0) {
                    float v = gL[row] * fmaf(acc[r], sc, bv);
                    float* Sb = slotL[row] ? S1 : S0;
                    Sb[(size_t)R2 * 64 + col] = v;
                }
            }
        }
    }
}

// ---------------- combine
__global__ __launch_bounds__(256) void combine_kernel(
    const float* __restrict__ S0, const float* __restrict__ S1, float* __restrict__ out)
{
    int i = blockIdx.x * 256 + threadIdx.x;
    if (i < B_ROWS * NC) {
        int row = i / NC, col = i % NC;
        out[i] = S0[(size_t)row * 64 + col] + S1[(size_t)row * 64 + col];
    }
}

extern "C" void kernel_launch(void* const* d_in, const int* in_sizes, int n_in,
                              void* d_out, int out_size, void* d_ws, size_t ws_size,
                              hipStream_t stream) {
    const float* x   = (const float*)d_in[0];
    const float* rW1 = (const float*)d_in[1];
    const float* rb1 = (const float*)d_in[2];
    const float* rW2 = (const float*)d_in[3];
    const float* rb2 = (const float*)d_in[4];
    const float* rW3 = (const float*)d_in[5];
    const float* rb3 = (const float*)d_in[6];
    const float* eW1 = (const float*)d_in[7];
    const float* eb1 = (const float*)d_in[8];
    const float* eW2 = (const float*)d_in[9];
    const float* eb2 = (const float*)d_in[10];
    const float* eW3 = (const float*)d_in[11];
    const float* eb3 = (const float*)d_in[12];

    float* out_main = (float*)d_out;
    float* router_p = out_main + (size_t)B_ROWS * NC;
    float* lb_out   = router_p + (size_t)B_ROWS * NE;

    char* ws = (char*)d_ws;
    size_t off = 0;
    unsigned char* W1p8 = (unsigned char*)(ws + off); off += (size_t)NE * 49152 * 8;
    unsigned char* W2p8 = (unsigned char*)(ws + off); off += (size_t)NE * 16384 * 8;
    unsigned char* W3p8 = (unsigned char*)(ws + off); off += (size_t)NE * 2048 * 8;
    ushort* xh  = (ushort*)(ws + off); off += (size_t)B_ROWS * IN_DIM * 2;
    ushort* xl  = (ushort*)(ws + off); off += (size_t)B_ROWS * IN_DIM * 2;
    float* S0   = (float*)(ws + off);  off += (size_t)B_ROWS * 64 * 4;
    float* S1   = (float*)(ws + off);  off += (size_t)B_ROWS * 64 * 4;
    ushort* rw1hp = (ushort*)(ws + off); off += (size_t)24576 * 8 * 2;
    ushort* rw1lp = (ushort*)(ws + off); off += (size_t)24576 * 8 * 2;
    ushort* rw2hp = (ushort*)(ws + off); off += (size_t)4096 * 8 * 2;
    ushort* rw2lp = (ushort*)(ws + off); off += (size_t)4096 * 8 * 2;
    float* gate = (float*)(ws + off);  off += (size_t)B_ROWS * NE * 4;
    int*   ent  = (int*)(ws + off);    off += (size_t)NE * B_ROWS * 4;
    int*   t2   = (int*)(ws + off);    off += (size_t)B_ROWS * 4;
    int* counts = (int*)(ws + off);    off += 256;
    float* s1   = (float*)(ws + off);  off += 256;
    float* s2   = (float*)(ws + off);  off += 256;
    float* s3   = (float*)(ws + off);  off += 256;
    float* p1   = (float*)(ws + off);  off += NE * 96 * 4;
    float* p2   = (float*)(ws + off);  off += NE * 32 * 4;
    float* p3   = (float*)(ws + off);  off += NE * 4 * 4;

    // 1) prep
    pack_absum_kernel<<<dim3(96, 24), 512, 0, stream>>>(
        eW1, eW2, eW3, W1p8, W2p8, W3p8, p1, p2, p3);
    pack_router_kernel<<<56, 512, 0, stream>>>(rW1, rw1hp, rw1lp, rW2, rw2hp, rw2lp);
    decomp_x_kernel<<<3072, 256, 0, stream>>>(x, xh, xl);
    finalize_scales_kernel<<<1, 64, 0, stream>>>(p1, p2, p3, s1, s2, s3, counts);

    // 2) fused router
    router_fused_kernel<<<B_ROWS / 32, 1024, 0, stream>>>(
        xh, xl, rw1hp, rw1lp, rb1, rw2hp, rw2lp, rb2, rW3, rb3, router_p, gate, lb_out, t2);
    build_lists_kernel<<<B_ROWS / 256, 256, 0, stream>>>(t2, counts, ent);

    // 3) sparse fused experts (2-step L1, 4-step L2 intervals) + combine
    expert_fused_kernel<<<1024, 1024, 0, stream>>>(
        xh, W1p8, W2p8, W3p8, s1, s2, s3, eb1, eb2, eb3, gate, counts, ent, S0, S1);
    combine_kernel<<<(B_ROWS * NC + 255) / 256, 256, 0, stream>>>(S0, S1, out_main);
}

// Round 22
// 145.377 us; speedup vs baseline: 1.5951x; 1.1198x over previous
//
#include <hip/hip_runtime.h>
#include <hip/hip_bf16.h>

typedef __attribute__((ext_vector_type(4))) float f32x4;
typedef __attribute__((ext_vector_type(8))) short bf16x8;

#define B_ROWS 16384
#define IN_DIM 768
#define H1 512
#define H2 256
#define NC 50
#define NE 8
#define RH1 256
#define RH2 128
#define CHK 128
#define CHKX 64

static __device__ __forceinline__ f32x4 mfma16(bf16x8 a, bf16x8 b, f32x4 c) {
    return __builtin_amdgcn_mfma_f32_16x16x32_bf16(a, b, c, 0, 0, 0);
}

typedef __attribute__((address_space(1))) const unsigned int gas_u32;
typedef __attribute__((address_space(3))) unsigned int las_u32;
static __device__ __forceinline__ void gl16(const void* g, void* l) {
    __builtin_amdgcn_global_load_lds((gas_u32*)g, (las_u32*)l, 16, 0, 0);
}

// expand 8 ternary byte-codes (bf16 high byte: 0x3F/0xBF/0x00) to exact bf16x8
static __device__ __forceinline__ bf16x8 expand_frag(uint2 pw) {
    unsigned q0 = (pw.x & 0x01010101u) << 7;
    unsigned q1 = (pw.y & 0x01010101u) << 7;
    union { unsigned u[4]; bf16x8 v; } r;
    r.u[0] = __builtin_amdgcn_perm(pw.x, q0, 0x05010400u);
    r.u[1] = __builtin_amdgcn_perm(pw.x, q0, 0x07030602u);
    r.u[2] = __builtin_amdgcn_perm(pw.y, q1, 0x05010400u);
    r.u[3] = __builtin_amdgcn_perm(pw.y, q1, 0x07030602u);
    return r.v;
}

// decompose float4 -> bf16 hi/lo ushort4 pair (RNE, identical to old decomp_x)
static __device__ __forceinline__ void decomp_f4(float4 v, ushort4* hv, ushort4* lv) {
    float vv[4] = {v.x, v.y, v.z, v.w};
    ushort ho[4], lo4[4];
    #pragma unroll
    for (int q = 0; q < 4; ++q) {
        __hip_bfloat16 h = __float2bfloat16(vv[q]);
        float hf = __bfloat162float(h);
        __hip_bfloat16 l = __float2bfloat16(vv[q] - hf);
        ho[q] = *(ushort*)&h; lo4[q] = *(ushort*)&l;
    }
    *hv = make_ushort4(ho[0], ho[1], ho[2], ho[3]);
    *lv = make_ushort4(lo4[0], lo4[1], lo4[2], lo4[3]);
}

static __device__ __forceinline__ ushort4 cvt_f4_bf16(float4 v) {
    float vv[4] = {v.x, v.y, v.z, v.w};
    ushort ho[4];
    #pragma unroll
    for (int q = 0; q < 4; ++q) {
        __hip_bfloat16 h = __float2bfloat16(vv[q]);
        ho[q] = *(ushort*)&h;
    }
    return make_ushort4(ho[0], ho[1], ho[2], ho[3]);
}

// ---------------- merged ternarize+pack+abs-sum: grid (96, 24), 512 thr.
__global__ __launch_bounds__(512) void pack_absum_kernel(
    const float* __restrict__ eW1, const float* __restrict__ eW2, const float* __restrict__ eW3,
    unsigned char* __restrict__ W1p8, unsigned char* __restrict__ W2p8,
    unsigned char* __restrict__ W3p8,
    float* __restrict__ p1, float* __restrict__ p2, float* __restrict__ p3)
{
    const int mat = blockIdx.y >> 3, e = blockIdx.y & 7;
    const int u = blockIdx.x * 512 + threadIdx.x;
    const float* src; unsigned char* dst; int valid = 1; float* P; int np;
    if (mat == 0) {
        int lane = u & 63, nblk = (u >> 6) & 31, ks = u >> 11;
        int n = nblk * 16 + (lane & 15), k = ks * 32 + (lane >> 4) * 8;
        src = eW1 + ((size_t)e * H1 + n) * IN_DIM + k;
        dst = W1p8 + (size_t)e * 393216
            + (size_t)ks * 16384 + (nblk >> 1) * 1024 + lane * 16 + (nblk & 1) * 8;
        P = p1; np = 96;
    } else if (mat == 1) {
        if (u >= 16384) return;
        int lane = u & 63, nblk = (u >> 6) & 15, ks = u >> 10;
        int n = nblk * 16 + (lane & 15), k = ks * 32 + (lane >> 4) * 8;
        src = eW2 + ((size_t)e * H2 + n) * H1 + k;
        dst = W2p8 + (size_t)e * 131072
            + (size_t)ks * 8192 + (nblk >> 1) * 1024 + lane * 16 + (nblk & 1) * 8;
        P = p2; np = 32;
    } else {
        if (u >= 2048) return;
        int lane = u & 63, nblk = (u >> 6) & 3, ks = u >> 8;
        int n = nblk * 16 + (lane & 15), k = ks * 32 + (lane >> 4) * 8;
        valid = (n < NC);
        src = eW3 + ((size_t)e * NC + (valid ? n : 0)) * H2 + k;
        dst = W3p8 + ((size_t)e * 2048 + u) * 8;
        P = p3; np = 4;
    }
    unsigned lo = 0, hi = 0;
    float s = 0.f;
    #pragma unroll
    for (int j = 0; j < 4; ++j) {
        float w = valid ? src[j] : 0.f;
        s += fabsf(w);
        unsigned c = (fabsf(w) > 0.05f) ? (w > 0.f ? 0x3Fu : 0xBFu) : 0u;
        lo |= c << (8 * j);
    }
    #pragma unroll
    for (int j = 0; j < 4; ++j) {
        float w = valid ? src[4 + j] : 0.f;
        s += fabsf(w);
        unsigned c = (fabsf(w) > 0.05f) ? (w > 0.f ? 0x3Fu : 0xBFu) : 0u;
        hi |= c << (8 * j);
    }
    *(uint2*)dst = make_uint2(lo, hi);
    const int lane = threadIdx.x & 63, wave = threadIdx.x >> 6;
    #pragma unroll
    for (int o = 32; o; o >>= 1) s += __shfl_down(s, o);
    __shared__ float red[8];
    if (lane == 0) red[wave] = s;
    __syncthreads();
    if (threadIdx.x == 0) {
        float t = 0.f;
        #pragma unroll
        for (int i = 0; i < 8; ++i) t += red[i];
        P[e * np + blockIdx.x] = t;
    }
}

// ---------------- finalize scales + zero dispatch counts
__global__ __launch_bounds__(64) void finalize_scales_kernel(
    const float* __restrict__ p1, const float* __restrict__ p2, const float* __restrict__ p3,
    float* __restrict__ s1, float* __restrict__ s2, float* __restrict__ s3,
    int* __restrict__ counts)
{
    int t = threadIdx.x;
    if (t < 8) {
        float a = 0.f;
        for (int i = 0; i < 96; ++i) a += p1[t * 96 + i];
        s1[t] = a / (float)(H1 * IN_DIM);
    } else if (t < 16) {
        int e = t - 8; float a = 0.f;
        for (int i = 0; i < 32; ++i) a += p2[e * 32 + i];
        s2[e] = a / (float)(H2 * H1);
    } else if (t < 24) {
        int e = t - 16; float a = 0.f;
        for (int i = 0; i < 4; ++i) a += p3[e * 4 + i];
        s3[e] = a / (float)(NC * H2);
    } else if (t < 32) {
        counts[t - 24] = 0;
    }
}

// ---------------- pack router weights into fragment-order hi/lo images
__global__ __launch_bounds__(512) void pack_router_kernel(
    const float* __restrict__ rW1, ushort* __restrict__ rw1hp, ushort* __restrict__ rw1lp,
    const float* __restrict__ rW2, ushort* __restrict__ rw2hp, ushort* __restrict__ rw2lp)
{
    int u = blockIdx.x * 512 + threadIdx.x;
    const float* src; ushort* dh; ushort* dl;
    if (u < 24576) {
        int lane = u & 63, nblk = (u >> 6) & 15, ks = u >> 10;
        int n = nblk * 16 + (lane & 15), k = ks * 32 + (lane >> 4) * 8;
        src = rW1 + (size_t)n * IN_DIM + k;
        dh = rw1hp + (size_t)u * 8; dl = rw1lp + (size_t)u * 8;
    } else {
        int v = u - 24576;
        if (v >= 4096) return;
        int lane = v & 63, nblk = (v >> 6) & 7, ks = v >> 9;
        int n = nblk * 16 + (lane & 15), k = ks * 32 + (lane >> 4) * 8;
        src = rW2 + (size_t)n * RH1 + k;
        dh = rw2hp + (size_t)v * 8; dl = rw2lp + (size_t)v * 8;
    }
    ushort oh[8], ol[8];
    #pragma unroll
    for (int j = 0; j < 8; ++j) {
        float w = src[j];
        __hip_bfloat16 h = __float2bfloat16(w);
        float hf = __bfloat162float(h);
        __hip_bfloat16 l = __float2bfloat16(w - hf);
        oh[j] = *(ushort*)&h; ol[j] = *(ushort*)&l;
    }
    ((ushort4*)dh)[0] = make_ushort4(oh[0], oh[1], oh[2], oh[3]);
    ((ushort4*)dh)[1] = make_ushort4(oh[4], oh[5], oh[6], oh[7]);
    ((ushort4*)dl)[0] = make_ushort4(ol[0], ol[1], ol[2], ol[3]);
    ((ushort4*)dl)[1] = make_ushort4(ol[4], ol[5], ol[6], ol[7]);
}

// ---------------- fused router, 1024 threads; X read as f32 + in-register decomposition
__global__ __launch_bounds__(1024) void router_fused_kernel(
    const float* __restrict__ x,
    const ushort* __restrict__ rw1hp, const ushort* __restrict__ rw1lp, const float* __restrict__ rb1,
    const ushort* __restrict__ rw2hp, const ushort* __restrict__ rw2lp, const float* __restrict__ rb2,
    const float* __restrict__ rW3, const float* __restrict__ rb3,
    float* __restrict__ router_p, float* __restrict__ gate,
    float* __restrict__ lb_out, int* __restrict__ t2)
{
    __shared__ __align__(16) unsigned char smem[134144];
    unsigned char* Wst = smem;
    ushort (*Xdh)[32][136] = (ushort(*)[32][136])(smem + 65536);
    ushort (*Xdl)[32][136] = (ushort(*)[32][136])(smem + 65536 + 17408);
    float (*h2s)[132]      = (float(*)[132])(smem + 65536);
    ushort (*h1hs)[264]    = (ushort(*)[264])(smem + 100352);
    ushort (*h1ls)[264]    = (ushort(*)[264])(smem + 117248);

    const int tid = threadIdx.x, wave = tid >> 6, lane = tid & 63;
    const int lm = lane & 15, lk = lane >> 4;
    const int r0 = blockIdx.x * 32;

    // X staging: thread covers row (tid>>5), cols (tid&31)*4 .. +3 of each 128-col chunk
    const int srow = tid >> 5;
    const int sc4r = (tid & 31) * 4;
    const float* sg = x + (size_t)(r0 + srow) * IN_DIM + sc4r;

    float4 sv = *(const float4*)sg;
    gl16(rw1hp + tid * 8, Wst + tid * 16);
    gl16(rw1lp + tid * 8, Wst + 16384 + tid * 16);
    {
        ushort4 hv, lv;
        decomp_f4(sv, &hv, &lv);
        *(ushort4*)&Xdh[0][srow][sc4r] = hv;
        *(ushort4*)&Xdl[0][srow][sc4r] = lv;
    }
    __syncthreads();

    // ---- layer 1
    {
        f32x4 acc[2] = {};
        for (int s = 0; s < 24; ++s) {
            const int c = s >> 2;
            const unsigned char* curh = Wst + (s & 1) * 32768;
            const unsigned char* curl = curh + 16384;
            if (s + 1 < 24) {
                unsigned char* dst = Wst + ((s + 1) & 1) * 32768;
                gl16(rw1hp + (size_t)(s + 1) * 8192 + tid * 8, dst + tid * 16);
                gl16(rw1lp + (size_t)(s + 1) * 8192 + tid * 8, dst + 16384 + tid * 16);
            } else {
                if (tid < 512) gl16(rw2hp + tid * 8, Wst + tid * 16);
                else           gl16(rw2lp + (tid & 511) * 8, Wst + 16384 + (tid & 511) * 16);
            }
            if ((s & 3) == 0 && c < 5)
                sv = *(const float4*)(sg + (c + 1) * CHK);
            const ushort (*Xch)[136] = Xdh[c & 1];
            const ushort (*Xcl)[136] = Xdl[c & 1];
            const int ko = (s & 3) * 32 + lk * 8;
            bf16x8 ah0 = *(const bf16x8*)&Xch[lm][ko];
            bf16x8 al0 = *(const bf16x8*)&Xcl[lm][ko];
            bf16x8 ah1 = *(const bf16x8*)&Xch[16 + lm][ko];
            bf16x8 al1 = *(const bf16x8*)&Xcl[16 + lm][ko];
            bf16x8 bh = *(const bf16x8*)(curh + (wave * 64 + lane) * 16);
            bf16x8 bl = *(const bf16x8*)(curl + (wave * 64 + lane) * 16);
            acc[0] = mfma16(ah0, bh, acc[0]);
            acc[0] = mfma16(ah0, bl, acc[0]);
            acc[0] = mfma16(al0, bh, acc[0]);
            acc[1] = mfma16(ah1, bh, acc[1]);
            acc[1] = mfma16(ah1, bl, acc[1]);
            acc[1] = mfma16(al1, bh, acc[1]);
            if ((s & 3) == 2 && c < 5) {
                ushort4 hv, lv;
                decomp_f4(sv, &hv, &lv);
                *(ushort4*)&Xdh[(c + 1) & 1][srow][sc4r] = hv;
                *(ushort4*)&Xdl[(c + 1) & 1][srow][sc4r] = lv;
            }
            __syncthreads();
        }
        int col = wave * 16 + lm;
        float bv = rb1[col];
        #pragma unroll
        for (int m = 0; m < 2; ++m)
            #pragma unroll
            for (int r = 0; r < 4; ++r) {
                float v = acc[m][r] + bv;
                v = v > 0.f ? v : 0.f;
                __hip_bfloat16 h = __float2bfloat16(v);
                float hf = __bfloat162float(h);
                __hip_bfloat16 l = __float2bfloat16(v - hf);
                int row = m * 16 + lk * 4 + r;
                h1hs[row][col] = *(ushort*)&h;
                h1ls[row][col] = *(ushort*)&l;
            }
    }
    __syncthreads();

    // ---- layer 2
    {
        const int mt = wave >> 3, nb = wave & 7;
        f32x4 acc2 = {};
        for (int s = 0; s < 8; ++s) {
            const unsigned char* curh = Wst + (s & 1) * 32768;
            const unsigned char* curl = curh + 16384;
            if (s + 1 < 8) {
                unsigned char* dst = Wst + ((s + 1) & 1) * 32768;
                if (tid < 512) gl16(rw2hp + (size_t)(s + 1) * 4096 + tid * 8, dst + tid * 16);
                else           gl16(rw2lp + (size_t)(s + 1) * 4096 + (tid & 511) * 8, dst + 16384 + (tid & 511) * 16);
            }
            const int ko = s * 32 + lk * 8;
            bf16x8 ah = *(const bf16x8*)&h1hs[mt * 16 + lm][ko];
            bf16x8 al = *(const bf16x8*)&h1ls[mt * 16 + lm][ko];
            bf16x8 bh = *(const bf16x8*)(curh + (nb * 64 + lane) * 16);
            bf16x8 bl = *(const bf16x8*)(curl + (nb * 64 + lane) * 16);
            acc2 = mfma16(ah, bh, acc2);
            acc2 = mfma16(ah, bl, acc2);
            acc2 = mfma16(al, bh, acc2);
            __syncthreads();
        }
        int col2 = nb * 16 + lm;
        float bv = rb2[col2];
        #pragma unroll
        for (int r = 0; r < 4; ++r) {
            float v = acc2[r] + bv;
            h2s[mt * 16 + lk * 4 + r][col2] = v > 0.f ? v : 0.f;
        }
    }
    __syncthreads();

    // ---- head
    const int o = lane >> 3, kq = lane & 7;
    #pragma unroll
    for (int i = 0; i < 2; ++i) {
        int rloc = wave * 2 + i;
        int b = r0 + rloc;
        float s = 0.f;
        #pragma unroll
        for (int q = 0; q < 4; ++q) {
            float4 hv = *(const float4*)&h2s[rloc][kq * 16 + q * 4];
            float4 wv = *(const float4*)&rW3[o * RH2 + kq * 16 + q * 4];
            s += hv.x * wv.x + hv.y * wv.y + hv.z * wv.z + hv.w * wv.w;
        }
        s += __shfl_xor(s, 1);
        s += __shfl_xor(s, 2);
        s += __shfl_xor(s, 4);
        float logit = s + rb3[o];
        float l[8];
        #pragma unroll
        for (int j = 0; j < 8; ++j) l[j] = __shfl(logit, j * 8);
        float m = l[0];
        #pragma unroll
        for (int j = 1; j < 8; ++j) m = fmaxf(m, l[j]);
        float p[8]; float sum = 0.f;
        #pragma unroll
        for (int j = 0; j < 8; ++j) { p[j] = expf(l[j] - m); sum += p[j]; }
        float inv = 1.f / sum;
        #pragma unroll
        for (int j = 0; j < 8; ++j) p[j] *= inv;
        int i1 = 0; float v1 = p[0];
        #pragma unroll
        for (int j = 1; j < 8; ++j) if (p[j] > v1) { v1 = p[j]; i1 = j; }
        int i2 = -1; float v2 = -1.f;
        #pragma unroll
        for (int j = 0; j < 8; ++j) if (j != i1 && p[j] > v2) { v2 = p[j]; i2 = j; }
        if (lane < 8) {
            router_p[(size_t)b * 8 + lane] = p[lane];
            float gv = (lane == i1) ? v1 * 0.5f : ((lane == i2) ? v2 * 0.5f : 0.f);
            gate[(size_t)b * 8 + lane] = gv;
        }
        if (lane == 0) t2[b] = i1 | (i2 << 8);
    }
    if (blockIdx.x == 0 && tid == 0) lb_out[0] = 0.f;
}

// ---------------- build dispatch lists
__global__ __launch_bounds__(256) void build_lists_kernel(
    const int* __restrict__ t2, int* __restrict__ counts, int* __restrict__ ent)
{
    __shared__ int hist[8], base[8];
    const int r = blockIdx.x * 256 + threadIdx.x;
    if (threadIdx.x < 8) hist[threadIdx.x] = 0;
    __syncthreads();
    const int v = t2[r];
    const int i1 = v & 255, i2 = v >> 8;
    const int rk1 = atomicAdd(&hist[i1], 1);
    const int rk2 = atomicAdd(&hist[i2], 1);
    __syncthreads();
    if (threadIdx.x < 8) base[threadIdx.x] = atomicAdd(&counts[threadIdx.x], hist[threadIdx.x]);
    __syncthreads();
    ent[i1 * B_ROWS + base[i1] + rk1] = (r << 1);
    ent[i2 * B_ROWS + base[i2] + rk2] = (r << 1) | 1;
}

// ---------------- sparse fused expert kernel: BM=64, 1024 thr, balanced affinity,
// 2-step L1 intervals, 4-step L2 intervals, pair-packed W; X read as f32 + in-reg cvt.
__global__ __launch_bounds__(1024) void expert_fused_kernel(
    const float* __restrict__ x,
    const unsigned char* __restrict__ W1p8, const unsigned char* __restrict__ W2p8,
    const unsigned char* __restrict__ W3p8,
    const float* __restrict__ s1, const float* __restrict__ s2, const float* __restrict__ s3,
    const float* __restrict__ eb1, const float* __restrict__ eb2, const float* __restrict__ eb3,
    const float* __restrict__ gate,
    const int* __restrict__ counts, const int* __restrict__ ent,
    float* __restrict__ S0, float* __restrict__ S1)
{
    int pfx[9]; pfx[0] = 0;
    #pragma unroll
    for (int i = 0; i < 8; ++i) pfx[i + 1] = pfx[i] + ((counts[i] + 63) >> 6);
    const int T = pfx[8];
    const int R = (T + 7) >> 3;
    const int xcd = blockIdx.x & 7, j = blockIdx.x >> 3;
    if (j >= R) return;
    const int g = xcd * R + j;
    if (g >= T) return;
    int e = 0;
    #pragma unroll
    for (int i = 0; i < 7; ++i) if (g >= pfx[i + 1]) e = i + 1;
    const int t = g - pfx[e];
    const int cnt = counts[e];

    __shared__ __align__(16) unsigned char smem[151552];
    unsigned char* Wst = smem;
    __hip_bfloat16 (*A2s)[264] = (__hip_bfloat16(*)[264])(smem + 32768);
    __hip_bfloat16 (*A1s)[520] = (__hip_bfloat16(*)[520])(smem + 66560);
    ushort (*Xd)[64][72]       = (ushort(*)[64][72])(smem + 133120);
    __shared__ int rowL[64];
    __shared__ int slotL[64];
    __shared__ float gL[64];

    const int tid = threadIdx.x;
    const int wave = tid >> 6;
    const int lane = tid & 63;
    const int lm = lane & 15;
    const int lk = lane >> 4;

    if (tid < 64) {
        int idx = t * 64 + tid;
        if (idx < cnt) {
            int entv = ent[e * B_ROWS + idx];
            int r = entv >> 1;
            rowL[tid] = r;
            slotL[tid] = entv & 1;
            gL[tid] = gate[(size_t)r * NE + e];
        } else {
            rowL[tid] = -1; slotL[tid] = 0; gL[tid] = 0.f;
        }
    }
    __syncthreads();

    const int srow = tid >> 4;
    const int sc4  = (tid & 15) * 4;
    int SR = rowL[srow]; if (SR < 0) SR = 0;
    const float* sg = x + (size_t)SR * IN_DIM + sc4;
    const unsigned char* Wsrc1 = W1p8 + (size_t)e * 393216;
    const unsigned char* Wsrc2 = W2p8 + (size_t)e * 131072;
    const unsigned char* Wsrc3 = W3p8 + (size_t)e * 16384;

    float4 sv = *(const float4*)sg;
    gl16(Wsrc1 + tid * 16, Wst + tid * 16);
    gl16(Wsrc1 + 16384 + tid * 16, Wst + 16384 + tid * 16);
    *(ushort4*)&Xd[0][srow][sc4] = cvt_f4_bf16(sv);
    __syncthreads();

    // ---- layer 1: 12 intervals x 2 K-steps
    {
        f32x4 acc[4][2] = {};
        const int w2 = wave * 2;
        for (int i = 0; i < 12; ++i) {
            const unsigned char* buf = Wst + (i & 1) * 32768;
            if (i + 1 < 12) {
                unsigned char* dst = Wst + ((i + 1) & 1) * 32768;
                gl16(Wsrc1 + (size_t)(i + 1) * 32768 + tid * 16, dst + tid * 16);
                gl16(Wsrc1 + (size_t)(i + 1) * 32768 + 16384 + tid * 16, dst + 16384 + tid * 16);
            } else {
                gl16(Wsrc2 + tid * 16, Wst + tid * 16);
                gl16(Wsrc2 + 16384 + tid * 16, Wst + 16384 + tid * 16);
            }
            if (i + 1 < 12) sv = *(const float4*)(sg + (i + 1) * CHKX);
            const ushort (*Xc)[72] = Xd[i & 1];
            #pragma unroll
            for (int k2 = 0; k2 < 2; ++k2) {
                const unsigned char* cur = buf + k2 * 16384;
                const int ko = k2 * 32 + lk * 8;
                bf16x8 a0 = *(const bf16x8*)&Xc[     lm][ko];
                bf16x8 a1 = *(const bf16x8*)&Xc[16 + lm][ko];
                bf16x8 a2 = *(const bf16x8*)&Xc[32 + lm][ko];
                bf16x8 a3 = *(const bf16x8*)&Xc[48 + lm][ko];
                uint4 pw4 = *(const uint4*)(cur + wave * 1024 + lane * 16);
                bf16x8 b0 = expand_frag(make_uint2(pw4.x, pw4.y));
                bf16x8 b1 = expand_frag(make_uint2(pw4.z, pw4.w));
                acc[0][0] = mfma16(a0, b0, acc[0][0]);
                acc[1][0] = mfma16(a1, b0, acc[1][0]);
                acc[2][0] = mfma16(a2, b0, acc[2][0]);
                acc[3][0] = mfma16(a3, b0, acc[3][0]);
                acc[0][1] = mfma16(a0, b1, acc[0][1]);
                acc[1][1] = mfma16(a1, b1, acc[1][1]);
                acc[2][1] = mfma16(a2, b1, acc[2][1]);
                acc[3][1] = mfma16(a3, b1, acc[3][1]);
            }
            if (i + 1 < 12) *(ushort4*)&Xd[(i + 1) & 1][srow][sc4] = cvt_f4_bf16(sv);
            __syncthreads();
        }
        const float* bias = eb1 + e * H1;
        const float sc = s1[e];
        #pragma unroll
        for (int n = 0; n < 2; ++n) {
            int ncol = (w2 + n) * 16 + lm;
            float bv = bias[ncol];
            #pragma unroll
            for (int m = 0; m < 4; ++m)
                #pragma unroll
                for (int r = 0; r < 4; ++r) {
                    float v = fmaf(acc[m][n][r], sc, bv);
                    v = v > 0.f ? v : 0.f;
                    A1s[m * 16 + lk * 4 + r][ncol] = __float2bfloat16(v);
                }
        }
    }
    __syncthreads();

    // ---- layer 2: 4 intervals x 4 K-steps, 32KB images
    {
        const int mt = wave >> 3, ntw = wave & 7;
        f32x4 acc[2][2] = {};
        for (int i = 0; i < 4; ++i) {
            const unsigned char* buf = Wst + (i & 1) * 32768;
            if (i + 1 < 4) {
                unsigned char* dst = Wst + ((i + 1) & 1) * 32768;
                gl16(Wsrc2 + (size_t)(i + 1) * 32768 + tid * 16, dst + tid * 16);
                gl16(Wsrc2 + (size_t)(i + 1) * 32768 + 16384 + tid * 16, dst + 16384 + tid * 16);
            } else {
                gl16(Wsrc3 + tid * 16, Wst + tid * 16);
            }
            #pragma unroll
            for (int k4 = 0; k4 < 4; ++k4) {
                const unsigned char* cur = buf + k4 * 8192;
                const int s = i * 4 + k4;
                const int ko = s * 32 + lk * 8;
                bf16x8 a0 = *(const bf16x8*)&A1s[mt * 32 +      lm][ko];
                bf16x8 a1 = *(const bf16x8*)&A1s[mt * 32 + 16 + lm][ko];
                uint4 pw4 = *(const uint4*)(cur + ntw * 1024 + lane * 16);
                bf16x8 b0 = expand_frag(make_uint2(pw4.x, pw4.y));
                bf16x8 b1 = expand_frag(make_uint2(pw4.z, pw4.w));
                acc[0][0] = mfma16(a0, b0, acc[0][0]);
                acc[1][0] = mfma16(a1, b0, acc[1][0]);
                acc[0][1] = mfma16(a0, b1, acc[0][1]);
                acc[1][1] = mfma16(a1, b1, acc[1][1]);
            }
            __syncthreads();
        }
        const float* bias = eb2 + e * H2;
        const float sc = s2[e];
        #pragma unroll
        for (int n = 0; n < 2; ++n) {
            int ncol = (ntw * 2 + n) * 16 + lm;
            float bv = bias[ncol];
            #pragma unroll
            for (int m = 0; m < 2; ++m)
                #pragma unroll
                for (int r = 0; r < 4; ++r) {
                    float v = fmaf(acc[m][n][r], sc, bv);
                    v = v > 0.f ? v : 0.f;
                    A2s[mt * 32 + m * 16 + lk * 4 + r][ncol] = __float2bfloat16(v);
                }
        }
    }
    __syncthreads();

    // ---- layer 3: W3 flat panel resident at Wst+0
    {
        const int mt = wave & 3, nt = wave >> 2;
        f32x4 acc = {};
        #pragma unroll
        for (int s = 0; s < 8; ++s) {
            bf16x8 a = *(const bf16x8*)&A2s[mt * 16 + lm][s * 32 + lk * 8];
            uint2 pw = *(const uint2*)(Wst + ((s * 4 + nt) * 64 + lane) * 8);
            bf16x8 b = expand_frag(pw);
            acc = mfma16(a, b, acc);
        }
        int col = nt * 16 + lm;
        if (col < NC) {
            const float bv = eb3[e * NC + col];
            const float sc = s3[e];
            #pragma unroll
            for (int r = 0; r < 4; ++r) {
                int row = mt * 16 + lk * 4 + r;
                int R2 = rowL[row];
                if (R2 >= 0) {
                    float v = gL[row] * fmaf(acc[r], sc, bv);
                    float* Sb = slotL[row] ? S1 : S0;
                    Sb[(size_t)R2 * 64 + col] = v;
                }
            }
        }
    }
}

// ---------------- combine
__global__ __launch_bounds__(256) void combine_kernel(
    const float* __restrict__ S0, const float* __restrict__ S1, float* __restrict__ out)
{
    int i = blockIdx.x * 256 + threadIdx.x;
    if (i < B_ROWS * NC) {
        int row = i / NC, col = i % NC;
        out[i] = S0[(size_t)row * 64 + col] + S1[(size_t)row * 64 + col];
    }
}

extern "C" void kernel_launch(void* const* d_in, const int* in_sizes, int n_in,
                              void* d_out, int out_size, void* d_ws, size_t ws_size,
                              hipStream_t stream) {
    const float* x   = (const float*)d_in[0];
    const float* rW1 = (const float*)d_in[1];
    const float* rb1 = (const float*)d_in[2];
    const float* rW2 = (const float*)d_in[3];
    const float* rb2 = (const float*)d_in[4];
    const float* rW3 = (const float*)d_in[5];
    const float* rb3 = (const float*)d_in[6];
    const float* eW1 = (const float*)d_in[7];
    const float* eb1 = (const float*)d_in[8];
    const float* eW2 = (const float*)d_in[9];
    const float* eb2 = (const float*)d_in[10];
    const float* eW3 = (const float*)d_in[11];
    const float* eb3 = (const float*)d_in[12];

    float* out_main = (float*)d_out;
    float* router_p = out_main + (size_t)B_ROWS * NC;
    float* lb_out   = router_p + (size_t)B_ROWS * NE;

    char* ws = (char*)d_ws;
    size_t off = 0;
    unsigned char* W1p8 = (unsigned char*)(ws + off); off += (size_t)NE * 49152 * 8;
    unsigned char* W2p8 = (unsigned char*)(ws + off); off += (size_t)NE * 16384 * 8;
    unsigned char* W3p8 = (unsigned char*)(ws + off); off += (size_t)NE * 2048 * 8;
    float* S0   = (float*)(ws + off);  off += (size_t)B_ROWS * 64 * 4;
    float* S1   = (float*)(ws + off);  off += (size_t)B_ROWS * 64 * 4;
    ushort* rw1hp = (ushort*)(ws + off); off += (size_t)24576 * 8 * 2;
    ushort* rw1lp = (ushort*)(ws + off); off += (size_t)24576 * 8 * 2;
    ushort* rw2hp = (ushort*)(ws + off); off += (size_t)4096 * 8 * 2;
    ushort* rw2lp = (ushort*)(ws + off); off += (size_t)4096 * 8 * 2;
    float* gate = (float*)(ws + off);  off += (size_t)B_ROWS * NE * 4;
    int*   ent  = (int*)(ws + off);    off += (size_t)NE * B_ROWS * 4;
    int*   t2   = (int*)(ws + off);    off += (size_t)B_ROWS * 4;
    int* counts = (int*)(ws + off);    off += 256;
    float* s1   = (float*)(ws + off);  off += 256;
    float* s2   = (float*)(ws + off);  off += 256;
    float* s3   = (float*)(ws + off);  off += 256;
    float* p1   = (float*)(ws + off);  off += NE * 96 * 4;
    float* p2   = (float*)(ws + off);  off += NE * 32 * 4;
    float* p3   = (float*)(ws + off);  off += NE * 4 * 4;

    // 1) prep (decomp_x eliminated — X decomposed in-register by consumers)
    pack_absum_kernel<<<dim3(96, 24), 512, 0, stream>>>(
        eW1, eW2, eW3, W1p8, W2p8, W3p8, p1, p2, p3);
    pack_router_kernel<<<56, 512, 0, stream>>>(rW1, rw1hp, rw1lp, rW2, rw2hp, rw2lp);
    finalize_scales_kernel<<<1, 64, 0, stream>>>(p1, p2, p3, s1, s2, s3, counts);

    // 2) fused router (reads x f32 directly)
    router_fused_kernel<<<B_ROWS / 32, 1024, 0, stream>>>(
        x, rw1hp, rw1lp, rb1, rw2hp, rw2lp, rb2, rW3, rb3, router_p, gate, lb_out, t2);
    build_lists_kernel<<<B_ROWS / 256, 256, 0, stream>>>(t2, counts, ent);

    // 3) sparse fused experts (reads x f32 directly) + combine
    expert_fused_kernel<<<1024, 1024, 0, stream>>>(
        x, W1p8, W2p8, W3p8, s1, s2, s3, eb1, eb2, eb3, gate, counts, ent, S0, S1);
    combine_kernel<<<(B_ROWS * NC + 255) / 256, 256, 0, stream>>>(S0, S1, out_main);
}

// Round 23
// 140.551 us; speedup vs baseline: 1.6498x; 1.0343x over previous
//
#include <hip/hip_runtime.h>
#include <hip/hip_bf16.h>

typedef __attribute__((ext_vector_type(4))) float f32x4;
typedef __attribute__((ext_vector_type(8))) short bf16x8;

#define B_ROWS 16384
#define IN_DIM 768
#define H1 512
#define H2 256
#define NC 50
#define NE 8
#define RH1 256
#define RH2 128
#define CHK 128

static __device__ __forceinline__ f32x4 mfma16(bf16x8 a, bf16x8 b, f32x4 c) {
    return __builtin_amdgcn_mfma_f32_16x16x32_bf16(a, b, c, 0, 0, 0);
}

typedef __attribute__((address_space(1))) const unsigned int gas_u32;
typedef __attribute__((address_space(3))) unsigned int las_u32;
static __device__ __forceinline__ void gl16(const void* g, void* l) {
    __builtin_amdgcn_global_load_lds((gas_u32*)g, (las_u32*)l, 16, 0, 0);
}

// expand 8 ternary byte-codes (bf16 high byte: 0x3F/0xBF/0x00) to exact bf16x8
static __device__ __forceinline__ bf16x8 expand_frag(uint2 pw) {
    unsigned q0 = (pw.x & 0x01010101u) << 7;
    unsigned q1 = (pw.y & 0x01010101u) << 7;
    union { unsigned u[4]; bf16x8 v; } r;
    r.u[0] = __builtin_amdgcn_perm(pw.x, q0, 0x05010400u);
    r.u[1] = __builtin_amdgcn_perm(pw.x, q0, 0x07030602u);
    r.u[2] = __builtin_amdgcn_perm(pw.y, q1, 0x05010400u);
    r.u[3] = __builtin_amdgcn_perm(pw.y, q1, 0x07030602u);
    return r.v;
}

// decompose float4 -> bf16 hi/lo ushort4 pair
static __device__ __forceinline__ void decomp_f4(float4 v, ushort4* hv, ushort4* lv) {
    float vv[4] = {v.x, v.y, v.z, v.w};
    ushort ho[4], lo4[4];
    #pragma unroll
    for (int q = 0; q < 4; ++q) {
        __hip_bfloat16 h = __float2bfloat16(vv[q]);
        float hf = __bfloat162float(h);
        __hip_bfloat16 l = __float2bfloat16(vv[q] - hf);
        ho[q] = *(ushort*)&h; lo4[q] = *(ushort*)&l;
    }
    *hv = make_ushort4(ho[0], ho[1], ho[2], ho[3]);
    *lv = make_ushort4(lo4[0], lo4[1], lo4[2], lo4[3]);
}

static __device__ __forceinline__ ushort4 cvt_f4_bf16(float4 v) {
    float vv[4] = {v.x, v.y, v.z, v.w};
    ushort ho[4];
    #pragma unroll
    for (int q = 0; q < 4; ++q) {
        __hip_bfloat16 h = __float2bfloat16(vv[q]);
        ho[q] = *(ushort*)&h;
    }
    return make_ushort4(ho[0], ho[1], ho[2], ho[3]);
}

// ---------------- merged ternarize+pack+abs-sum: grid (96, 24), 512 thr.
__global__ __launch_bounds__(512) void pack_absum_kernel(
    const float* __restrict__ eW1, const float* __restrict__ eW2, const float* __restrict__ eW3,
    unsigned char* __restrict__ W1p8, unsigned char* __restrict__ W2p8,
    unsigned char* __restrict__ W3p8,
    float* __restrict__ p1, float* __restrict__ p2, float* __restrict__ p3)
{
    const int mat = blockIdx.y >> 3, e = blockIdx.y & 7;
    const int u = blockIdx.x * 512 + threadIdx.x;
    const float* src; unsigned char* dst; int valid = 1; float* P; int np;
    if (mat == 0) {
        int lane = u & 63, nblk = (u >> 6) & 31, ks = u >> 11;
        int n = nblk * 16 + (lane & 15), k = ks * 32 + (lane >> 4) * 8;
        src = eW1 + ((size_t)e * H1 + n) * IN_DIM + k;
        dst = W1p8 + (size_t)e * 393216
            + (size_t)ks * 16384 + (nblk >> 1) * 1024 + lane * 16 + (nblk & 1) * 8;
        P = p1; np = 96;
    } else if (mat == 1) {
        if (u >= 16384) return;
        int lane = u & 63, nblk = (u >> 6) & 15, ks = u >> 10;
        int n = nblk * 16 + (lane & 15), k = ks * 32 + (lane >> 4) * 8;
        src = eW2 + ((size_t)e * H2 + n) * H1 + k;
        dst = W2p8 + (size_t)e * 131072
            + (size_t)ks * 8192 + (nblk >> 1) * 1024 + lane * 16 + (nblk & 1) * 8;
        P = p2; np = 32;
    } else {
        if (u >= 2048) return;
        int lane = u & 63, nblk = (u >> 6) & 3, ks = u >> 8;
        int n = nblk * 16 + (lane & 15), k = ks * 32 + (lane >> 4) * 8;
        valid = (n < NC);
        src = eW3 + ((size_t)e * NC + (valid ? n : 0)) * H2 + k;
        dst = W3p8 + ((size_t)e * 2048 + u) * 8;
        P = p3; np = 4;
    }
    unsigned lo = 0, hi = 0;
    float s = 0.f;
    #pragma unroll
    for (int j = 0; j < 4; ++j) {
        float w = valid ? src[j] : 0.f;
        s += fabsf(w);
        unsigned c = (fabsf(w) > 0.05f) ? (w > 0.f ? 0x3Fu : 0xBFu) : 0u;
        lo |= c << (8 * j);
    }
    #pragma unroll
    for (int j = 0; j < 4; ++j) {
        float w = valid ? src[4 + j] : 0.f;
        s += fabsf(w);
        unsigned c = (fabsf(w) > 0.05f) ? (w > 0.f ? 0x3Fu : 0xBFu) : 0u;
        hi |= c << (8 * j);
    }
    *(uint2*)dst = make_uint2(lo, hi);
    const int lane = threadIdx.x & 63, wave = threadIdx.x >> 6;
    #pragma unroll
    for (int o = 32; o; o >>= 1) s += __shfl_down(s, o);
    __shared__ float red[8];
    if (lane == 0) red[wave] = s;
    __syncthreads();
    if (threadIdx.x == 0) {
        float t = 0.f;
        #pragma unroll
        for (int i = 0; i < 8; ++i) t += red[i];
        P[e * np + blockIdx.x] = t;
    }
}

// ---------------- finalize scales + zero dispatch counts
__global__ __launch_bounds__(64) void finalize_scales_kernel(
    const float* __restrict__ p1, const float* __restrict__ p2, const float* __restrict__ p3,
    float* __restrict__ s1, float* __restrict__ s2, float* __restrict__ s3,
    int* __restrict__ counts)
{
    int t = threadIdx.x;
    if (t < 8) {
        float a = 0.f;
        for (int i = 0; i < 96; ++i) a += p1[t * 96 + i];
        s1[t] = a / (float)(H1 * IN_DIM);
    } else if (t < 16) {
        int e = t - 8; float a = 0.f;
        for (int i = 0; i < 32; ++i) a += p2[e * 32 + i];
        s2[e] = a / (float)(H2 * H1);
    } else if (t < 24) {
        int e = t - 16; float a = 0.f;
        for (int i = 0; i < 4; ++i) a += p3[e * 4 + i];
        s3[e] = a / (float)(NC * H2);
    } else if (t < 32) {
        counts[t - 24] = 0;
    }
}

// ---------------- pack router weights into fragment-order hi/lo images
__global__ __launch_bounds__(512) void pack_router_kernel(
    const float* __restrict__ rW1, ushort* __restrict__ rw1hp, ushort* __restrict__ rw1lp,
    const float* __restrict__ rW2, ushort* __restrict__ rw2hp, ushort* __restrict__ rw2lp)
{
    int u = blockIdx.x * 512 + threadIdx.x;
    const float* src; ushort* dh; ushort* dl;
    if (u < 24576) {
        int lane = u & 63, nblk = (u >> 6) & 15, ks = u >> 10;
        int n = nblk * 16 + (lane & 15), k = ks * 32 + (lane >> 4) * 8;
        src = rW1 + (size_t)n * IN_DIM + k;
        dh = rw1hp + (size_t)u * 8; dl = rw1lp + (size_t)u * 8;
    } else {
        int v = u - 24576;
        if (v >= 4096) return;
        int lane = v & 63, nblk = (v >> 6) & 7, ks = v >> 9;
        int n = nblk * 16 + (lane & 15), k = ks * 32 + (lane >> 4) * 8;
        src = rW2 + (size_t)n * RH1 + k;
        dh = rw2hp + (size_t)v * 8; dl = rw2lp + (size_t)v * 8;
    }
    ushort oh[8], ol[8];
    #pragma unroll
    for (int j = 0; j < 8; ++j) {
        float w = src[j];
        __hip_bfloat16 h = __float2bfloat16(w);
        float hf = __bfloat162float(h);
        __hip_bfloat16 l = __float2bfloat16(w - hf);
        oh[j] = *(ushort*)&h; ol[j] = *(ushort*)&l;
    }
    ((ushort4*)dh)[0] = make_ushort4(oh[0], oh[1], oh[2], oh[3]);
    ((ushort4*)dh)[1] = make_ushort4(oh[4], oh[5], oh[6], oh[7]);
    ((ushort4*)dl)[0] = make_ushort4(ol[0], ol[1], ol[2], ol[3]);
    ((ushort4*)dl)[1] = make_ushort4(ol[4], ol[5], ol[6], ol[7]);
}

// ---------------- fused router, 1024 threads; X read as f32 + in-register decomposition
__global__ __launch_bounds__(1024) void router_fused_kernel(
    const float* __restrict__ x,
    const ushort* __restrict__ rw1hp, const ushort* __restrict__ rw1lp, const float* __restrict__ rb1,
    const ushort* __restrict__ rw2hp, const ushort* __restrict__ rw2lp, const float* __restrict__ rb2,
    const float* __restrict__ rW3, const float* __restrict__ rb3,
    float* __restrict__ router_p, float* __restrict__ gate,
    float* __restrict__ lb_out, int* __restrict__ t2)
{
    __shared__ __align__(16) unsigned char smem[134144];
    unsigned char* Wst = smem;
    ushort (*Xdh)[32][136] = (ushort(*)[32][136])(smem + 65536);
    ushort (*Xdl)[32][136] = (ushort(*)[32][136])(smem + 65536 + 17408);
    float (*h2s)[132]      = (float(*)[132])(smem + 65536);
    ushort (*h1hs)[264]    = (ushort(*)[264])(smem + 100352);
    ushort (*h1ls)[264]    = (ushort(*)[264])(smem + 117248);

    const int tid = threadIdx.x, wave = tid >> 6, lane = tid & 63;
    const int lm = lane & 15, lk = lane >> 4;
    const int r0 = blockIdx.x * 32;

    const int srow = tid >> 5;
    const int sc4r = (tid & 31) * 4;
    const float* sg = x + (size_t)(r0 + srow) * IN_DIM + sc4r;

    float4 sv = *(const float4*)sg;
    gl16(rw1hp + tid * 8, Wst + tid * 16);
    gl16(rw1lp + tid * 8, Wst + 16384 + tid * 16);
    {
        ushort4 hv, lv;
        decomp_f4(sv, &hv, &lv);
        *(ushort4*)&Xdh[0][srow][sc4r] = hv;
        *(ushort4*)&Xdl[0][srow][sc4r] = lv;
    }
    __syncthreads();

    // ---- layer 1
    {
        f32x4 acc[2] = {};
        for (int s = 0; s < 24; ++s) {
            const int c = s >> 2;
            const unsigned char* curh = Wst + (s & 1) * 32768;
            const unsigned char* curl = curh + 16384;
            if (s + 1 < 24) {
                unsigned char* dst = Wst + ((s + 1) & 1) * 32768;
                gl16(rw1hp + (size_t)(s + 1) * 8192 + tid * 8, dst + tid * 16);
                gl16(rw1lp + (size_t)(s + 1) * 8192 + tid * 8, dst + 16384 + tid * 16);
            } else {
                if (tid < 512) gl16(rw2hp + tid * 8, Wst + tid * 16);
                else           gl16(rw2lp + (tid & 511) * 8, Wst + 16384 + (tid & 511) * 16);
            }
            if ((s & 3) == 0 && c < 5)
                sv = *(const float4*)(sg + (c + 1) * CHK);
            const ushort (*Xch)[136] = Xdh[c & 1];
            const ushort (*Xcl)[136] = Xdl[c & 1];
            const int ko = (s & 3) * 32 + lk * 8;
            bf16x8 ah0 = *(const bf16x8*)&Xch[lm][ko];
            bf16x8 al0 = *(const bf16x8*)&Xcl[lm][ko];
            bf16x8 ah1 = *(const bf16x8*)&Xch[16 + lm][ko];
            bf16x8 al1 = *(const bf16x8*)&Xcl[16 + lm][ko];
            bf16x8 bh = *(const bf16x8*)(curh + (wave * 64 + lane) * 16);
            bf16x8 bl = *(const bf16x8*)(curl + (wave * 64 + lane) * 16);
            acc[0] = mfma16(ah0, bh, acc[0]);
            acc[0] = mfma16(ah0, bl, acc[0]);
            acc[0] = mfma16(al0, bh, acc[0]);
            acc[1] = mfma16(ah1, bh, acc[1]);
            acc[1] = mfma16(ah1, bl, acc[1]);
            acc[1] = mfma16(al1, bh, acc[1]);
            if ((s & 3) == 2 && c < 5) {
                ushort4 hv, lv;
                decomp_f4(sv, &hv, &lv);
                *(ushort4*)&Xdh[(c + 1) & 1][srow][sc4r] = hv;
                *(ushort4*)&Xdl[(c + 1) & 1][srow][sc4r] = lv;
            }
            __syncthreads();
        }
        int col = wave * 16 + lm;
        float bv = rb1[col];
        #pragma unroll
        for (int m = 0; m < 2; ++m)
            #pragma unroll
            for (int r = 0; r < 4; ++r) {
                float v = acc[m][r] + bv;
                v = v > 0.f ? v : 0.f;
                __hip_bfloat16 h = __float2bfloat16(v);
                float hf = __bfloat162float(h);
                __hip_bfloat16 l = __float2bfloat16(v - hf);
                int row = m * 16 + lk * 4 + r;
                h1hs[row][col] = *(ushort*)&h;
                h1ls[row][col] = *(ushort*)&l;
            }
    }
    __syncthreads();

    // ---- layer 2
    {
        const int mt = wave >> 3, nb = wave & 7;
        f32x4 acc2 = {};
        for (int s = 0; s < 8; ++s) {
            const unsigned char* curh = Wst + (s & 1) * 32768;
            const unsigned char* curl = curh + 16384;
            if (s + 1 < 8) {
                unsigned char* dst = Wst + ((s + 1) & 1) * 32768;
                if (tid < 512) gl16(rw2hp + (size_t)(s + 1) * 4096 + tid * 8, dst + tid * 16);
                else           gl16(rw2lp + (size_t)(s + 1) * 4096 + (tid & 511) * 8, dst + 16384 + (tid & 511) * 16);
            }
            const int ko = s * 32 + lk * 8;
            bf16x8 ah = *(const bf16x8*)&h1hs[mt * 16 + lm][ko];
            bf16x8 al = *(const bf16x8*)&h1ls[mt * 16 + lm][ko];
            bf16x8 bh = *(const bf16x8*)(curh + (nb * 64 + lane) * 16);
            bf16x8 bl = *(const bf16x8*)(curl + (nb * 64 + lane) * 16);
            acc2 = mfma16(ah, bh, acc2);
            acc2 = mfma16(ah, bl, acc2);
            acc2 = mfma16(al, bh, acc2);
            __syncthreads();
        }
        int col2 = nb * 16 + lm;
        float bv = rb2[col2];
        #pragma unroll
        for (int r = 0; r < 4; ++r) {
            float v = acc2[r] + bv;
            h2s[mt * 16 + lk * 4 + r][col2] = v > 0.f ? v : 0.f;
        }
    }
    __syncthreads();

    // ---- head
    const int o = lane >> 3, kq = lane & 7;
    #pragma unroll
    for (int i = 0; i < 2; ++i) {
        int rloc = wave * 2 + i;
        int b = r0 + rloc;
        float s = 0.f;
        #pragma unroll
        for (int q = 0; q < 4; ++q) {
            float4 hv = *(const float4*)&h2s[rloc][kq * 16 + q * 4];
            float4 wv = *(const float4*)&rW3[o * RH2 + kq * 16 + q * 4];
            s += hv.x * wv.x + hv.y * wv.y + hv.z * wv.z + hv.w * wv.w;
        }
        s += __shfl_xor(s, 1);
        s += __shfl_xor(s, 2);
        s += __shfl_xor(s, 4);
        float logit = s + rb3[o];
        float l[8];
        #pragma unroll
        for (int j = 0; j < 8; ++j) l[j] = __shfl(logit, j * 8);
        float m = l[0];
        #pragma unroll
        for (int j = 1; j < 8; ++j) m = fmaxf(m, l[j]);
        float p[8]; float sum = 0.f;
        #pragma unroll
        for (int j = 0; j < 8; ++j) { p[j] = expf(l[j] - m); sum += p[j]; }
        float inv = 1.f / sum;
        #pragma unroll
        for (int j = 0; j < 8; ++j) p[j] *= inv;
        int i1 = 0; float v1 = p[0];
        #pragma unroll
        for (int j = 1; j < 8; ++j) if (p[j] > v1) { v1 = p[j]; i1 = j; }
        int i2 = -1; float v2 = -1.f;
        #pragma unroll
        for (int j = 0; j < 8; ++j) if (j != i1 && p[j] > v2) { v2 = p[j]; i2 = j; }
        if (lane < 8) {
            router_p[(size_t)b * 8 + lane] = p[lane];
            float gv = (lane == i1) ? v1 * 0.5f : ((lane == i2) ? v2 * 0.5f : 0.f);
            gate[(size_t)b * 8 + lane] = gv;
        }
        if (lane == 0) t2[b] = i1 | (i2 << 8);
    }
    if (blockIdx.x == 0 && tid == 0) lb_out[0] = 0.f;
}

// ---------------- build dispatch lists
__global__ __launch_bounds__(256) void build_lists_kernel(
    const int* __restrict__ t2, int* __restrict__ counts, int* __restrict__ ent)
{
    __shared__ int hist[8], base[8];
    const int r = blockIdx.x * 256 + threadIdx.x;
    if (threadIdx.x < 8) hist[threadIdx.x] = 0;
    __syncthreads();
    const int v = t2[r];
    const int i1 = v & 255, i2 = v >> 8;
    const int rk1 = atomicAdd(&hist[i1], 1);
    const int rk2 = atomicAdd(&hist[i2], 1);
    __syncthreads();
    if (threadIdx.x < 8) base[threadIdx.x] = atomicAdd(&counts[threadIdx.x], hist[threadIdx.x]);
    __syncthreads();
    ent[i1 * B_ROWS + base[i1] + rk1] = (r << 1);
    ent[i2 * B_ROWS + base[i2] + rk2] = (r << 1) | 1;
}

// ---------------- sparse fused expert kernel: BM=64, 1024 thr, balanced affinity.
// NEW: W read GLOBAL->REGISTER (per-lane uint4, depth-4/2 prefetch, L2-resident via
// affinity) — no W LDS staging, no W barrier drains. X chunk 128 cols -> 6 L1 barriers;
// L2 barrier-free. LDS: A1s 66560 | (Xd 34816 | A2s 33792 alias) = 101376 B.
__global__ __launch_bounds__(1024) void expert_fused_kernel(
    const float* __restrict__ x,
    const unsigned char* __restrict__ W1p8, const unsigned char* __restrict__ W2p8,
    const unsigned char* __restrict__ W3p8,
    const float* __restrict__ s1, const float* __restrict__ s2, const float* __restrict__ s3,
    const float* __restrict__ eb1, const float* __restrict__ eb2, const float* __restrict__ eb3,
    const float* __restrict__ gate,
    const int* __restrict__ counts, const int* __restrict__ ent,
    float* __restrict__ S0, float* __restrict__ S1)
{
    int pfx[9]; pfx[0] = 0;
    #pragma unroll
    for (int i = 0; i < 8; ++i) pfx[i + 1] = pfx[i] + ((counts[i] + 63) >> 6);
    const int T = pfx[8];
    const int R = (T + 7) >> 3;
    const int xcd = blockIdx.x & 7, j = blockIdx.x >> 3;
    if (j >= R) return;
    const int g = xcd * R + j;
    if (g >= T) return;
    int e = 0;
    #pragma unroll
    for (int i = 0; i < 7; ++i) if (g >= pfx[i + 1]) e = i + 1;
    const int t = g - pfx[e];
    const int cnt = counts[e];

    __shared__ __align__(16) unsigned char smem[101376];
    __hip_bfloat16 (*A1s)[520] = (__hip_bfloat16(*)[520])(smem);
    __hip_bfloat16 (*A2s)[264] = (__hip_bfloat16(*)[264])(smem + 66560);
    ushort (*Xd)[64][136]      = (ushort(*)[64][136])(smem + 66560);   // alias A2s region
    __shared__ int rowL[64];
    __shared__ int slotL[64];
    __shared__ float gL[64];

    const int tid = threadIdx.x;
    const int wave = tid >> 6;
    const int lane = tid & 63;
    const int lm = lane & 15;
    const int lk = lane >> 4;

    if (tid < 64) {
        int idx = t * 64 + tid;
        if (idx < cnt) {
            int entv = ent[e * B_ROWS + idx];
            int r = entv >> 1;
            rowL[tid] = r;
            slotL[tid] = entv & 1;
            gL[tid] = gate[(size_t)r * NE + e];
        } else {
            rowL[tid] = -1; slotL[tid] = 0; gL[tid] = 0.f;
        }
    }
    __syncthreads();

    // X staging: 128-col chunks; thread covers row (tid>>4), cols (tid&15)*8 .. +7
    const int srow = tid >> 4;
    const int sc8  = (tid & 15) * 8;
    int SR = rowL[srow]; if (SR < 0) SR = 0;
    const float* sg = x + (size_t)SR * IN_DIM + sc8;
    const unsigned char* Wsrc1 = W1p8 + (size_t)e * 393216;
    const unsigned char* Wsrc2 = W2p8 + (size_t)e * 131072;
    const unsigned char* Wsrc3 = W3p8 + (size_t)e * 16384;

    // prologue: X chunk 0 -> Xd[0]
    {
        float4 fa = *(const float4*)(sg);
        float4 fb = *(const float4*)(sg + 4);
        *(ushort4*)&Xd[0][srow][sc8]     = cvt_f4_bf16(fa);
        *(ushort4*)&Xd[0][srow][sc8 + 4] = cvt_f4_bf16(fb);
    }
    __syncthreads();

    // ---- layer 1: 6 intervals x 4 K-steps; W global->reg, depth-4 prefetch
    {
        f32x4 acc[4][2] = {};
        const int w2 = wave * 2;
        const unsigned char* wp1 = Wsrc1 + wave * 1024 + lane * 16;
        uint4 pw[4];
        #pragma unroll
        for (int k = 0; k < 4; ++k)
            pw[k] = *(const uint4*)(wp1 + (size_t)k * 16384);
        for (int i = 0; i < 6; ++i) {
            float4 fa, fb;
            if (i + 1 < 6) {                       // issue-early next X chunk
                fa = *(const float4*)(sg + (i + 1) * CHK);
                fb = *(const float4*)(sg + (i + 1) * CHK + 4);
            }
            uint4 cur[4];
            #pragma unroll
            for (int k = 0; k < 4; ++k) cur[k] = pw[k];
            if (i + 1 < 6) {                       // prefetch next interval's W
                #pragma unroll
                for (int k = 0; k < 4; ++k)
                    pw[k] = *(const uint4*)(wp1 + (size_t)(4 * i + 4 + k) * 16384);
            }
            const ushort (*Xc)[136] = Xd[i & 1];
            #pragma unroll
            for (int k4 = 0; k4 < 4; ++k4) {
                const int ko = k4 * 32 + lk * 8;
                bf16x8 a0 = *(const bf16x8*)&Xc[     lm][ko];
                bf16x8 a1 = *(const bf16x8*)&Xc[16 + lm][ko];
                bf16x8 a2 = *(const bf16x8*)&Xc[32 + lm][ko];
                bf16x8 a3 = *(const bf16x8*)&Xc[48 + lm][ko];
                bf16x8 b0 = expand_frag(make_uint2(cur[k4].x, cur[k4].y));
                bf16x8 b1 = expand_frag(make_uint2(cur[k4].z, cur[k4].w));
                acc[0][0] = mfma16(a0, b0, acc[0][0]);
                acc[1][0] = mfma16(a1, b0, acc[1][0]);
                acc[2][0] = mfma16(a2, b0, acc[2][0]);
                acc[3][0] = mfma16(a3, b0, acc[3][0]);
                acc[0][1] = mfma16(a0, b1, acc[0][1]);
                acc[1][1] = mfma16(a1, b1, acc[1][1]);
                acc[2][1] = mfma16(a2, b1, acc[2][1]);
                acc[3][1] = mfma16(a3, b1, acc[3][1]);
            }
            if (i + 1 < 6) {                       // write-late to other X buffer
                *(ushort4*)&Xd[(i + 1) & 1][srow][sc8]     = cvt_f4_bf16(fa);
                *(ushort4*)&Xd[(i + 1) & 1][srow][sc8 + 4] = cvt_f4_bf16(fb);
            }
            __syncthreads();
        }
        const float* bias = eb1 + e * H1;
        const float sc = s1[e];
        #pragma unroll
        for (int n = 0; n < 2; ++n) {
            int ncol = (w2 + n) * 16 + lm;
            float bv = bias[ncol];
            #pragma unroll
            for (int m = 0; m < 4; ++m)
                #pragma unroll
                for (int r = 0; r < 4; ++r) {
                    float v = fmaf(acc[m][n][r], sc, bv);
                    v = v > 0.f ? v : 0.f;
                    A1s[m * 16 + lk * 4 + r][ncol] = __float2bfloat16(v);
                }
        }
    }
    __syncthreads();

    // ---- layer 2: 16 K-steps, zero internal barriers; W global->reg, depth-2
    {
        const int mt = wave >> 3, ntw = wave & 7;
        const unsigned char* wp2 = Wsrc2 + ntw * 1024 + lane * 16;
        f32x4 acc[2][2] = {};
        uint4 pwa = *(const uint4*)(wp2);
        uint4 pwb = *(const uint4*)(wp2 + 8192);
        for (int s = 0; s < 16; s += 2) {
            uint4 c0 = pwa, c1 = pwb;
            if (s + 2 < 16) {
                pwa = *(const uint4*)(wp2 + (size_t)(s + 2) * 8192);
                pwb = *(const uint4*)(wp2 + (size_t)(s + 3) * 8192);
            }
            {
                const int ko = s * 32 + lk * 8;
                bf16x8 a0 = *(const bf16x8*)&A1s[mt * 32 +      lm][ko];
                bf16x8 a1 = *(const bf16x8*)&A1s[mt * 32 + 16 + lm][ko];
                bf16x8 b0 = expand_frag(make_uint2(c0.x, c0.y));
                bf16x8 b1 = expand_frag(make_uint2(c0.z, c0.w));
                acc[0][0] = mfma16(a0, b0, acc[0][0]);
                acc[1][0] = mfma16(a1, b0, acc[1][0]);
                acc[0][1] = mfma16(a0, b1, acc[0][1]);
                acc[1][1] = mfma16(a1, b1, acc[1][1]);
            }
            {
                const int ko = (s + 1) * 32 + lk * 8;
                bf16x8 a0 = *(const bf16x8*)&A1s[mt * 32 +      lm][ko];
                bf16x8 a1 = *(const bf16x8*)&A1s[mt * 32 + 16 + lm][ko];
                bf16x8 b0 = expand_frag(make_uint2(c1.x, c1.y));
                bf16x8 b1 = expand_frag(make_uint2(c1.z, c1.w));
                acc[0][0] = mfma16(a0, b0, acc[0][0]);
                acc[1][0] = mfma16(a1, b0, acc[1][0]);
                acc[0][1] = mfma16(a0, b1, acc[0][1]);
                acc[1][1] = mfma16(a1, b1, acc[1][1]);
            }
        }
        const float* bias = eb2 + e * H2;
        const float sc = s2[e];
        #pragma unroll
        for (int n = 0; n < 2; ++n) {
            int ncol = (ntw * 2 + n) * 16 + lm;
            float bv = bias[ncol];
            #pragma unroll
            for (int m = 0; m < 2; ++m)
                #pragma unroll
                for (int r = 0; r < 4; ++r) {
                    float v = fmaf(acc[m][n][r], sc, bv);
                    v = v > 0.f ? v : 0.f;
                    A2s[mt * 32 + m * 16 + lk * 4 + r][ncol] = __float2bfloat16(v);
                }
        }
    }
    __syncthreads();   // A2s visible

    // ---- layer 3: W3 global->reg (flat layout)
    {
        const int mt = wave & 3, nt = wave >> 2;
        f32x4 acc = {};
        #pragma unroll
        for (int s = 0; s < 8; ++s) {
            bf16x8 a = *(const bf16x8*)&A2s[mt * 16 + lm][s * 32 + lk * 8];
            uint2 pw = *(const uint2*)(Wsrc3 + ((s * 4 + nt) * 64 + lane) * 8);
            bf16x8 b = expand_frag(pw);
            acc = mfma16(a, b, acc);
        }
        int col = nt * 16 + lm;
        if (col < NC) {
            const float bv = eb3[e * NC + col];
            const float sc = s3[e];
            #pragma unroll
            for (int r = 0; r < 4; ++r) {
                int row = mt * 16 + lk * 4 + r;
                int R2 = rowL[row];
                if (R2 >= 0) {
                    float v = gL[row] * fmaf(acc[r], sc, bv);
                    float* Sb = slotL[row] ? S1 : S0;
                    Sb[(size_t)R2 * 64 + col] = v;
                }
            }
        }
    }
}

// ---------------- combine
__global__ __launch_bounds__(256) void combine_kernel(
    const float* __restrict__ S0, const float* __restrict__ S1, float* __restrict__ out)
{
    int i = blockIdx.x * 256 + threadIdx.x;
    if (i < B_ROWS * NC) {
        int row = i / NC, col = i % NC;
        out[i] = S0[(size_t)row * 64 + col] + S1[(size_t)row * 64 + col];
    }
}

extern "C" void kernel_launch(void* const* d_in, const int* in_sizes, int n_in,
                              void* d_out, int out_size, void* d_ws, size_t ws_size,
                              hipStream_t stream) {
    const float* x   = (const float*)d_in[0];
    const float* rW1 = (const float*)d_in[1];
    const float* rb1 = (const float*)d_in[2];
    const float* rW2 = (const float*)d_in[3];
    const float* rb2 = (const float*)d_in[4];
    const float* rW3 = (const float*)d_in[5];
    const float* rb3 = (const float*)d_in[6];
    const float* eW1 = (const float*)d_in[7];
    const float* eb1 = (const float*)d_in[8];
    const float* eW2 = (const float*)d_in[9];
    const float* eb2 = (const float*)d_in[10];
    const float* eW3 = (const float*)d_in[11];
    const float* eb3 = (const float*)d_in[12];

    float* out_main = (float*)d_out;
    float* router_p = out_main + (size_t)B_ROWS * NC;
    float* lb_out   = router_p + (size_t)B_ROWS * NE;

    char* ws = (char*)d_ws;
    size_t off = 0;
    unsigned char* W1p8 = (unsigned char*)(ws + off); off += (size_t)NE * 49152 * 8;
    unsigned char* W2p8 = (unsigned char*)(ws + off); off += (size_t)NE * 16384 * 8;
    unsigned char* W3p8 = (unsigned char*)(ws + off); off += (size_t)NE * 2048 * 8;
    float* S0   = (float*)(ws + off);  off += (size_t)B_ROWS * 64 * 4;
    float* S1   = (float*)(ws + off);  off += (size_t)B_ROWS * 64 * 4;
    ushort* rw1hp = (ushort*)(ws + off); off += (size_t)24576 * 8 * 2;
    ushort* rw1lp = (ushort*)(ws + off); off += (size_t)24576 * 8 * 2;
    ushort* rw2hp = (ushort*)(ws + off); off += (size_t)4096 * 8 * 2;
    ushort* rw2lp = (ushort*)(ws + off); off += (size_t)4096 * 8 * 2;
    float* gate = (float*)(ws + off);  off += (size_t)B_ROWS * NE * 4;
    int*   ent  = (int*)(ws + off);    off += (size_t)NE * B_ROWS * 4;
    int*   t2   = (int*)(ws + off);    off += (size_t)B_ROWS * 4;
    int* counts = (int*)(ws + off);    off += 256;
    float* s1   = (float*)(ws + off);  off += 256;
    float* s2   = (float*)(ws + off);  off += 256;
    float* s3   = (float*)(ws + off);  off += 256;
    float* p1   = (float*)(ws + off);  off += NE * 96 * 4;
    float* p2   = (float*)(ws + off);  off += NE * 32 * 4;
    float* p3   = (float*)(ws + off);  off += NE * 4 * 4;

    // 1) prep
    pack_absum_kernel<<<dim3(96, 24), 512, 0, stream>>>(
        eW1, eW2, eW3, W1p8, W2p8, W3p8, p1, p2, p3);
    pack_router_kernel<<<56, 512, 0, stream>>>(rW1, rw1hp, rw1lp, rW2, rw2hp, rw2lp);
    finalize_scales_kernel<<<1, 64, 0, stream>>>(p1, p2, p3, s1, s2, s3, counts);

    // 2) fused router
    router_fused_kernel<<<B_ROWS / 32, 1024, 0, stream>>>(
        x, rw1hp, rw1lp, rb1, rw2hp, rw2lp, rb2, rW3, rb3, router_p, gate, lb_out, t2);
    build_lists_kernel<<<B_ROWS / 256, 256, 0, stream>>>(t2, counts, ent);

    // 3) sparse fused experts (W global->register streaming) + combine
    expert_fused_kernel<<<1024, 1024, 0, stream>>>(
        x, W1p8, W2p8, W3p8, s1, s2, s3, eb1, eb2, eb3, gate, counts, ent, S0, S1);
    combine_kernel<<<(B_ROWS * NC + 255) / 256, 256, 0, stream>>>(S0, S1, out_main);
}

// Round 24
// 124.799 us; speedup vs baseline: 1.8581x; 1.1262x over previous
//
#include <hip/hip_runtime.h>
#include <hip/hip_bf16.h>

typedef __attribute__((ext_vector_type(4))) float f32x4;
typedef __attribute__((ext_vector_type(8))) short bf16x8;

#define B_ROWS 16384
#define IN_DIM 768
#define H1 512
#define H2 256
#define NC 50
#define NE 8
#define RH1 256
#define RH2 128
#define CHK 128

static __device__ __forceinline__ f32x4 mfma16(bf16x8 a, bf16x8 b, f32x4 c) {
    return __builtin_amdgcn_mfma_f32_16x16x32_bf16(a, b, c, 0, 0, 0);
}

// expand 8 ternary byte-codes (bf16 high byte: 0x3F/0xBF/0x00) to exact bf16x8
static __device__ __forceinline__ bf16x8 expand_frag(uint2 pw) {
    unsigned q0 = (pw.x & 0x01010101u) << 7;
    unsigned q1 = (pw.y & 0x01010101u) << 7;
    union { unsigned u[4]; bf16x8 v; } r;
    r.u[0] = __builtin_amdgcn_perm(pw.x, q0, 0x05010400u);
    r.u[1] = __builtin_amdgcn_perm(pw.x, q0, 0x07030602u);
    r.u[2] = __builtin_amdgcn_perm(pw.y, q1, 0x05010400u);
    r.u[3] = __builtin_amdgcn_perm(pw.y, q1, 0x07030602u);
    return r.v;
}

// decompose float4 -> bf16 hi/lo ushort4 pair
static __device__ __forceinline__ void decomp_f4(float4 v, ushort4* hv, ushort4* lv) {
    float vv[4] = {v.x, v.y, v.z, v.w};
    ushort ho[4], lo4[4];
    #pragma unroll
    for (int q = 0; q < 4; ++q) {
        __hip_bfloat16 h = __float2bfloat16(vv[q]);
        float hf = __bfloat162float(h);
        __hip_bfloat16 l = __float2bfloat16(vv[q] - hf);
        ho[q] = *(ushort*)&h; lo4[q] = *(ushort*)&l;
    }
    *hv = make_ushort4(ho[0], ho[1], ho[2], ho[3]);
    *lv = make_ushort4(lo4[0], lo4[1], lo4[2], lo4[3]);
}

static __device__ __forceinline__ ushort4 cvt_f4_bf16(float4 v) {
    float vv[4] = {v.x, v.y, v.z, v.w};
    ushort ho[4];
    #pragma unroll
    for (int q = 0; q < 4; ++q) {
        __hip_bfloat16 h = __float2bfloat16(vv[q]);
        ho[q] = *(ushort*)&h;
    }
    return make_ushort4(ho[0], ho[1], ho[2], ho[3]);
}

// ---------------- merged ternarize+pack+abs-sum: grid (96, 24), 512 thr.
__global__ __launch_bounds__(512) void pack_absum_kernel(
    const float* __restrict__ eW1, const float* __restrict__ eW2, const float* __restrict__ eW3,
    unsigned char* __restrict__ W1p8, unsigned char* __restrict__ W2p8,
    unsigned char* __restrict__ W3p8,
    float* __restrict__ p1, float* __restrict__ p2, float* __restrict__ p3)
{
    const int mat = blockIdx.y >> 3, e = blockIdx.y & 7;
    const int u = blockIdx.x * 512 + threadIdx.x;
    const float* src; unsigned char* dst; int valid = 1; float* P; int np;
    if (mat == 0) {
        int lane = u & 63, nblk = (u >> 6) & 31, ks = u >> 11;
        int n = nblk * 16 + (lane & 15), k = ks * 32 + (lane >> 4) * 8;
        src = eW1 + ((size_t)e * H1 + n) * IN_DIM + k;
        dst = W1p8 + (size_t)e * 393216
            + (size_t)ks * 16384 + (nblk >> 1) * 1024 + lane * 16 + (nblk & 1) * 8;
        P = p1; np = 96;
    } else if (mat == 1) {
        if (u >= 16384) return;
        int lane = u & 63, nblk = (u >> 6) & 15, ks = u >> 10;
        int n = nblk * 16 + (lane & 15), k = ks * 32 + (lane >> 4) * 8;
        src = eW2 + ((size_t)e * H2 + n) * H1 + k;
        dst = W2p8 + (size_t)e * 131072
            + (size_t)ks * 8192 + (nblk >> 1) * 1024 + lane * 16 + (nblk & 1) * 8;
        P = p2; np = 32;
    } else {
        if (u >= 2048) return;
        int lane = u & 63, nblk = (u >> 6) & 3, ks = u >> 8;
        int n = nblk * 16 + (lane & 15), k = ks * 32 + (lane >> 4) * 8;
        valid = (n < NC);
        src = eW3 + ((size_t)e * NC + (valid ? n : 0)) * H2 + k;
        dst = W3p8 + ((size_t)e * 2048 + u) * 8;
        P = p3; np = 4;
    }
    unsigned lo = 0, hi = 0;
    float s = 0.f;
    #pragma unroll
    for (int j = 0; j < 4; ++j) {
        float w = valid ? src[j] : 0.f;
        s += fabsf(w);
        unsigned c = (fabsf(w) > 0.05f) ? (w > 0.f ? 0x3Fu : 0xBFu) : 0u;
        lo |= c << (8 * j);
    }
    #pragma unroll
    for (int j = 0; j < 4; ++j) {
        float w = valid ? src[4 + j] : 0.f;
        s += fabsf(w);
        unsigned c = (fabsf(w) > 0.05f) ? (w > 0.f ? 0x3Fu : 0xBFu) : 0u;
        hi |= c << (8 * j);
    }
    *(uint2*)dst = make_uint2(lo, hi);
    const int lane = threadIdx.x & 63, wave = threadIdx.x >> 6;
    #pragma unroll
    for (int o = 32; o; o >>= 1) s += __shfl_down(s, o);
    __shared__ float red[8];
    if (lane == 0) red[wave] = s;
    __syncthreads();
    if (threadIdx.x == 0) {
        float t = 0.f;
        #pragma unroll
        for (int i = 0; i < 8; ++i) t += red[i];
        P[e * np + blockIdx.x] = t;
    }
}

// ---------------- finalize scales + zero dispatch counts
__global__ __launch_bounds__(64) void finalize_scales_kernel(
    const float* __restrict__ p1, const float* __restrict__ p2, const float* __restrict__ p3,
    float* __restrict__ s1, float* __restrict__ s2, float* __restrict__ s3,
    int* __restrict__ counts)
{
    int t = threadIdx.x;
    if (t < 8) {
        float a = 0.f;
        for (int i = 0; i < 96; ++i) a += p1[t * 96 + i];
        s1[t] = a / (float)(H1 * IN_DIM);
    } else if (t < 16) {
        int e = t - 8; float a = 0.f;
        for (int i = 0; i < 32; ++i) a += p2[e * 32 + i];
        s2[e] = a / (float)(H2 * H1);
    } else if (t < 24) {
        int e = t - 16; float a = 0.f;
        for (int i = 0; i < 4; ++i) a += p3[e * 4 + i];
        s3[e] = a / (float)(NC * H2);
    } else if (t < 32) {
        counts[t - 24] = 0;
    }
}

// ---------------- pack router weights into fragment-order hi/lo images
__global__ __launch_bounds__(512) void pack_router_kernel(
    const float* __restrict__ rW1, ushort* __restrict__ rw1hp, ushort* __restrict__ rw1lp,
    const float* __restrict__ rW2, ushort* __restrict__ rw2hp, ushort* __restrict__ rw2lp)
{
    int u = blockIdx.x * 512 + threadIdx.x;
    const float* src; ushort* dh; ushort* dl;
    if (u < 24576) {
        int lane = u & 63, nblk = (u >> 6) & 15, ks = u >> 10;
        int n = nblk * 16 + (lane & 15), k = ks * 32 + (lane >> 4) * 8;
        src = rW1 + (size_t)n * IN_DIM + k;
        dh = rw1hp + (size_t)u * 8; dl = rw1lp + (size_t)u * 8;
    } else {
        int v = u - 24576;
        if (v >= 4096) return;
        int lane = v & 63, nblk = (v >> 6) & 7, ks = v >> 9;
        int n = nblk * 16 + (lane & 15), k = ks * 32 + (lane >> 4) * 8;
        src = rW2 + (size_t)n * RH1 + k;
        dh = rw2hp + (size_t)v * 8; dl = rw2lp + (size_t)v * 8;
    }
    ushort oh[8], ol[8];
    #pragma unroll
    for (int j = 0; j < 8; ++j) {
        float w = src[j];
        __hip_bfloat16 h = __float2bfloat16(w);
        float hf = __bfloat162float(h);
        __hip_bfloat16 l = __float2bfloat16(w - hf);
        oh[j] = *(ushort*)&h; ol[j] = *(ushort*)&l;
    }
    ((ushort4*)dh)[0] = make_ushort4(oh[0], oh[1], oh[2], oh[3]);
    ((ushort4*)dh)[1] = make_ushort4(oh[4], oh[5], oh[6], oh[7]);
    ((ushort4*)dl)[0] = make_ushort4(ol[0], ol[1], ol[2], ol[3]);
    ((ushort4*)dl)[1] = make_ushort4(ol[4], ol[5], ol[6], ol[7]);
}

// ---------------- fused router, 1024 threads; W global->register (L2-shared across
// blocks), X f32 + in-register decomposition. LDS 68608 B -> 2 blocks/CU.
// L1: 6 intervals x 4 K-steps (6 barriers); L2 barrier-free.
__global__ __launch_bounds__(1024) void router_fused_kernel(
    const float* __restrict__ x,
    const ushort* __restrict__ rw1hp, const ushort* __restrict__ rw1lp, const float* __restrict__ rb1,
    const ushort* __restrict__ rw2hp, const ushort* __restrict__ rw2lp, const float* __restrict__ rb2,
    const float* __restrict__ rW3, const float* __restrict__ rb3,
    float* __restrict__ router_p, float* __restrict__ gate,
    float* __restrict__ lb_out, int* __restrict__ t2)
{
    __shared__ __align__(16) unsigned char smem[68608];
    ushort (*Xdh)[32][136] = (ushort(*)[32][136])(smem);
    ushort (*Xdl)[32][136] = (ushort(*)[32][136])(smem + 17408);
    ushort (*h1hs)[264]    = (ushort(*)[264])(smem + 34816);
    ushort (*h1ls)[264]    = (ushort(*)[264])(smem + 51712);
    float (*h2s)[132]      = (float(*)[132])(smem);          // alias Xdh (dead after L1)

    const int tid = threadIdx.x, wave = tid >> 6, lane = tid & 63;
    const int lm = lane & 15, lk = lane >> 4;
    const int r0 = blockIdx.x * 32;

    // X staging: thread covers row (tid>>5), cols (tid&31)*4 of each 128-col chunk
    const int srow = tid >> 5;
    const int sc4r = (tid & 31) * 4;
    const float* sg = x + (size_t)(r0 + srow) * IN_DIM + sc4r;

    {
        float4 sv = *(const float4*)sg;
        ushort4 hv, lv;
        decomp_f4(sv, &hv, &lv);
        *(ushort4*)&Xdh[0][srow][sc4r] = hv;
        *(ushort4*)&Xdl[0][srow][sc4r] = lv;
    }
    __syncthreads();

    // ---- layer 1: 6 intervals x 4 K-steps; W global->reg depth-4
    {
        f32x4 acc[2] = {};
        const ushort* wph = rw1hp + (size_t)(wave * 64 + lane) * 8;
        const ushort* wpl = rw1lp + (size_t)(wave * 64 + lane) * 8;
        uint4 ph[4], pl[4];
        #pragma unroll
        for (int k = 0; k < 4; ++k) {
            ph[k] = *(const uint4*)(wph + (size_t)k * 8192);
            pl[k] = *(const uint4*)(wpl + (size_t)k * 8192);
        }
        for (int i = 0; i < 6; ++i) {
            float4 sv;
            if (i + 1 < 6) sv = *(const float4*)(sg + (i + 1) * CHK);   // issue-early
            const ushort (*Xch)[136] = Xdh[i & 1];
            const ushort (*Xcl)[136] = Xdl[i & 1];
            #pragma unroll
            for (int k4 = 0; k4 < 4; ++k4) {
                uint4 ch = ph[k4], cl = pl[k4];
                if (i + 1 < 6) {                     // prefetch next interval's W
                    ph[k4] = *(const uint4*)(wph + (size_t)(4 * i + 4 + k4) * 8192);
                    pl[k4] = *(const uint4*)(wpl + (size_t)(4 * i + 4 + k4) * 8192);
                }
                const int ko = k4 * 32 + lk * 8;
                bf16x8 ah0 = *(const bf16x8*)&Xch[lm][ko];
                bf16x8 al0 = *(const bf16x8*)&Xcl[lm][ko];
                bf16x8 ah1 = *(const bf16x8*)&Xch[16 + lm][ko];
                bf16x8 al1 = *(const bf16x8*)&Xcl[16 + lm][ko];
                bf16x8 bh = *(bf16x8*)&ch;
                bf16x8 bl = *(bf16x8*)&cl;
                acc[0] = mfma16(ah0, bh, acc[0]);
                acc[0] = mfma16(ah0, bl, acc[0]);
                acc[0] = mfma16(al0, bh, acc[0]);
                acc[1] = mfma16(ah1, bh, acc[1]);
                acc[1] = mfma16(ah1, bl, acc[1]);
                acc[1] = mfma16(al1, bh, acc[1]);
            }
            if (i + 1 < 6) {                         // write-late to other X buffer
                ushort4 hv, lv;
                decomp_f4(sv, &hv, &lv);
                *(ushort4*)&Xdh[(i + 1) & 1][srow][sc4r] = hv;
                *(ushort4*)&Xdl[(i + 1) & 1][srow][sc4r] = lv;
            }
            __syncthreads();
        }
        int col = wave * 16 + lm;
        float bv = rb1[col];
        #pragma unroll
        for (int m = 0; m < 2; ++m)
            #pragma unroll
            for (int r = 0; r < 4; ++r) {
                float v = acc[m][r] + bv;
                v = v > 0.f ? v : 0.f;
                __hip_bfloat16 h = __float2bfloat16(v);
                float hf = __bfloat162float(h);
                __hip_bfloat16 l = __float2bfloat16(v - hf);
                int row = m * 16 + lk * 4 + r;
                h1hs[row][col] = *(ushort*)&h;
                h1ls[row][col] = *(ushort*)&l;
            }
    }
    __syncthreads();

    // ---- layer 2: 8 K-steps, barrier-free; W global->reg depth-2
    {
        const int mt = wave >> 3, nb = wave & 7;
        const ushort* w2h = rw2hp + (size_t)(nb * 64 + lane) * 8;
        const ushort* w2l = rw2lp + (size_t)(nb * 64 + lane) * 8;
        f32x4 acc2 = {};
        uint4 pha = *(const uint4*)(w2h);
        uint4 pla = *(const uint4*)(w2l);
        uint4 phb = *(const uint4*)(w2h + 4096);
        uint4 plb = *(const uint4*)(w2l + 4096);
        for (int s = 0; s < 8; s += 2) {
            uint4 cha = pha, cla = pla, chb = phb, clb = plb;
            if (s + 2 < 8) {
                pha = *(const uint4*)(w2h + (size_t)(s + 2) * 4096);
                pla = *(const uint4*)(w2l + (size_t)(s + 2) * 4096);
                phb = *(const uint4*)(w2h + (size_t)(s + 3) * 4096);
                plb = *(const uint4*)(w2l + (size_t)(s + 3) * 4096);
            }
            {
                const int ko = s * 32 + lk * 8;
                bf16x8 ah = *(const bf16x8*)&h1hs[mt * 16 + lm][ko];
                bf16x8 al = *(const bf16x8*)&h1ls[mt * 16 + lm][ko];
                bf16x8 bh = *(bf16x8*)&cha;
                bf16x8 bl = *(bf16x8*)&cla;
                acc2 = mfma16(ah, bh, acc2);
                acc2 = mfma16(ah, bl, acc2);
                acc2 = mfma16(al, bh, acc2);
            }
            {
                const int ko = (s + 1) * 32 + lk * 8;
                bf16x8 ah = *(const bf16x8*)&h1hs[mt * 16 + lm][ko];
                bf16x8 al = *(const bf16x8*)&h1ls[mt * 16 + lm][ko];
                bf16x8 bh = *(bf16x8*)&chb;
                bf16x8 bl = *(bf16x8*)&clb;
                acc2 = mfma16(ah, bh, acc2);
                acc2 = mfma16(ah, bl, acc2);
                acc2 = mfma16(al, bh, acc2);
            }
        }
        __syncthreads();   // Xdh alias region free (all waves past L1 reads)
        int col2 = nb * 16 + lm;
        float bv = rb2[col2];
        #pragma unroll
        for (int r = 0; r < 4; ++r) {
            float v = acc2[r] + bv;
            h2s[mt * 16 + lk * 4 + r][col2] = v > 0.f ? v : 0.f;
        }
    }
    __syncthreads();

    // ---- head
    const int o = lane >> 3, kq = lane & 7;
    #pragma unroll
    for (int i = 0; i < 2; ++i) {
        int rloc = wave * 2 + i;
        int b = r0 + rloc;
        float s = 0.f;
        #pragma unroll
        for (int q = 0; q < 4; ++q) {
            float4 hv = *(const float4*)&h2s[rloc][kq * 16 + q * 4];
            float4 wv = *(const float4*)&rW3[o * RH2 + kq * 16 + q * 4];
            s += hv.x * wv.x + hv.y * wv.y + hv.z * wv.z + hv.w * wv.w;
        }
        s += __shfl_xor(s, 1);
        s += __shfl_xor(s, 2);
        s += __shfl_xor(s, 4);
        float logit = s + rb3[o];
        float l[8];
        #pragma unroll
        for (int j = 0; j < 8; ++j) l[j] = __shfl(logit, j * 8);
        float m = l[0];
        #pragma unroll
        for (int j = 1; j < 8; ++j) m = fmaxf(m, l[j]);
        float p[8]; float sum = 0.f;
        #pragma unroll
        for (int j = 0; j < 8; ++j) { p[j] = expf(l[j] - m); sum += p[j]; }
        float inv = 1.f / sum;
        #pragma unroll
        for (int j = 0; j < 8; ++j) p[j] *= inv;
        int i1 = 0; float v1 = p[0];
        #pragma unroll
        for (int j = 1; j < 8; ++j) if (p[j] > v1) { v1 = p[j]; i1 = j; }
        int i2 = -1; float v2 = -1.f;
        #pragma unroll
        for (int j = 0; j < 8; ++j) if (j != i1 && p[j] > v2) { v2 = p[j]; i2 = j; }
        if (lane < 8) {
            router_p[(size_t)b * 8 + lane] = p[lane];
            float gv = (lane == i1) ? v1 * 0.5f : ((lane == i2) ? v2 * 0.5f : 0.f);
            gate[(size_t)b * 8 + lane] = gv;
        }
        if (lane == 0) t2[b] = i1 | (i2 << 8);
    }
    if (blockIdx.x == 0 && tid == 0) lb_out[0] = 0.f;
}

// ---------------- build dispatch lists
__global__ __launch_bounds__(256) void build_lists_kernel(
    const int* __restrict__ t2, int* __restrict__ counts, int* __restrict__ ent)
{
    __shared__ int hist[8], base[8];
    const int r = blockIdx.x * 256 + threadIdx.x;
    if (threadIdx.x < 8) hist[threadIdx.x] = 0;
    __syncthreads();
    const int v = t2[r];
    const int i1 = v & 255, i2 = v >> 8;
    const int rk1 = atomicAdd(&hist[i1], 1);
    const int rk2 = atomicAdd(&hist[i2], 1);
    __syncthreads();
    if (threadIdx.x < 8) base[threadIdx.x] = atomicAdd(&counts[threadIdx.x], hist[threadIdx.x]);
    __syncthreads();
    ent[i1 * B_ROWS + base[i1] + rk1] = (r << 1);
    ent[i2 * B_ROWS + base[i2] + rk2] = (r << 1) | 1;
}

// ---------------- sparse fused expert kernel (R23 best, unchanged)
__global__ __launch_bounds__(1024) void expert_fused_kernel(
    const float* __restrict__ x,
    const unsigned char* __restrict__ W1p8, const unsigned char* __restrict__ W2p8,
    const unsigned char* __restrict__ W3p8,
    const float* __restrict__ s1, const float* __restrict__ s2, const float* __restrict__ s3,
    const float* __restrict__ eb1, const float* __restrict__ eb2, const float* __restrict__ eb3,
    const float* __restrict__ gate,
    const int* __restrict__ counts, const int* __restrict__ ent,
    float* __restrict__ S0, float* __restrict__ S1)
{
    int pfx[9]; pfx[0] = 0;
    #pragma unroll
    for (int i = 0; i < 8; ++i) pfx[i + 1] = pfx[i] + ((counts[i] + 63) >> 6);
    const int T = pfx[8];
    const int R = (T + 7) >> 3;
    const int xcd = blockIdx.x & 7, j = blockIdx.x >> 3;
    if (j >= R) return;
    const int g = xcd * R + j;
    if (g >= T) return;
    int e = 0;
    #pragma unroll
    for (int i = 0; i < 7; ++i) if (g >= pfx[i + 1]) e = i + 1;
    const int t = g - pfx[e];
    const int cnt = counts[e];

    __shared__ __align__(16) unsigned char smem[101376];
    __hip_bfloat16 (*A1s)[520] = (__hip_bfloat16(*)[520])(smem);
    __hip_bfloat16 (*A2s)[264] = (__hip_bfloat16(*)[264])(smem + 66560);
    ushort (*Xd)[64][136]      = (ushort(*)[64][136])(smem + 66560);
    __shared__ int rowL[64];
    __shared__ int slotL[64];
    __shared__ float gL[64];

    const int tid = threadIdx.x;
    const int wave = tid >> 6;
    const int lane = tid & 63;
    const int lm = lane & 15;
    const int lk = lane >> 4;

    if (tid < 64) {
        int idx = t * 64 + tid;
        if (idx < cnt) {
            int entv = ent[e * B_ROWS + idx];
            int r = entv >> 1;
            rowL[tid] = r;
            slotL[tid] = entv & 1;
            gL[tid] = gate[(size_t)r * NE + e];
        } else {
            rowL[tid] = -1; slotL[tid] = 0; gL[tid] = 0.f;
        }
    }
    __syncthreads();

    const int srow = tid >> 4;
    const int sc8  = (tid & 15) * 8;
    int SR = rowL[srow]; if (SR < 0) SR = 0;
    const float* sg = x + (size_t)SR * IN_DIM + sc8;
    const unsigned char* Wsrc1 = W1p8 + (size_t)e * 393216;
    const unsigned char* Wsrc2 = W2p8 + (size_t)e * 131072;
    const unsigned char* Wsrc3 = W3p8 + (size_t)e * 16384;

    {
        float4 fa = *(const float4*)(sg);
        float4 fb = *(const float4*)(sg + 4);
        *(ushort4*)&Xd[0][srow][sc8]     = cvt_f4_bf16(fa);
        *(ushort4*)&Xd[0][srow][sc8 + 4] = cvt_f4_bf16(fb);
    }
    __syncthreads();

    // ---- layer 1: 6 intervals x 4 K-steps; W global->reg, depth-4 prefetch
    {
        f32x4 acc[4][2] = {};
        const int w2 = wave * 2;
        const unsigned char* wp1 = Wsrc1 + wave * 1024 + lane * 16;
        uint4 pw[4];
        #pragma unroll
        for (int k = 0; k < 4; ++k)
            pw[k] = *(const uint4*)(wp1 + (size_t)k * 16384);
        for (int i = 0; i < 6; ++i) {
            float4 fa, fb;
            if (i + 1 < 6) {
                fa = *(const float4*)(sg + (i + 1) * CHK);
                fb = *(const float4*)(sg + (i + 1) * CHK + 4);
            }
            uint4 cur[4];
            #pragma unroll
            for (int k = 0; k < 4; ++k) cur[k] = pw[k];
            if (i + 1 < 6) {
                #pragma unroll
                for (int k = 0; k < 4; ++k)
                    pw[k] = *(const uint4*)(wp1 + (size_t)(4 * i + 4 + k) * 16384);
            }
            const ushort (*Xc)[136] = Xd[i & 1];
            #pragma unroll
            for (int k4 = 0; k4 < 4; ++k4) {
                const int ko = k4 * 32 + lk * 8;
                bf16x8 a0 = *(const bf16x8*)&Xc[     lm][ko];
                bf16x8 a1 = *(const bf16x8*)&Xc[16 + lm][ko];
                bf16x8 a2 = *(const bf16x8*)&Xc[32 + lm][ko];
                bf16x8 a3 = *(const bf16x8*)&Xc[48 + lm][ko];
                bf16x8 b0 = expand_frag(make_uint2(cur[k4].x, cur[k4].y));
                bf16x8 b1 = expand_frag(make_uint2(cur[k4].z, cur[k4].w));
                acc[0][0] = mfma16(a0, b0, acc[0][0]);
                acc[1][0] = mfma16(a1, b0, acc[1][0]);
                acc[2][0] = mfma16(a2, b0, acc[2][0]);
                acc[3][0] = mfma16(a3, b0, acc[3][0]);
                acc[0][1] = mfma16(a0, b1, acc[0][1]);
                acc[1][1] = mfma16(a1, b1, acc[1][1]);
                acc[2][1] = mfma16(a2, b1, acc[2][1]);
                acc[3][1] = mfma16(a3, b1, acc[3][1]);
            }
            if (i + 1 < 6) {
                *(ushort4*)&Xd[(i + 1) & 1][srow][sc8]     = cvt_f4_bf16(fa);
                *(ushort4*)&Xd[(i + 1) & 1][srow][sc8 + 4] = cvt_f4_bf16(fb);
            }
            __syncthreads();
        }
        const float* bias = eb1 + e * H1;
        const float sc = s1[e];
        #pragma unroll
        for (int n = 0; n < 2; ++n) {
            int ncol = (w2 + n) * 16 + lm;
            float bv = bias[ncol];
            #pragma unroll
            for (int m = 0; m < 4; ++m)
                #pragma unroll
                for (int r = 0; r < 4; ++r) {
                    float v = fmaf(acc[m][n][r], sc, bv);
                    v = v > 0.f ? v : 0.f;
                    A1s[m * 16 + lk * 4 + r][ncol] = __float2bfloat16(v);
                }
        }
    }
    __syncthreads();

    // ---- layer 2: 16 K-steps, zero internal barriers; W global->reg, depth-2
    {
        const int mt = wave >> 3, ntw = wave & 7;
        const unsigned char* wp2 = Wsrc2 + ntw * 1024 + lane * 16;
        f32x4 acc[2][2] = {};
        uint4 pwa = *(const uint4*)(wp2);
        uint4 pwb = *(const uint4*)(wp2 + 8192);
        for (int s = 0; s < 16; s += 2) {
            uint4 c0 = pwa, c1 = pwb;
            if (s + 2 < 16) {
                pwa = *(const uint4*)(wp2 + (size_t)(s + 2) * 8192);
                pwb = *(const uint4*)(wp2 + (size_t)(s + 3) * 8192);
            }
            {
                const int ko = s * 32 + lk * 8;
                bf16x8 a0 = *(const bf16x8*)&A1s[mt * 32 +      lm][ko];
                bf16x8 a1 = *(const bf16x8*)&A1s[mt * 32 + 16 + lm][ko];
                bf16x8 b0 = expand_frag(make_uint2(c0.x, c0.y));
                bf16x8 b1 = expand_frag(make_uint2(c0.z, c0.w));
                acc[0][0] = mfma16(a0, b0, acc[0][0]);
                acc[1][0] = mfma16(a1, b0, acc[1][0]);
                acc[0][1] = mfma16(a0, b1, acc[0][1]);
                acc[1][1] = mfma16(a1, b1, acc[1][1]);
            }
            {
                const int ko = (s + 1) * 32 + lk * 8;
                bf16x8 a0 = *(const bf16x8*)&A1s[mt * 32 +      lm][ko];
                bf16x8 a1 = *(const bf16x8*)&A1s[mt * 32 + 16 + lm][ko];
                bf16x8 b0 = expand_frag(make_uint2(c1.x, c1.y));
                bf16x8 b1 = expand_frag(make_uint2(c1.z, c1.w));
                acc[0][0] = mfma16(a0, b0, acc[0][0]);
                acc[1][0] = mfma16(a1, b0, acc[1][0]);
                acc[0][1] = mfma16(a0, b1, acc[0][1]);
                acc[1][1] = mfma16(a1, b1, acc[1][1]);
            }
        }
        const float* bias = eb2 + e * H2;
        const float sc = s2[e];
        #pragma unroll
        for (int n = 0; n < 2; ++n) {
            int ncol = (ntw * 2 + n) * 16 + lm;
            float bv = bias[ncol];
            #pragma unroll
            for (int m = 0; m < 2; ++m)
                #pragma unroll
                for (int r = 0; r < 4; ++r) {
                    float v = fmaf(acc[m][n][r], sc, bv);
                    v = v > 0.f ? v : 0.f;
                    A2s[mt * 32 + m * 16 + lk * 4 + r][ncol] = __float2bfloat16(v);
                }
        }
    }
    __syncthreads();

    // ---- layer 3: W3 global->reg (flat layout)
    {
        const int mt = wave & 3, nt = wave >> 2;
        f32x4 acc = {};
        #pragma unroll
        for (int s = 0; s < 8; ++s) {
            bf16x8 a = *(const bf16x8*)&A2s[mt * 16 + lm][s * 32 + lk * 8];
            uint2 pw = *(const uint2*)(Wsrc3 + ((s * 4 + nt) * 64 + lane) * 8);
            bf16x8 b = expand_frag(pw);
            acc = mfma16(a, b, acc);
        }
        int col = nt * 16 + lm;
        if (col < NC) {
            const float bv = eb3[e * NC + col];
            const float sc = s3[e];
            #pragma unroll
            for (int r = 0; r < 4; ++r) {
                int row = mt * 16 + lk * 4 + r;
                int R2 = rowL[row];
                if (R2 >= 0) {
                    float v = gL[row] * fmaf(acc[r], sc, bv);
                    float* Sb = slotL[row] ? S1 : S0;
                    Sb[(size_t)R2 * 64 + col] = v;
                }
            }
        }
    }
}

// ---------------- combine
__global__ __launch_bounds__(256) void combine_kernel(
    const float* __restrict__ S0, const float* __restrict__ S1, float* __restrict__ out)
{
    int i = blockIdx.x * 256 + threadIdx.x;
    if (i < B_ROWS * NC) {
        int row = i / NC, col = i % NC;
        out[i] = S0[(size_t)row * 64 + col] + S1[(size_t)row * 64 + col];
    }
}

extern "C" void kernel_launch(void* const* d_in, const int* in_sizes, int n_in,
                              void* d_out, int out_size, void* d_ws, size_t ws_size,
                              hipStream_t stream) {
    const float* x   = (const float*)d_in[0];
    const float* rW1 = (const float*)d_in[1];
    const float* rb1 = (const float*)d_in[2];
    const float* rW2 = (const float*)d_in[3];
    const float* rb2 = (const float*)d_in[4];
    const float* rW3 = (const float*)d_in[5];
    const float* rb3 = (const float*)d_in[6];
    const float* eW1 = (const float*)d_in[7];
    const float* eb1 = (const float*)d_in[8];
    const float* eW2 = (const float*)d_in[9];
    const float* eb2 = (const float*)d_in[10];
    const float* eW3 = (const float*)d_in[11];
    const float* eb3 = (const float*)d_in[12];

    float* out_main = (float*)d_out;
    float* router_p = out_main + (size_t)B_ROWS * NC;
    float* lb_out   = router_p + (size_t)B_ROWS * NE;

    char* ws = (char*)d_ws;
    size_t off = 0;
    unsigned char* W1p8 = (unsigned char*)(ws + off); off += (size_t)NE * 49152 * 8;
    unsigned char* W2p8 = (unsigned char*)(ws + off); off += (size_t)NE * 16384 * 8;
    unsigned char* W3p8 = (unsigned char*)(ws + off); off += (size_t)NE * 2048 * 8;
    float* S0   = (float*)(ws + off);  off += (size_t)B_ROWS * 64 * 4;
    float* S1   = (float*)(ws + off);  off += (size_t)B_ROWS * 64 * 4;
    ushort* rw1hp = (ushort*)(ws + off); off += (size_t)24576 * 8 * 2;
    ushort* rw1lp = (ushort*)(ws + off); off += (size_t)24576 * 8 * 2;
    ushort* rw2hp = (ushort*)(ws + off); off += (size_t)4096 * 8 * 2;
    ushort* rw2lp = (ushort*)(ws + off); off += (size_t)4096 * 8 * 2;
    float* gate = (float*)(ws + off);  off += (size_t)B_ROWS * NE * 4;
    int*   ent  = (int*)(ws + off);    off += (size_t)NE * B_ROWS * 4;
    int*   t2   = (int*)(ws + off);    off += (size_t)B_ROWS * 4;
    int* counts = (int*)(ws + off);    off += 256;
    float* s1   = (float*)(ws + off);  off += 256;
    float* s2   = (float*)(ws + off);  off += 256;
    float* s3   = (float*)(ws + off);  off += 256;
    float* p1   = (float*)(ws + off);  off += NE * 96 * 4;
    float* p2   = (float*)(ws + off);  off += NE * 32 * 4;
    float* p3   = (float*)(ws + off);  off += NE * 4 * 4;

    // 1) prep
    pack_absum_kernel<<<dim3(96, 24), 512, 0, stream>>>(
        eW1, eW2, eW3, W1p8, W2p8, W3p8, p1, p2, p3);
    pack_router_kernel<<<56, 512, 0, stream>>>(rW1, rw1hp, rw1lp, rW2, rw2hp, rw2lp);
    finalize_scales_kernel<<<1, 64, 0, stream>>>(p1, p2, p3, s1, s2, s3, counts);

    // 2) fused router (W global->register, 2 blocks/CU)
    router_fused_kernel<<<B_ROWS / 32, 1024, 0, stream>>>(
        x, rw1hp, rw1lp, rb1, rw2hp, rw2lp, rb2, rW3, rb3, router_p, gate, lb_out, t2);
    build_lists_kernel<<<B_ROWS / 256, 256, 0, stream>>>(t2, counts, ent);

    // 3) sparse fused experts (W global->register) + combine
    expert_fused_kernel<<<1024, 1024, 0, stream>>>(
        x, W1p8, W2p8, W3p8, s1, s2, s3, eb1, eb2, eb3, gate, counts, ent, S0, S1);
    combine_kernel<<<(B_ROWS * NC + 255) / 256, 256, 0, stream>>>(S0, S1, out_main);
}

// Round 25
// 121.802 us; speedup vs baseline: 1.9038x; 1.0246x over previous
//
#include <hip/hip_runtime.h>
#include <hip/hip_bf16.h>

typedef __attribute__((ext_vector_type(4))) float f32x4;
typedef __attribute__((ext_vector_type(8))) short bf16x8;

#define B_ROWS 16384
#define IN_DIM 768
#define H1 512
#define H2 256
#define NC 50
#define NE 8
#define RH1 256
#define RH2 128
#define CHK 128

static __device__ __forceinline__ f32x4 mfma16(bf16x8 a, bf16x8 b, f32x4 c) {
    return __builtin_amdgcn_mfma_f32_16x16x32_bf16(a, b, c, 0, 0, 0);
}

// expand 8 ternary byte-codes (bf16 high byte: 0x3F/0xBF/0x00) to exact bf16x8
static __device__ __forceinline__ bf16x8 expand_frag(uint2 pw) {
    unsigned q0 = (pw.x & 0x01010101u) << 7;
    unsigned q1 = (pw.y & 0x01010101u) << 7;
    union { unsigned u[4]; bf16x8 v; } r;
    r.u[0] = __builtin_amdgcn_perm(pw.x, q0, 0x05010400u);
    r.u[1] = __builtin_amdgcn_perm(pw.x, q0, 0x07030602u);
    r.u[2] = __builtin_amdgcn_perm(pw.y, q1, 0x05010400u);
    r.u[3] = __builtin_amdgcn_perm(pw.y, q1, 0x07030602u);
    return r.v;
}

// decompose float4 -> bf16 hi/lo ushort4 pair
static __device__ __forceinline__ void decomp_f4(float4 v, ushort4* hv, ushort4* lv) {
    float vv[4] = {v.x, v.y, v.z, v.w};
    ushort ho[4], lo4[4];
    #pragma unroll
    for (int q = 0; q < 4; ++q) {
        __hip_bfloat16 h = __float2bfloat16(vv[q]);
        float hf = __bfloat162float(h);
        __hip_bfloat16 l = __float2bfloat16(vv[q] - hf);
        ho[q] = *(ushort*)&h; lo4[q] = *(ushort*)&l;
    }
    *hv = make_ushort4(ho[0], ho[1], ho[2], ho[3]);
    *lv = make_ushort4(lo4[0], lo4[1], lo4[2], lo4[3]);
}

static __device__ __forceinline__ ushort4 cvt_f4_bf16(float4 v) {
    float vv[4] = {v.x, v.y, v.z, v.w};
    ushort ho[4];
    #pragma unroll
    for (int q = 0; q < 4; ++q) {
        __hip_bfloat16 h = __float2bfloat16(vv[q]);
        ho[q] = *(ushort*)&h;
    }
    return make_ushort4(ho[0], ho[1], ho[2], ho[3]);
}

// ---------------- merged ternarize+pack+abs-sum + router-pack: grid (96, 25), 512 thr.
// y<24: expert mats (+counts zeroing at (0,0)). y==24: router hi/lo pack (no sync path).
__global__ __launch_bounds__(512) void pack_absum_kernel(
    const float* __restrict__ eW1, const float* __restrict__ eW2, const float* __restrict__ eW3,
    unsigned char* __restrict__ W1p8, unsigned char* __restrict__ W2p8,
    unsigned char* __restrict__ W3p8,
    float* __restrict__ p1, float* __restrict__ p2, float* __restrict__ p3,
    const float* __restrict__ rW1, ushort* __restrict__ rw1hp, ushort* __restrict__ rw1lp,
    const float* __restrict__ rW2, ushort* __restrict__ rw2hp, ushort* __restrict__ rw2lp,
    int* __restrict__ counts)
{
    if (blockIdx.y == 24) {
        // ---- router weight pack (block-uniform path, no __syncthreads)
        int u = blockIdx.x * 512 + threadIdx.x;
        const float* src; ushort* dh; ushort* dl;
        if (u < 24576) {
            int lane = u & 63, nblk = (u >> 6) & 15, ks = u >> 10;
            int n = nblk * 16 + (lane & 15), k = ks * 32 + (lane >> 4) * 8;
            src = rW1 + (size_t)n * IN_DIM + k;
            dh = rw1hp + (size_t)u * 8; dl = rw1lp + (size_t)u * 8;
        } else {
            int v = u - 24576;
            if (v >= 4096) return;
            int lane = v & 63, nblk = (v >> 6) & 7, ks = v >> 9;
            int n = nblk * 16 + (lane & 15), k = ks * 32 + (lane >> 4) * 8;
            src = rW2 + (size_t)n * RH1 + k;
            dh = rw2hp + (size_t)v * 8; dl = rw2lp + (size_t)v * 8;
        }
        ushort oh[8], ol[8];
        #pragma unroll
        for (int j = 0; j < 8; ++j) {
            float w = src[j];
            __hip_bfloat16 h = __float2bfloat16(w);
            float hf = __bfloat162float(h);
            __hip_bfloat16 l = __float2bfloat16(w - hf);
            oh[j] = *(ushort*)&h; ol[j] = *(ushort*)&l;
        }
        ((ushort4*)dh)[0] = make_ushort4(oh[0], oh[1], oh[2], oh[3]);
        ((ushort4*)dh)[1] = make_ushort4(oh[4], oh[5], oh[6], oh[7]);
        ((ushort4*)dl)[0] = make_ushort4(ol[0], ol[1], ol[2], ol[3]);
        ((ushort4*)dl)[1] = make_ushort4(ol[4], ol[5], ol[6], ol[7]);
        return;
    }

    const int mat = blockIdx.y >> 3, e = blockIdx.y & 7;
    const int u = blockIdx.x * 512 + threadIdx.x;
    if (blockIdx.x == 0 && blockIdx.y == 0 && threadIdx.x < 8) counts[threadIdx.x] = 0;
    const float* src; unsigned char* dst; int valid = 1; float* P; int np;
    if (mat == 0) {
        int lane = u & 63, nblk = (u >> 6) & 31, ks = u >> 11;
        int n = nblk * 16 + (lane & 15), k = ks * 32 + (lane >> 4) * 8;
        src = eW1 + ((size_t)e * H1 + n) * IN_DIM + k;
        dst = W1p8 + (size_t)e * 393216
            + (size_t)ks * 16384 + (nblk >> 1) * 1024 + lane * 16 + (nblk & 1) * 8;
        P = p1; np = 96;
    } else if (mat == 1) {
        if (u >= 16384) { if (u == 16384) {} }
        int lane = u & 63, nblk = (u >> 6) & 15, ks = u >> 10;
        int active = (u < 16384);
        if (!active) { // still participate in sync below with s=0
            float s = 0.f;
            const int lane2 = threadIdx.x & 63, wave2 = threadIdx.x >> 6;
            #pragma unroll
            for (int o = 32; o; o >>= 1) s += __shfl_down(s, o);
            __shared__ float redp[8];
            if (lane2 == 0) redp[wave2] = s;
            __syncthreads();
            return;
        }
        int n = nblk * 16 + (lane & 15), k = ks * 32 + (lane >> 4) * 8;
        src = eW2 + ((size_t)e * H2 + n) * H1 + k;
        dst = W2p8 + (size_t)e * 131072
            + (size_t)ks * 8192 + (nblk >> 1) * 1024 + lane * 16 + (nblk & 1) * 8;
        P = p2; np = 32;
    } else {
        if (u >= 2048) {
            float s = 0.f;
            const int lane2 = threadIdx.x & 63, wave2 = threadIdx.x >> 6;
            #pragma unroll
            for (int o = 32; o; o >>= 1) s += __shfl_down(s, o);
            __shared__ float redp2[8];
            if (lane2 == 0) redp2[wave2] = s;
            __syncthreads();
            return;
        }
        int lane = u & 63, nblk = (u >> 6) & 3, ks = u >> 8;
        int n = nblk * 16 + (lane & 15), k = ks * 32 + (lane >> 4) * 8;
        valid = (n < NC);
        src = eW3 + ((size_t)e * NC + (valid ? n : 0)) * H2 + k;
        dst = W3p8 + ((size_t)e * 2048 + u) * 8;
        P = p3; np = 4;
    }
    unsigned lo = 0, hi = 0;
    float s = 0.f;
    #pragma unroll
    for (int j = 0; j < 4; ++j) {
        float w = valid ? src[j] : 0.f;
        s += fabsf(w);
        unsigned c = (fabsf(w) > 0.05f) ? (w > 0.f ? 0x3Fu : 0xBFu) : 0u;
        lo |= c << (8 * j);
    }
    #pragma unroll
    for (int j = 0; j < 4; ++j) {
        float w = valid ? src[4 + j] : 0.f;
        s += fabsf(w);
        unsigned c = (fabsf(w) > 0.05f) ? (w > 0.f ? 0x3Fu : 0xBFu) : 0u;
        hi |= c << (8 * j);
    }
    *(uint2*)dst = make_uint2(lo, hi);
    const int lane = threadIdx.x & 63, wave = threadIdx.x >> 6;
    #pragma unroll
    for (int o = 32; o; o >>= 1) s += __shfl_down(s, o);
    __shared__ float red[8];
    if (lane == 0) red[wave] = s;
    __syncthreads();
    if (threadIdx.x == 0) {
        float t = 0.f;
        #pragma unroll
        for (int i = 0; i < 8; ++i) t += red[i];
        P[e * np + blockIdx.x] = t;
    }
}

// ---------------- fused router, 1024 threads; W global->register (unchanged from R24)
__global__ __launch_bounds__(1024) void router_fused_kernel(
    const float* __restrict__ x,
    const ushort* __restrict__ rw1hp, const ushort* __restrict__ rw1lp, const float* __restrict__ rb1,
    const ushort* __restrict__ rw2hp, const ushort* __restrict__ rw2lp, const float* __restrict__ rb2,
    const float* __restrict__ rW3, const float* __restrict__ rb3,
    float* __restrict__ router_p, float* __restrict__ gate,
    float* __restrict__ lb_out, int* __restrict__ t2)
{
    __shared__ __align__(16) unsigned char smem[68608];
    ushort (*Xdh)[32][136] = (ushort(*)[32][136])(smem);
    ushort (*Xdl)[32][136] = (ushort(*)[32][136])(smem + 17408);
    ushort (*h1hs)[264]    = (ushort(*)[264])(smem + 34816);
    ushort (*h1ls)[264]    = (ushort(*)[264])(smem + 51712);
    float (*h2s)[132]      = (float(*)[132])(smem);

    const int tid = threadIdx.x, wave = tid >> 6, lane = tid & 63;
    const int lm = lane & 15, lk = lane >> 4;
    const int r0 = blockIdx.x * 32;

    const int srow = tid >> 5;
    const int sc4r = (tid & 31) * 4;
    const float* sg = x + (size_t)(r0 + srow) * IN_DIM + sc4r;

    {
        float4 sv = *(const float4*)sg;
        ushort4 hv, lv;
        decomp_f4(sv, &hv, &lv);
        *(ushort4*)&Xdh[0][srow][sc4r] = hv;
        *(ushort4*)&Xdl[0][srow][sc4r] = lv;
    }
    __syncthreads();

    // ---- layer 1: 6 intervals x 4 K-steps; W global->reg depth-4
    {
        f32x4 acc[2] = {};
        const ushort* wph = rw1hp + (size_t)(wave * 64 + lane) * 8;
        const ushort* wpl = rw1lp + (size_t)(wave * 64 + lane) * 8;
        uint4 ph[4], pl[4];
        #pragma unroll
        for (int k = 0; k < 4; ++k) {
            ph[k] = *(const uint4*)(wph + (size_t)k * 8192);
            pl[k] = *(const uint4*)(wpl + (size_t)k * 8192);
        }
        for (int i = 0; i < 6; ++i) {
            float4 sv;
            if (i + 1 < 6) sv = *(const float4*)(sg + (i + 1) * CHK);
            const ushort (*Xch)[136] = Xdh[i & 1];
            const ushort (*Xcl)[136] = Xdl[i & 1];
            #pragma unroll
            for (int k4 = 0; k4 < 4; ++k4) {
                uint4 ch = ph[k4], cl = pl[k4];
                if (i + 1 < 6) {
                    ph[k4] = *(const uint4*)(wph + (size_t)(4 * i + 4 + k4) * 8192);
                    pl[k4] = *(const uint4*)(wpl + (size_t)(4 * i + 4 + k4) * 8192);
                }
                const int ko = k4 * 32 + lk * 8;
                bf16x8 ah0 = *(const bf16x8*)&Xch[lm][ko];
                bf16x8 al0 = *(const bf16x8*)&Xcl[lm][ko];
                bf16x8 ah1 = *(const bf16x8*)&Xch[16 + lm][ko];
                bf16x8 al1 = *(const bf16x8*)&Xcl[16 + lm][ko];
                bf16x8 bh = *(bf16x8*)&ch;
                bf16x8 bl = *(bf16x8*)&cl;
                acc[0] = mfma16(ah0, bh, acc[0]);
                acc[0] = mfma16(ah0, bl, acc[0]);
                acc[0] = mfma16(al0, bh, acc[0]);
                acc[1] = mfma16(ah1, bh, acc[1]);
                acc[1] = mfma16(ah1, bl, acc[1]);
                acc[1] = mfma16(al1, bh, acc[1]);
            }
            if (i + 1 < 6) {
                ushort4 hv, lv;
                decomp_f4(sv, &hv, &lv);
                *(ushort4*)&Xdh[(i + 1) & 1][srow][sc4r] = hv;
                *(ushort4*)&Xdl[(i + 1) & 1][srow][sc4r] = lv;
            }
            __syncthreads();
        }
        int col = wave * 16 + lm;
        float bv = rb1[col];
        #pragma unroll
        for (int m = 0; m < 2; ++m)
            #pragma unroll
            for (int r = 0; r < 4; ++r) {
                float v = acc[m][r] + bv;
                v = v > 0.f ? v : 0.f;
                __hip_bfloat16 h = __float2bfloat16(v);
                float hf = __bfloat162float(h);
                __hip_bfloat16 l = __float2bfloat16(v - hf);
                int row = m * 16 + lk * 4 + r;
                h1hs[row][col] = *(ushort*)&h;
                h1ls[row][col] = *(ushort*)&l;
            }
    }
    __syncthreads();

    // ---- layer 2: 8 K-steps, barrier-free; W global->reg depth-2
    {
        const int mt = wave >> 3, nb = wave & 7;
        const ushort* w2h = rw2hp + (size_t)(nb * 64 + lane) * 8;
        const ushort* w2l = rw2lp + (size_t)(nb * 64 + lane) * 8;
        f32x4 acc2 = {};
        uint4 pha = *(const uint4*)(w2h);
        uint4 pla = *(const uint4*)(w2l);
        uint4 phb = *(const uint4*)(w2h + 4096);
        uint4 plb = *(const uint4*)(w2l + 4096);
        for (int s = 0; s < 8; s += 2) {
            uint4 cha = pha, cla = pla, chb = phb, clb = plb;
            if (s + 2 < 8) {
                pha = *(const uint4*)(w2h + (size_t)(s + 2) * 4096);
                pla = *(const uint4*)(w2l + (size_t)(s + 2) * 4096);
                phb = *(const uint4*)(w2h + (size_t)(s + 3) * 4096);
                plb = *(const uint4*)(w2l + (size_t)(s + 3) * 4096);
            }
            {
                const int ko = s * 32 + lk * 8;
                bf16x8 ah = *(const bf16x8*)&h1hs[mt * 16 + lm][ko];
                bf16x8 al = *(const bf16x8*)&h1ls[mt * 16 + lm][ko];
                bf16x8 bh = *(bf16x8*)&cha;
                bf16x8 bl = *(bf16x8*)&cla;
                acc2 = mfma16(ah, bh, acc2);
                acc2 = mfma16(ah, bl, acc2);
                acc2 = mfma16(al, bh, acc2);
            }
            {
                const int ko = (s + 1) * 32 + lk * 8;
                bf16x8 ah = *(const bf16x8*)&h1hs[mt * 16 + lm][ko];
                bf16x8 al = *(const bf16x8*)&h1ls[mt * 16 + lm][ko];
                bf16x8 bh = *(bf16x8*)&chb;
                bf16x8 bl = *(bf16x8*)&clb;
                acc2 = mfma16(ah, bh, acc2);
                acc2 = mfma16(ah, bl, acc2);
                acc2 = mfma16(al, bh, acc2);
            }
        }
        __syncthreads();
        int col2 = nb * 16 + lm;
        float bv = rb2[col2];
        #pragma unroll
        for (int r = 0; r < 4; ++r) {
            float v = acc2[r] + bv;
            h2s[mt * 16 + lk * 4 + r][col2] = v > 0.f ? v : 0.f;
        }
    }
    __syncthreads();

    // ---- head
    const int o = lane >> 3, kq = lane & 7;
    #pragma unroll
    for (int i = 0; i < 2; ++i) {
        int rloc = wave * 2 + i;
        int b = r0 + rloc;
        float s = 0.f;
        #pragma unroll
        for (int q = 0; q < 4; ++q) {
            float4 hv = *(const float4*)&h2s[rloc][kq * 16 + q * 4];
            float4 wv = *(const float4*)&rW3[o * RH2 + kq * 16 + q * 4];
            s += hv.x * wv.x + hv.y * wv.y + hv.z * wv.z + hv.w * wv.w;
        }
        s += __shfl_xor(s, 1);
        s += __shfl_xor(s, 2);
        s += __shfl_xor(s, 4);
        float logit = s + rb3[o];
        float l[8];
        #pragma unroll
        for (int j = 0; j < 8; ++j) l[j] = __shfl(logit, j * 8);
        float m = l[0];
        #pragma unroll
        for (int j = 1; j < 8; ++j) m = fmaxf(m, l[j]);
        float p[8]; float sum = 0.f;
        #pragma unroll
        for (int j = 0; j < 8; ++j) { p[j] = expf(l[j] - m); sum += p[j]; }
        float inv = 1.f / sum;
        #pragma unroll
        for (int j = 0; j < 8; ++j) p[j] *= inv;
        int i1 = 0; float v1 = p[0];
        #pragma unroll
        for (int j = 1; j < 8; ++j) if (p[j] > v1) { v1 = p[j]; i1 = j; }
        int i2 = -1; float v2 = -1.f;
        #pragma unroll
        for (int j = 0; j < 8; ++j) if (j != i1 && p[j] > v2) { v2 = p[j]; i2 = j; }
        if (lane < 8) {
            router_p[(size_t)b * 8 + lane] = p[lane];
            float gv = (lane == i1) ? v1 * 0.5f : ((lane == i2) ? v2 * 0.5f : 0.f);
            gate[(size_t)b * 8 + lane] = gv;
        }
        if (lane == 0) t2[b] = i1 | (i2 << 8);
    }
    if (blockIdx.x == 0 && tid == 0) lb_out[0] = 0.f;
}

// ---------------- build dispatch lists + finalize scales (block 0)
__global__ __launch_bounds__(256) void build_lists_kernel(
    const int* __restrict__ t2, int* __restrict__ counts, int* __restrict__ ent,
    const float* __restrict__ p1, const float* __restrict__ p2, const float* __restrict__ p3,
    float* __restrict__ s1, float* __restrict__ s2, float* __restrict__ s3)
{
    if (blockIdx.x == 0 && threadIdx.x < 24) {
        int t = threadIdx.x;
        if (t < 8) {
            float a = 0.f;
            for (int i = 0; i < 96; ++i) a += p1[t * 96 + i];
            s1[t] = a / (float)(H1 * IN_DIM);
        } else if (t < 16) {
            int e = t - 8; float a = 0.f;
            for (int i = 0; i < 32; ++i) a += p2[e * 32 + i];
            s2[e] = a / (float)(H2 * H1);
        } else {
            int e = t - 16; float a = 0.f;
            for (int i = 0; i < 4; ++i) a += p3[e * 4 + i];
            s3[e] = a / (float)(NC * H2);
        }
    }
    __shared__ int hist[8], base[8];
    const int r = blockIdx.x * 256 + threadIdx.x;
    if (threadIdx.x < 8) hist[threadIdx.x] = 0;
    __syncthreads();
    const int v = t2[r];
    const int i1 = v & 255, i2 = v >> 8;
    const int rk1 = atomicAdd(&hist[i1], 1);
    const int rk2 = atomicAdd(&hist[i2], 1);
    __syncthreads();
    if (threadIdx.x < 8) base[threadIdx.x] = atomicAdd(&counts[threadIdx.x], hist[threadIdx.x]);
    __syncthreads();
    ent[i1 * B_ROWS + base[i1] + rk1] = (r << 1);
    ent[i2 * B_ROWS + base[i2] + rk2] = (r << 1) | 1;
}

// ---------------- sparse fused expert kernel (R23/R24 best, unchanged)
__global__ __launch_bounds__(1024) void expert_fused_kernel(
    const float* __restrict__ x,
    const unsigned char* __restrict__ W1p8, const unsigned char* __restrict__ W2p8,
    const unsigned char* __restrict__ W3p8,
    const float* __restrict__ s1, const float* __restrict__ s2, const float* __restrict__ s3,
    const float* __restrict__ eb1, const float* __restrict__ eb2, const float* __restrict__ eb3,
    const float* __restrict__ gate,
    const int* __restrict__ counts, const int* __restrict__ ent,
    float* __restrict__ S0, float* __restrict__ S1)
{
    int pfx[9]; pfx[0] = 0;
    #pragma unroll
    for (int i = 0; i < 8; ++i) pfx[i + 1] = pfx[i] + ((counts[i] + 63) >> 6);
    const int T = pfx[8];
    const int R = (T + 7) >> 3;
    const int xcd = blockIdx.x & 7, j = blockIdx.x >> 3;
    if (j >= R) return;
    const int g = xcd * R + j;
    if (g >= T) return;
    int e = 0;
    #pragma unroll
    for (int i = 0; i < 7; ++i) if (g >= pfx[i + 1]) e = i + 1;
    const int t = g - pfx[e];
    const int cnt = counts[e];

    __shared__ __align__(16) unsigned char smem[101376];
    __hip_bfloat16 (*A1s)[520] = (__hip_bfloat16(*)[520])(smem);
    __hip_bfloat16 (*A2s)[264] = (__hip_bfloat16(*)[264])(smem + 66560);
    ushort (*Xd)[64][136]      = (ushort(*)[64][136])(smem + 66560);
    __shared__ int rowL[64];
    __shared__ int slotL[64];
    __shared__ float gL[64];

    const int tid = threadIdx.x;
    const int wave = tid >> 6;
    const int lane = tid & 63;
    const int lm = lane & 15;
    const int lk = lane >> 4;

    if (tid < 64) {
        int idx = t * 64 + tid;
        if (idx < cnt) {
            int entv = ent[e * B_ROWS + idx];
            int r = entv >> 1;
            rowL[tid] = r;
            slotL[tid] = entv & 1;
            gL[tid] = gate[(size_t)r * NE + e];
        } else {
            rowL[tid] = -1; slotL[tid] = 0; gL[tid] = 0.f;
        }
    }
    __syncthreads();

    const int srow = tid >> 4;
    const int sc8  = (tid & 15) * 8;
    int SR = rowL[srow]; if (SR < 0) SR = 0;
    const float* sg = x + (size_t)SR * IN_DIM + sc8;
    const unsigned char* Wsrc1 = W1p8 + (size_t)e * 393216;
    const unsigned char* Wsrc2 = W2p8 + (size_t)e * 131072;
    const unsigned char* Wsrc3 = W3p8 + (size_t)e * 16384;

    {
        float4 fa = *(const float4*)(sg);
        float4 fb = *(const float4*)(sg + 4);
        *(ushort4*)&Xd[0][srow][sc8]     = cvt_f4_bf16(fa);
        *(ushort4*)&Xd[0][srow][sc8 + 4] = cvt_f4_bf16(fb);
    }
    __syncthreads();

    // ---- layer 1: 6 intervals x 4 K-steps; W global->reg, depth-4 prefetch
    {
        f32x4 acc[4][2] = {};
        const int w2 = wave * 2;
        const unsigned char* wp1 = Wsrc1 + wave * 1024 + lane * 16;
        uint4 pw[4];
        #pragma unroll
        for (int k = 0; k < 4; ++k)
            pw[k] = *(const uint4*)(wp1 + (size_t)k * 16384);
        for (int i = 0; i < 6; ++i) {
            float4 fa, fb;
            if (i + 1 < 6) {
                fa = *(const float4*)(sg + (i + 1) * CHK);
                fb = *(const float4*)(sg + (i + 1) * CHK + 4);
            }
            uint4 cur[4];
            #pragma unroll
            for (int k = 0; k < 4; ++k) cur[k] = pw[k];
            if (i + 1 < 6) {
                #pragma unroll
                for (int k = 0; k < 4; ++k)
                    pw[k] = *(const uint4*)(wp1 + (size_t)(4 * i + 4 + k) * 16384);
            }
            const ushort (*Xc)[136] = Xd[i & 1];
            #pragma unroll
            for (int k4 = 0; k4 < 4; ++k4) {
                const int ko = k4 * 32 + lk * 8;
                bf16x8 a0 = *(const bf16x8*)&Xc[     lm][ko];
                bf16x8 a1 = *(const bf16x8*)&Xc[16 + lm][ko];
                bf16x8 a2 = *(const bf16x8*)&Xc[32 + lm][ko];
                bf16x8 a3 = *(const bf16x8*)&Xc[48 + lm][ko];
                bf16x8 b0 = expand_frag(make_uint2(cur[k4].x, cur[k4].y));
                bf16x8 b1 = expand_frag(make_uint2(cur[k4].z, cur[k4].w));
                acc[0][0] = mfma16(a0, b0, acc[0][0]);
                acc[1][0] = mfma16(a1, b0, acc[1][0]);
                acc[2][0] = mfma16(a2, b0, acc[2][0]);
                acc[3][0] = mfma16(a3, b0, acc[3][0]);
                acc[0][1] = mfma16(a0, b1, acc[0][1]);
                acc[1][1] = mfma16(a1, b1, acc[1][1]);
                acc[2][1] = mfma16(a2, b1, acc[2][1]);
                acc[3][1] = mfma16(a3, b1, acc[3][1]);
            }
            if (i + 1 < 6) {
                *(ushort4*)&Xd[(i + 1) & 1][srow][sc8]     = cvt_f4_bf16(fa);
                *(ushort4*)&Xd[(i + 1) & 1][srow][sc8 + 4] = cvt_f4_bf16(fb);
            }
            __syncthreads();
        }
        const float* bias = eb1 + e * H1;
        const float sc = s1[e];
        #pragma unroll
        for (int n = 0; n < 2; ++n) {
            int ncol = (w2 + n) * 16 + lm;
            float bv = bias[ncol];
            #pragma unroll
            for (int m = 0; m < 4; ++m)
                #pragma unroll
                for (int r = 0; r < 4; ++r) {
                    float v = fmaf(acc[m][n][r], sc, bv);
                    v = v > 0.f ? v : 0.f;
                    A1s[m * 16 + lk * 4 + r][ncol] = __float2bfloat16(v);
                }
        }
    }
    __syncthreads();

    // ---- layer 2: 16 K-steps, zero internal barriers; W global->reg, depth-2
    {
        const int mt = wave >> 3, ntw = wave & 7;
        const unsigned char* wp2 = Wsrc2 + ntw * 1024 + lane * 16;
        f32x4 acc[2][2] = {};
        uint4 pwa = *(const uint4*)(wp2);
        uint4 pwb = *(const uint4*)(wp2 + 8192);
        for (int s = 0; s < 16; s += 2) {
            uint4 c0 = pwa, c1 = pwb;
            if (s + 2 < 16) {
                pwa = *(const uint4*)(wp2 + (size_t)(s + 2) * 8192);
                pwb = *(const uint4*)(wp2 + (size_t)(s + 3) * 8192);
            }
            {
                const int ko = s * 32 + lk * 8;
                bf16x8 a0 = *(const bf16x8*)&A1s[mt * 32 +      lm][ko];
                bf16x8 a1 = *(const bf16x8*)&A1s[mt * 32 + 16 + lm][ko];
                bf16x8 b0 = expand_frag(make_uint2(c0.x, c0.y));
                bf16x8 b1 = expand_frag(make_uint2(c0.z, c0.w));
                acc[0][0] = mfma16(a0, b0, acc[0][0]);
                acc[1][0] = mfma16(a1, b0, acc[1][0]);
                acc[0][1] = mfma16(a0, b1, acc[0][1]);
                acc[1][1] = mfma16(a1, b1, acc[1][1]);
            }
            {
                const int ko = (s + 1) * 32 + lk * 8;
                bf16x8 a0 = *(const bf16x8*)&A1s[mt * 32 +      lm][ko];
                bf16x8 a1 = *(const bf16x8*)&A1s[mt * 32 + 16 + lm][ko];
                bf16x8 b0 = expand_frag(make_uint2(c1.x, c1.y));
                bf16x8 b1 = expand_frag(make_uint2(c1.z, c1.w));
                acc[0][0] = mfma16(a0, b0, acc[0][0]);
                acc[1][0] = mfma16(a1, b0, acc[1][0]);
                acc[0][1] = mfma16(a0, b1, acc[0][1]);
                acc[1][1] = mfma16(a1, b1, acc[1][1]);
            }
        }
        const float* bias = eb2 + e * H2;
        const float sc = s2[e];
        #pragma unroll
        for (int n = 0; n < 2; ++n) {
            int ncol = (ntw * 2 + n) * 16 + lm;
            float bv = bias[ncol];
            #pragma unroll
            for (int m = 0; m < 2; ++m)
                #pragma unroll
                for (int r = 0; r < 4; ++r) {
                    float v = fmaf(acc[m][n][r], sc, bv);
                    v = v > 0.f ? v : 0.f;
                    A2s[mt * 32 + m * 16 + lk * 4 + r][ncol] = __float2bfloat16(v);
                }
        }
    }
    __syncthreads();

    // ---- layer 3: W3 global->reg (flat layout)
    {
        const int mt = wave & 3, nt = wave >> 2;
        f32x4 acc = {};
        #pragma unroll
        for (int s = 0; s < 8; ++s) {
            bf16x8 a = *(const bf16x8*)&A2s[mt * 16 + lm][s * 32 + lk * 8];
            uint2 pw = *(const uint2*)(Wsrc3 + ((s * 4 + nt) * 64 + lane) * 8);
            bf16x8 b = expand_frag(pw);
            acc = mfma16(a, b, acc);
        }
        int col = nt * 16 + lm;
        if (col < NC) {
            const float bv = eb3[e * NC + col];
            const float sc = s3[e];
            #pragma unroll
            for (int r = 0; r < 4; ++r) {
                int row = mt * 16 + lk * 4 + r;
                int R2 = rowL[row];
                if (R2 >= 0) {
                    float v = gL[row] * fmaf(acc[r], sc, bv);
                    float* Sb = slotL[row] ? S1 : S0;
                    Sb[(size_t)R2 * 64 + col] = v;
                }
            }
        }
    }
}

// ---------------- combine
__global__ __launch_bounds__(256) void combine_kernel(
    const float* __restrict__ S0, const float* __restrict__ S1, float* __restrict__ out)
{
    int i = blockIdx.x * 256 + threadIdx.x;
    if (i < B_ROWS * NC) {
        int row = i / NC, col = i % NC;
        out[i] = S0[(size_t)row * 64 + col] + S1[(size_t)row * 64 + col];
    }
}

extern "C" void kernel_launch(void* const* d_in, const int* in_sizes, int n_in,
                              void* d_out, int out_size, void* d_ws, size_t ws_size,
                              hipStream_t stream) {
    const float* x   = (const float*)d_in[0];
    const float* rW1 = (const float*)d_in[1];
    const float* rb1 = (const float*)d_in[2];
    const float* rW2 = (const float*)d_in[3];
    const float* rb2 = (const float*)d_in[4];
    const float* rW3 = (const float*)d_in[5];
    const float* rb3 = (const float*)d_in[6];
    const float* eW1 = (const float*)d_in[7];
    const float* eb1 = (const float*)d_in[8];
    const float* eW2 = (const float*)d_in[9];
    const float* eb2 = (const float*)d_in[10];
    const float* eW3 = (const float*)d_in[11];
    const float* eb3 = (const float*)d_in[12];

    float* out_main = (float*)d_out;
    float* router_p = out_main + (size_t)B_ROWS * NC;
    float* lb_out   = router_p + (size_t)B_ROWS * NE;

    char* ws = (char*)d_ws;
    size_t off = 0;
    unsigned char* W1p8 = (unsigned char*)(ws + off); off += (size_t)NE * 49152 * 8;
    unsigned char* W2p8 = (unsigned char*)(ws + off); off += (size_t)NE * 16384 * 8;
    unsigned char* W3p8 = (unsigned char*)(ws + off); off += (size_t)NE * 2048 * 8;
    float* S0   = (float*)(ws + off);  off += (size_t)B_ROWS * 64 * 4;
    float* S1   = (float*)(ws + off);  off += (size_t)B_ROWS * 64 * 4;
    ushort* rw1hp = (ushort*)(ws + off); off += (size_t)24576 * 8 * 2;
    ushort* rw1lp = (ushort*)(ws + off); off += (size_t)24576 * 8 * 2;
    ushort* rw2hp = (ushort*)(ws + off); off += (size_t)4096 * 8 * 2;
    ushort* rw2lp = (ushort*)(ws + off); off += (size_t)4096 * 8 * 2;
    float* gate = (float*)(ws + off);  off += (size_t)B_ROWS * NE * 4;
    int*   ent  = (int*)(ws + off);    off += (size_t)NE * B_ROWS * 4;
    int*   t2   = (int*)(ws + off);    off += (size_t)B_ROWS * 4;
    int* counts = (int*)(ws + off);    off += 256;
    float* s1   = (float*)(ws + off);  off += 256;
    float* s2   = (float*)(ws + off);  off += 256;
    float* s3   = (float*)(ws + off);  off += 256;
    float* p1   = (float*)(ws + off);  off += NE * 96 * 4;
    float* p2   = (float*)(ws + off);  off += NE * 32 * 4;
    float* p3   = (float*)(ws + off);  off += NE * 4 * 4;

    // 1) prep (single merged kernel: expert pack+absum, router pack, counts zeroing)
    pack_absum_kernel<<<dim3(96, 25), 512, 0, stream>>>(
        eW1, eW2, eW3, W1p8, W2p8, W3p8, p1, p2, p3,
        rW1, rw1hp, rw1lp, rW2, rw2hp, rw2lp, counts);

    // 2) fused router
    router_fused_kernel<<<B_ROWS / 32, 1024, 0, stream>>>(
        x, rw1hp, rw1lp, rb1, rw2hp, rw2lp, rb2, rW3, rb3, router_p, gate, lb_out, t2);
    // lists + scale finalization (block 0)
    build_lists_kernel<<<B_ROWS / 256, 256, 0, stream>>>(
        t2, counts, ent, p1, p2, p3, s1, s2, s3);

    // 3) sparse fused experts + combine
    expert_fused_kernel<<<1024, 1024, 0, stream>>>(
        x, W1p8, W2p8, W3p8, s1, s2, s3, eb1, eb2, eb3, gate, counts, ent, S0, S1);
    combine_kernel<<<(B_ROWS * NC + 255) / 256, 256, 0, stream>>>(S0, S1, out_main);
}

// Round 26
// 118.588 us; speedup vs baseline: 1.9554x; 1.0271x over previous
//
#include <hip/hip_runtime.h>
#include <hip/hip_bf16.h>

typedef __attribute__((ext_vector_type(4))) float f32x4;
typedef __attribute__((ext_vector_type(8))) short bf16x8;

#define B_ROWS 16384
#define IN_DIM 768
#define H1 512
#define H2 256
#define NC 50
#define NE 8
#define RH1 256
#define RH2 128
#define CHK 128

static __device__ __forceinline__ f32x4 mfma16(bf16x8 a, bf16x8 b, f32x4 c) {
    return __builtin_amdgcn_mfma_f32_16x16x32_bf16(a, b, c, 0, 0, 0);
}

// expand 8 ternary byte-codes (bf16 high byte: 0x3F/0xBF/0x00) to exact bf16x8
static __device__ __forceinline__ bf16x8 expand_frag(uint2 pw) {
    unsigned q0 = (pw.x & 0x01010101u) << 7;
    unsigned q1 = (pw.y & 0x01010101u) << 7;
    union { unsigned u[4]; bf16x8 v; } r;
    r.u[0] = __builtin_amdgcn_perm(pw.x, q0, 0x05010400u);
    r.u[1] = __builtin_amdgcn_perm(pw.x, q0, 0x07030602u);
    r.u[2] = __builtin_amdgcn_perm(pw.y, q1, 0x05010400u);
    r.u[3] = __builtin_amdgcn_perm(pw.y, q1, 0x07030602u);
    return r.v;
}

// decompose float4 -> bf16 hi/lo ushort4 pair
static __device__ __forceinline__ void decomp_f4(float4 v, ushort4* hv, ushort4* lv) {
    float vv[4] = {v.x, v.y, v.z, v.w};
    ushort ho[4], lo4[4];
    #pragma unroll
    for (int q = 0; q < 4; ++q) {
        __hip_bfloat16 h = __float2bfloat16(vv[q]);
        float hf = __bfloat162float(h);
        __hip_bfloat16 l = __float2bfloat16(vv[q] - hf);
        ho[q] = *(ushort*)&h; lo4[q] = *(ushort*)&l;
    }
    *hv = make_ushort4(ho[0], ho[1], ho[2], ho[3]);
    *lv = make_ushort4(lo4[0], lo4[1], lo4[2], lo4[3]);
}

// ---------------- merged ternarize+pack+abs-sum + router-pack: grid (96, 25), 512 thr.
__global__ __launch_bounds__(512) void pack_absum_kernel(
    const float* __restrict__ eW1, const float* __restrict__ eW2, const float* __restrict__ eW3,
    unsigned char* __restrict__ W1p8, unsigned char* __restrict__ W2p8,
    unsigned char* __restrict__ W3p8,
    float* __restrict__ p1, float* __restrict__ p2, float* __restrict__ p3,
    const float* __restrict__ rW1, ushort* __restrict__ rw1hp, ushort* __restrict__ rw1lp,
    const float* __restrict__ rW2, ushort* __restrict__ rw2hp, ushort* __restrict__ rw2lp,
    int* __restrict__ counts)
{
    if (blockIdx.y == 24) {
        int u = blockIdx.x * 512 + threadIdx.x;
        const float* src; ushort* dh; ushort* dl;
        if (u < 24576) {
            int lane = u & 63, nblk = (u >> 6) & 15, ks = u >> 10;
            int n = nblk * 16 + (lane & 15), k = ks * 32 + (lane >> 4) * 8;
            src = rW1 + (size_t)n * IN_DIM + k;
            dh = rw1hp + (size_t)u * 8; dl = rw1lp + (size_t)u * 8;
        } else {
            int v = u - 24576;
            if (v >= 4096) return;
            int lane = v & 63, nblk = (v >> 6) & 7, ks = v >> 9;
            int n = nblk * 16 + (lane & 15), k = ks * 32 + (lane >> 4) * 8;
            src = rW2 + (size_t)n * RH1 + k;
            dh = rw2hp + (size_t)v * 8; dl = rw2lp + (size_t)v * 8;
        }
        ushort oh[8], ol[8];
        #pragma unroll
        for (int j = 0; j < 8; ++j) {
            float w = src[j];
            __hip_bfloat16 h = __float2bfloat16(w);
            float hf = __bfloat162float(h);
            __hip_bfloat16 l = __float2bfloat16(w - hf);
            oh[j] = *(ushort*)&h; ol[j] = *(ushort*)&l;
        }
        ((ushort4*)dh)[0] = make_ushort4(oh[0], oh[1], oh[2], oh[3]);
        ((ushort4*)dh)[1] = make_ushort4(oh[4], oh[5], oh[6], oh[7]);
        ((ushort4*)dl)[0] = make_ushort4(ol[0], ol[1], ol[2], ol[3]);
        ((ushort4*)dl)[1] = make_ushort4(ol[4], ol[5], ol[6], ol[7]);
        return;
    }

    const int mat = blockIdx.y >> 3, e = blockIdx.y & 7;
    const int u = blockIdx.x * 512 + threadIdx.x;
    if (blockIdx.x == 0 && blockIdx.y == 0 && threadIdx.x < 8) counts[threadIdx.x] = 0;
    const float* src; unsigned char* dst; int valid = 1; float* P; int np;
    if (mat == 0) {
        int lane = u & 63, nblk = (u >> 6) & 31, ks = u >> 11;
        int n = nblk * 16 + (lane & 15), k = ks * 32 + (lane >> 4) * 8;
        src = eW1 + ((size_t)e * H1 + n) * IN_DIM + k;
        dst = W1p8 + (size_t)e * 393216
            + (size_t)ks * 16384 + (nblk >> 1) * 1024 + lane * 16 + (nblk & 1) * 8;
        P = p1; np = 96;
    } else if (mat == 1) {
        int lane = u & 63, nblk = (u >> 6) & 15, ks = u >> 10;
        if (u >= 16384) {
            float s = 0.f;
            const int lane2 = threadIdx.x & 63, wave2 = threadIdx.x >> 6;
            #pragma unroll
            for (int o = 32; o; o >>= 1) s += __shfl_down(s, o);
            __shared__ float redp[8];
            if (lane2 == 0) redp[wave2] = s;
            __syncthreads();
            return;
        }
        int n = nblk * 16 + (lane & 15), k = ks * 32 + (lane >> 4) * 8;
        src = eW2 + ((size_t)e * H2 + n) * H1 + k;
        dst = W2p8 + (size_t)e * 131072
            + (size_t)ks * 8192 + (nblk >> 1) * 1024 + lane * 16 + (nblk & 1) * 8;
        P = p2; np = 32;
    } else {
        if (u >= 2048) {
            float s = 0.f;
            const int lane2 = threadIdx.x & 63, wave2 = threadIdx.x >> 6;
            #pragma unroll
            for (int o = 32; o; o >>= 1) s += __shfl_down(s, o);
            __shared__ float redp2[8];
            if (lane2 == 0) redp2[wave2] = s;
            __syncthreads();
            return;
        }
        int lane = u & 63, nblk = (u >> 6) & 3, ks = u >> 8;
        int n = nblk * 16 + (lane & 15), k = ks * 32 + (lane >> 4) * 8;
        valid = (n < NC);
        src = eW3 + ((size_t)e * NC + (valid ? n : 0)) * H2 + k;
        dst = W3p8 + ((size_t)e * 2048 + u) * 8;
        P = p3; np = 4;
    }
    unsigned lo = 0, hi = 0;
    float s = 0.f;
    #pragma unroll
    for (int j = 0; j < 4; ++j) {
        float w = valid ? src[j] : 0.f;
        s += fabsf(w);
        unsigned c = (fabsf(w) > 0.05f) ? (w > 0.f ? 0x3Fu : 0xBFu) : 0u;
        lo |= c << (8 * j);
    }
    #pragma unroll
    for (int j = 0; j < 4; ++j) {
        float w = valid ? src[4 + j] : 0.f;
        s += fabsf(w);
        unsigned c = (fabsf(w) > 0.05f) ? (w > 0.f ? 0x3Fu : 0xBFu) : 0u;
        hi |= c << (8 * j);
    }
    *(uint2*)dst = make_uint2(lo, hi);
    const int lane = threadIdx.x & 63, wave = threadIdx.x >> 6;
    #pragma unroll
    for (int o = 32; o; o >>= 1) s += __shfl_down(s, o);
    __shared__ float red[8];
    if (lane == 0) red[wave] = s;
    __syncthreads();
    if (threadIdx.x == 0) {
        float t = 0.f;
        #pragma unroll
        for (int i = 0; i < 8; ++i) t += red[i];
        P[e * np + blockIdx.x] = t;
    }
}

// ---------------- fused router, 1024 threads; W global->register; NEW: writes bf16
// X-hi image (xh_out) as a by-product of the staging decomposition.
__global__ __launch_bounds__(1024) void router_fused_kernel(
    const float* __restrict__ x, ushort* __restrict__ xh_out,
    const ushort* __restrict__ rw1hp, const ushort* __restrict__ rw1lp, const float* __restrict__ rb1,
    const ushort* __restrict__ rw2hp, const ushort* __restrict__ rw2lp, const float* __restrict__ rb2,
    const float* __restrict__ rW3, const float* __restrict__ rb3,
    float* __restrict__ router_p, float* __restrict__ gate,
    float* __restrict__ lb_out, int* __restrict__ t2)
{
    __shared__ __align__(16) unsigned char smem[68608];
    ushort (*Xdh)[32][136] = (ushort(*)[32][136])(smem);
    ushort (*Xdl)[32][136] = (ushort(*)[32][136])(smem + 17408);
    ushort (*h1hs)[264]    = (ushort(*)[264])(smem + 34816);
    ushort (*h1ls)[264]    = (ushort(*)[264])(smem + 51712);
    float (*h2s)[132]      = (float(*)[132])(smem);

    const int tid = threadIdx.x, wave = tid >> 6, lane = tid & 63;
    const int lm = lane & 15, lk = lane >> 4;
    const int r0 = blockIdx.x * 32;

    const int srow = tid >> 5;
    const int sc4r = (tid & 31) * 4;
    const float* sg = x + (size_t)(r0 + srow) * IN_DIM + sc4r;
    ushort* xo = xh_out + (size_t)(r0 + srow) * IN_DIM + sc4r;

    {
        float4 sv = *(const float4*)sg;
        ushort4 hv, lv;
        decomp_f4(sv, &hv, &lv);
        *(ushort4*)&Xdh[0][srow][sc4r] = hv;
        *(ushort4*)&Xdl[0][srow][sc4r] = lv;
        *(ushort4*)xo = hv;
    }
    __syncthreads();

    // ---- layer 1: 6 intervals x 4 K-steps; W global->reg depth-4
    {
        f32x4 acc[2] = {};
        const ushort* wph = rw1hp + (size_t)(wave * 64 + lane) * 8;
        const ushort* wpl = rw1lp + (size_t)(wave * 64 + lane) * 8;
        uint4 ph[4], pl[4];
        #pragma unroll
        for (int k = 0; k < 4; ++k) {
            ph[k] = *(const uint4*)(wph + (size_t)k * 8192);
            pl[k] = *(const uint4*)(wpl + (size_t)k * 8192);
        }
        for (int i = 0; i < 6; ++i) {
            float4 sv;
            if (i + 1 < 6) sv = *(const float4*)(sg + (i + 1) * CHK);
            const ushort (*Xch)[136] = Xdh[i & 1];
            const ushort (*Xcl)[136] = Xdl[i & 1];
            #pragma unroll
            for (int k4 = 0; k4 < 4; ++k4) {
                uint4 ch = ph[k4], cl = pl[k4];
                if (i + 1 < 6) {
                    ph[k4] = *(const uint4*)(wph + (size_t)(4 * i + 4 + k4) * 8192);
                    pl[k4] = *(const uint4*)(wpl + (size_t)(4 * i + 4 + k4) * 8192);
                }
                const int ko = k4 * 32 + lk * 8;
                bf16x8 ah0 = *(const bf16x8*)&Xch[lm][ko];
                bf16x8 al0 = *(const bf16x8*)&Xcl[lm][ko];
                bf16x8 ah1 = *(const bf16x8*)&Xch[16 + lm][ko];
                bf16x8 al1 = *(const bf16x8*)&Xcl[16 + lm][ko];
                bf16x8 bh = *(bf16x8*)&ch;
                bf16x8 bl = *(bf16x8*)&cl;
                acc[0] = mfma16(ah0, bh, acc[0]);
                acc[0] = mfma16(ah0, bl, acc[0]);
                acc[0] = mfma16(al0, bh, acc[0]);
                acc[1] = mfma16(ah1, bh, acc[1]);
                acc[1] = mfma16(ah1, bl, acc[1]);
                acc[1] = mfma16(al1, bh, acc[1]);
            }
            if (i + 1 < 6) {
                ushort4 hv, lv;
                decomp_f4(sv, &hv, &lv);
                *(ushort4*)&Xdh[(i + 1) & 1][srow][sc4r] = hv;
                *(ushort4*)&Xdl[(i + 1) & 1][srow][sc4r] = lv;
                *(ushort4*)(xo + (i + 1) * CHK) = hv;
            }
            __syncthreads();
        }
        int col = wave * 16 + lm;
        float bv = rb1[col];
        #pragma unroll
        for (int m = 0; m < 2; ++m)
            #pragma unroll
            for (int r = 0; r < 4; ++r) {
                float v = acc[m][r] + bv;
                v = v > 0.f ? v : 0.f;
                __hip_bfloat16 h = __float2bfloat16(v);
                float hf = __bfloat162float(h);
                __hip_bfloat16 l = __float2bfloat16(v - hf);
                int row = m * 16 + lk * 4 + r;
                h1hs[row][col] = *(ushort*)&h;
                h1ls[row][col] = *(ushort*)&l;
            }
    }
    __syncthreads();

    // ---- layer 2: 8 K-steps, barrier-free; W global->reg depth-2
    {
        const int mt = wave >> 3, nb = wave & 7;
        const ushort* w2h = rw2hp + (size_t)(nb * 64 + lane) * 8;
        const ushort* w2l = rw2lp + (size_t)(nb * 64 + lane) * 8;
        f32x4 acc2 = {};
        uint4 pha = *(const uint4*)(w2h);
        uint4 pla = *(const uint4*)(w2l);
        uint4 phb = *(const uint4*)(w2h + 4096);
        uint4 plb = *(const uint4*)(w2l + 4096);
        for (int s = 0; s < 8; s += 2) {
            uint4 cha = pha, cla = pla, chb = phb, clb = plb;
            if (s + 2 < 8) {
                pha = *(const uint4*)(w2h + (size_t)(s + 2) * 4096);
                pla = *(const uint4*)(w2l + (size_t)(s + 2) * 4096);
                phb = *(const uint4*)(w2h + (size_t)(s + 3) * 4096);
                plb = *(const uint4*)(w2l + (size_t)(s + 3) * 4096);
            }
            {
                const int ko = s * 32 + lk * 8;
                bf16x8 ah = *(const bf16x8*)&h1hs[mt * 16 + lm][ko];
                bf16x8 al = *(const bf16x8*)&h1ls[mt * 16 + lm][ko];
                bf16x8 bh = *(bf16x8*)&cha;
                bf16x8 bl = *(bf16x8*)&cla;
                acc2 = mfma16(ah, bh, acc2);
                acc2 = mfma16(ah, bl, acc2);
                acc2 = mfma16(al, bh, acc2);
            }
            {
                const int ko = (s + 1) * 32 + lk * 8;
                bf16x8 ah = *(const bf16x8*)&h1hs[mt * 16 + lm][ko];
                bf16x8 al = *(const bf16x8*)&h1ls[mt * 16 + lm][ko];
                bf16x8 bh = *(bf16x8*)&chb;
                bf16x8 bl = *(bf16x8*)&clb;
                acc2 = mfma16(ah, bh, acc2);
                acc2 = mfma16(ah, bl, acc2);
                acc2 = mfma16(al, bh, acc2);
            }
        }
        __syncthreads();
        int col2 = nb * 16 + lm;
        float bv = rb2[col2];
        #pragma unroll
        for (int r = 0; r < 4; ++r) {
            float v = acc2[r] + bv;
            h2s[mt * 16 + lk * 4 + r][col2] = v > 0.f ? v : 0.f;
        }
    }
    __syncthreads();

    // ---- head
    const int o = lane >> 3, kq = lane & 7;
    #pragma unroll
    for (int i = 0; i < 2; ++i) {
        int rloc = wave * 2 + i;
        int b = r0 + rloc;
        float s = 0.f;
        #pragma unroll
        for (int q = 0; q < 4; ++q) {
            float4 hv = *(const float4*)&h2s[rloc][kq * 16 + q * 4];
            float4 wv = *(const float4*)&rW3[o * RH2 + kq * 16 + q * 4];
            s += hv.x * wv.x + hv.y * wv.y + hv.z * wv.z + hv.w * wv.w;
        }
        s += __shfl_xor(s, 1);
        s += __shfl_xor(s, 2);
        s += __shfl_xor(s, 4);
        float logit = s + rb3[o];
        float l[8];
        #pragma unroll
        for (int j = 0; j < 8; ++j) l[j] = __shfl(logit, j * 8);
        float m = l[0];
        #pragma unroll
        for (int j = 1; j < 8; ++j) m = fmaxf(m, l[j]);
        float p[8]; float sum = 0.f;
        #pragma unroll
        for (int j = 0; j < 8; ++j) { p[j] = expf(l[j] - m); sum += p[j]; }
        float inv = 1.f / sum;
        #pragma unroll
        for (int j = 0; j < 8; ++j) p[j] *= inv;
        int i1 = 0; float v1 = p[0];
        #pragma unroll
        for (int j = 1; j < 8; ++j) if (p[j] > v1) { v1 = p[j]; i1 = j; }
        int i2 = -1; float v2 = -1.f;
        #pragma unroll
        for (int j = 0; j < 8; ++j) if (j != i1 && p[j] > v2) { v2 = p[j]; i2 = j; }
        if (lane < 8) {
            router_p[(size_t)b * 8 + lane] = p[lane];
            float gv = (lane == i1) ? v1 * 0.5f : ((lane == i2) ? v2 * 0.5f : 0.f);
            gate[(size_t)b * 8 + lane] = gv;
        }
        if (lane == 0) t2[b] = i1 | (i2 << 8);
    }
    if (blockIdx.x == 0 && tid == 0) lb_out[0] = 0.f;
}

// ---------------- build dispatch lists + finalize scales (block 0)
__global__ __launch_bounds__(256) void build_lists_kernel(
    const int* __restrict__ t2, int* __restrict__ counts, int* __restrict__ ent,
    const float* __restrict__ p1, const float* __restrict__ p2, const float* __restrict__ p3,
    float* __restrict__ s1, float* __restrict__ s2, float* __restrict__ s3)
{
    if (blockIdx.x == 0 && threadIdx.x < 24) {
        int t = threadIdx.x;
        if (t < 8) {
            float a = 0.f;
            for (int i = 0; i < 96; ++i) a += p1[t * 96 + i];
            s1[t] = a / (float)(H1 * IN_DIM);
        } else if (t < 16) {
            int e = t - 8; float a = 0.f;
            for (int i = 0; i < 32; ++i) a += p2[e * 32 + i];
            s2[e] = a / (float)(H2 * H1);
        } else {
            int e = t - 16; float a = 0.f;
            for (int i = 0; i < 4; ++i) a += p3[e * 4 + i];
            s3[e] = a / (float)(NC * H2);
        }
    }
    __shared__ int hist[8], base[8];
    const int r = blockIdx.x * 256 + threadIdx.x;
    if (threadIdx.x < 8) hist[threadIdx.x] = 0;
    __syncthreads();
    const int v = t2[r];
    const int i1 = v & 255, i2 = v >> 8;
    const int rk1 = atomicAdd(&hist[i1], 1);
    const int rk2 = atomicAdd(&hist[i2], 1);
    __syncthreads();
    if (threadIdx.x < 8) base[threadIdx.x] = atomicAdd(&counts[threadIdx.x], hist[threadIdx.x]);
    __syncthreads();
    ent[i1 * B_ROWS + base[i1] + rk1] = (r << 1);
    ent[i2 * B_ROWS + base[i2] + rk2] = (r << 1) | 1;
}

// ---------------- sparse fused expert kernel: X gathered as bf16 (xh by-product)
__global__ __launch_bounds__(1024) void expert_fused_kernel(
    const ushort* __restrict__ xh,
    const unsigned char* __restrict__ W1p8, const unsigned char* __restrict__ W2p8,
    const unsigned char* __restrict__ W3p8,
    const float* __restrict__ s1, const float* __restrict__ s2, const float* __restrict__ s3,
    const float* __restrict__ eb1, const float* __restrict__ eb2, const float* __restrict__ eb3,
    const float* __restrict__ gate,
    const int* __restrict__ counts, const int* __restrict__ ent,
    float* __restrict__ S0, float* __restrict__ S1)
{
    int pfx[9]; pfx[0] = 0;
    #pragma unroll
    for (int i = 0; i < 8; ++i) pfx[i + 1] = pfx[i] + ((counts[i] + 63) >> 6);
    const int T = pfx[8];
    const int R = (T + 7) >> 3;
    const int xcd = blockIdx.x & 7, j = blockIdx.x >> 3;
    if (j >= R) return;
    const int g = xcd * R + j;
    if (g >= T) return;
    int e = 0;
    #pragma unroll
    for (int i = 0; i < 7; ++i) if (g >= pfx[i + 1]) e = i + 1;
    const int t = g - pfx[e];
    const int cnt = counts[e];

    __shared__ __align__(16) unsigned char smem[101376];
    __hip_bfloat16 (*A1s)[520] = (__hip_bfloat16(*)[520])(smem);
    __hip_bfloat16 (*A2s)[264] = (__hip_bfloat16(*)[264])(smem + 66560);
    ushort (*Xd)[64][136]      = (ushort(*)[64][136])(smem + 66560);
    __shared__ int rowL[64];
    __shared__ int slotL[64];
    __shared__ float gL[64];

    const int tid = threadIdx.x;
    const int wave = tid >> 6;
    const int lane = tid & 63;
    const int lm = lane & 15;
    const int lk = lane >> 4;

    if (tid < 64) {
        int idx = t * 64 + tid;
        if (idx < cnt) {
            int entv = ent[e * B_ROWS + idx];
            int r = entv >> 1;
            rowL[tid] = r;
            slotL[tid] = entv & 1;
            gL[tid] = gate[(size_t)r * NE + e];
        } else {
            rowL[tid] = -1; slotL[tid] = 0; gL[tid] = 0.f;
        }
    }
    __syncthreads();

    const int srow = tid >> 4;
    const int sc8  = (tid & 15) * 8;
    int SR = rowL[srow]; if (SR < 0) SR = 0;
    const ushort* sg = xh + (size_t)SR * IN_DIM + sc8;
    const unsigned char* Wsrc1 = W1p8 + (size_t)e * 393216;
    const unsigned char* Wsrc2 = W2p8 + (size_t)e * 131072;
    const unsigned char* Wsrc3 = W3p8 + (size_t)e * 16384;

    {
        bf16x8 sv = *(const bf16x8*)sg;
        *(bf16x8*)&Xd[0][srow][sc8] = sv;
    }
    __syncthreads();

    // ---- layer 1: 6 intervals x 4 K-steps; W global->reg, depth-4 prefetch
    {
        f32x4 acc[4][2] = {};
        const int w2 = wave * 2;
        const unsigned char* wp1 = Wsrc1 + wave * 1024 + lane * 16;
        uint4 pw[4];
        #pragma unroll
        for (int k = 0; k < 4; ++k)
            pw[k] = *(const uint4*)(wp1 + (size_t)k * 16384);
        for (int i = 0; i < 6; ++i) {
            bf16x8 sv;
            if (i + 1 < 6) sv = *(const bf16x8*)(sg + (i + 1) * CHK);
            uint4 cur[4];
            #pragma unroll
            for (int k = 0; k < 4; ++k) cur[k] = pw[k];
            if (i + 1 < 6) {
                #pragma unroll
                for (int k = 0; k < 4; ++k)
                    pw[k] = *(const uint4*)(wp1 + (size_t)(4 * i + 4 + k) * 16384);
            }
            const ushort (*Xc)[136] = Xd[i & 1];
            #pragma unroll
            for (int k4 = 0; k4 < 4; ++k4) {
                const int ko = k4 * 32 + lk * 8;
                bf16x8 a0 = *(const bf16x8*)&Xc[     lm][ko];
                bf16x8 a1 = *(const bf16x8*)&Xc[16 + lm][ko];
                bf16x8 a2 = *(const bf16x8*)&Xc[32 + lm][ko];
                bf16x8 a3 = *(const bf16x8*)&Xc[48 + lm][ko];
                bf16x8 b0 = expand_frag(make_uint2(cur[k4].x, cur[k4].y));
                bf16x8 b1 = expand_frag(make_uint2(cur[k4].z, cur[k4].w));
                acc[0][0] = mfma16(a0, b0, acc[0][0]);
                acc[1][0] = mfma16(a1, b0, acc[1][0]);
                acc[2][0] = mfma16(a2, b0, acc[2][0]);
                acc[3][0] = mfma16(a3, b0, acc[3][0]);
                acc[0][1] = mfma16(a0, b1, acc[0][1]);
                acc[1][1] = mfma16(a1, b1, acc[1][1]);
                acc[2][1] = mfma16(a2, b1, acc[2][1]);
                acc[3][1] = mfma16(a3, b1, acc[3][1]);
            }
            if (i + 1 < 6) *(bf16x8*)&Xd[(i + 1) & 1][srow][sc8] = sv;
            __syncthreads();
        }
        const float* bias = eb1 + e * H1;
        const float sc = s1[e];
        #pragma unroll
        for (int n = 0; n < 2; ++n) {
            int ncol = (w2 + n) * 16 + lm;
            float bv = bias[ncol];
            #pragma unroll
            for (int m = 0; m < 4; ++m)
                #pragma unroll
                for (int r = 0; r < 4; ++r) {
                    float v = fmaf(acc[m][n][r], sc, bv);
                    v = v > 0.f ? v : 0.f;
                    A1s[m * 16 + lk * 4 + r][ncol] = __float2bfloat16(v);
                }
        }
    }
    __syncthreads();

    // ---- layer 2: 16 K-steps, zero internal barriers; W global->reg, depth-2
    {
        const int mt = wave >> 3, ntw = wave & 7;
        const unsigned char* wp2 = Wsrc2 + ntw * 1024 + lane * 16;
        f32x4 acc[2][2] = {};
        uint4 pwa = *(const uint4*)(wp2);
        uint4 pwb = *(const uint4*)(wp2 + 8192);
        for (int s = 0; s < 16; s += 2) {
            uint4 c0 = pwa, c1 = pwb;
            if (s + 2 < 16) {
                pwa = *(const uint4*)(wp2 + (size_t)(s + 2) * 8192);
                pwb = *(const uint4*)(wp2 + (size_t)(s + 3) * 8192);
            }
            {
                const int ko = s * 32 + lk * 8;
                bf16x8 a0 = *(const bf16x8*)&A1s[mt * 32 +      lm][ko];
                bf16x8 a1 = *(const bf16x8*)&A1s[mt * 32 + 16 + lm][ko];
                bf16x8 b0 = expand_frag(make_uint2(c0.x, c0.y));
                bf16x8 b1 = expand_frag(make_uint2(c0.z, c0.w));
                acc[0][0] = mfma16(a0, b0, acc[0][0]);
                acc[1][0] = mfma16(a1, b0, acc[1][0]);
                acc[0][1] = mfma16(a0, b1, acc[0][1]);
                acc[1][1] = mfma16(a1, b1, acc[1][1]);
            }
            {
                const int ko = (s + 1) * 32 + lk * 8;
                bf16x8 a0 = *(const bf16x8*)&A1s[mt * 32 +      lm][ko];
                bf16x8 a1 = *(const bf16x8*)&A1s[mt * 32 + 16 + lm][ko];
                bf16x8 b0 = expand_frag(make_uint2(c1.x, c1.y));
                bf16x8 b1 = expand_frag(make_uint2(c1.z, c1.w));
                acc[0][0] = mfma16(a0, b0, acc[0][0]);
                acc[1][0] = mfma16(a1, b0, acc[1][0]);
                acc[0][1] = mfma16(a0, b1, acc[0][1]);
                acc[1][1] = mfma16(a1, b1, acc[1][1]);
            }
        }
        const float* bias = eb2 + e * H2;
        const float sc = s2[e];
        #pragma unroll
        for (int n = 0; n < 2; ++n) {
            int ncol = (ntw * 2 + n) * 16 + lm;
            float bv = bias[ncol];
            #pragma unroll
            for (int m = 0; m < 2; ++m)
                #pragma unroll
                for (int r = 0; r < 4; ++r) {
                    float v = fmaf(acc[m][n][r], sc, bv);
                    v = v > 0.f ? v : 0.f;
                    A2s[mt * 32 + m * 16 + lk * 4 + r][ncol] = __float2bfloat16(v);
                }
        }
    }
    __syncthreads();

    // ---- layer 3: W3 global->reg (flat layout)
    {
        const int mt = wave & 3, nt = wave >> 2;
        f32x4 acc = {};
        #pragma unroll
        for (int s = 0; s < 8; ++s) {
            bf16x8 a = *(const bf16x8*)&A2s[mt * 16 + lm][s * 32 + lk * 8];
            uint2 pw = *(const uint2*)(Wsrc3 + ((s * 4 + nt) * 64 + lane) * 8);
            bf16x8 b = expand_frag(pw);
            acc = mfma16(a, b, acc);
        }
        int col = nt * 16 + lm;
        if (col < NC) {
            const float bv = eb3[e * NC + col];
            const float sc = s3[e];
            #pragma unroll
            for (int r = 0; r < 4; ++r) {
                int row = mt * 16 + lk * 4 + r;
                int R2 = rowL[row];
                if (R2 >= 0) {
                    float v = gL[row] * fmaf(acc[r], sc, bv);
                    float* Sb = slotL[row] ? S1 : S0;
                    Sb[(size_t)R2 * 64 + col] = v;
                }
            }
        }
    }
}

// ---------------- combine
__global__ __launch_bounds__(256) void combine_kernel(
    const float* __restrict__ S0, const float* __restrict__ S1, float* __restrict__ out)
{
    int i = blockIdx.x * 256 + threadIdx.x;
    if (i < B_ROWS * NC) {
        int row = i / NC, col = i % NC;
        out[i] = S0[(size_t)row * 64 + col] + S1[(size_t)row * 64 + col];
    }
}

extern "C" void kernel_launch(void* const* d_in, const int* in_sizes, int n_in,
                              void* d_out, int out_size, void* d_ws, size_t ws_size,
                              hipStream_t stream) {
    const float* x   = (const float*)d_in[0];
    const float* rW1 = (const float*)d_in[1];
    const float* rb1 = (const float*)d_in[2];
    const float* rW2 = (const float*)d_in[3];
    const float* rb2 = (const float*)d_in[4];
    const float* rW3 = (const float*)d_in[5];
    const float* rb3 = (const float*)d_in[6];
    const float* eW1 = (const float*)d_in[7];
    const float* eb1 = (const float*)d_in[8];
    const float* eW2 = (const float*)d_in[9];
    const float* eb2 = (const float*)d_in[10];
    const float* eW3 = (const float*)d_in[11];
    const float* eb3 = (const float*)d_in[12];

    float* out_main = (float*)d_out;
    float* router_p = out_main + (size_t)B_ROWS * NC;
    float* lb_out   = router_p + (size_t)B_ROWS * NE;

    char* ws = (char*)d_ws;
    size_t off = 0;
    unsigned char* W1p8 = (unsigned char*)(ws + off); off += (size_t)NE * 49152 * 8;
    unsigned char* W2p8 = (unsigned char*)(ws + off); off += (size_t)NE * 16384 * 8;
    unsigned char* W3p8 = (unsigned char*)(ws + off); off += (size_t)NE * 2048 * 8;
    ushort* xh  = (ushort*)(ws + off); off += (size_t)B_ROWS * IN_DIM * 2;
    float* S0   = (float*)(ws + off);  off += (size_t)B_ROWS * 64 * 4;
    float* S1   = (float*)(ws + off);  off += (size_t)B_ROWS * 64 * 4;
    ushort* rw1hp = (ushort*)(ws + off); off += (size_t)24576 * 8 * 2;
    ushort* rw1lp = (ushort*)(ws + off); off += (size_t)24576 * 8 * 2;
    ushort* rw2hp = (ushort*)(ws + off); off += (size_t)4096 * 8 * 2;
    ushort* rw2lp = (ushort*)(ws + off); off += (size_t)4096 * 8 * 2;
    float* gate = (float*)(ws + off);  off += (size_t)B_ROWS * NE * 4;
    int*   ent  = (int*)(ws + off);    off += (size_t)NE * B_ROWS * 4;
    int*   t2   = (int*)(ws + off);    off += (size_t)B_ROWS * 4;
    int* counts = (int*)(ws + off);    off += 256;
    float* s1   = (float*)(ws + off);  off += 256;
    float* s2   = (float*)(ws + off);  off += 256;
    float* s3   = (float*)(ws + off);  off += 256;
    float* p1   = (float*)(ws + off);  off += NE * 96 * 4;
    float* p2   = (float*)(ws + off);  off += NE * 32 * 4;
    float* p3   = (float*)(ws + off);  off += NE * 4 * 4;

    // 1) prep (single merged kernel)
    pack_absum_kernel<<<dim3(96, 25), 512, 0, stream>>>(
        eW1, eW2, eW3, W1p8, W2p8, W3p8, p1, p2, p3,
        rW1, rw1hp, rw1lp, rW2, rw2hp, rw2lp, counts);

    // 2) fused router (writes xh by-product)
    router_fused_kernel<<<B_ROWS / 32, 1024, 0, stream>>>(
        x, xh, rw1hp, rw1lp, rb1, rw2hp, rw2lp, rb2, rW3, rb3, router_p, gate, lb_out, t2);
    build_lists_kernel<<<B_ROWS / 256, 256, 0, stream>>>(
        t2, counts, ent, p1, p2, p3, s1, s2, s3);

    // 3) sparse fused experts (bf16 X gather) + combine
    expert_fused_kernel<<<1024, 1024, 0, stream>>>(
        xh, W1p8, W2p8, W3p8, s1, s2, s3, eb1, eb2, eb3, gate, counts, ent, S0, S1);
    combine_kernel<<<(B_ROWS * NC + 255) / 256, 256, 0, stream>>>(S0, S1, out_main);
}